// Round 2
// baseline (10189.359 us; speedup 1.0000x reference)
//
#include <hip/hip_runtime.h>
#include <hip/hip_bf16.h>

// Problem constants
#define T_STEPS 64
#define BATCH   32
#define HID     1024
#define VOCAB   32000
#define WLEN_   101
#define WSZ_    50
#define SENC    229

static const size_t Y_SZ   = (size_t)T_STEPS * BATCH * VOCAB;   // 65,536,000
static const size_t HN_SZ  = (size_t)2 * BATCH * HID;           // 65,536
static const size_t CTX_OFF = Y_SZ + 2 * HN_SZ;                 // y + h_n + c_n

typedef __attribute__((ext_vector_type(8))) unsigned short us8;
typedef __attribute__((ext_vector_type(8))) __bf16 bf16x8;
typedef __attribute__((ext_vector_type(4))) float f32x4;

static __device__ inline unsigned short f2bf(float x) {
    __hip_bfloat16 b = __float2bfloat16(x);
    return __builtin_bit_cast(unsigned short, b);
}

// ---------------------------------------------------------------------------
// fp32 GEMM (kept for gates/attn-proj paths): out[M,N] = A[M,K] @ W[N,K]^T
// ---------------------------------------------------------------------------
__global__ __launch_bounds__(256) void gemm_bt(
    const float* __restrict__ A, const float* __restrict__ W,
    const float* __restrict__ b1, const float* __restrict__ b2,
    float* __restrict__ out, int M, int N, int K, int act)
{
    __shared__ __align__(16) float As[16 * 132];
    __shared__ __align__(16) float Ws[16 * 68];
    const int tid  = threadIdx.x;
    const int col0 = blockIdx.x * 64;
    const int row0 = blockIdx.y * 128;
    const int ty   = tid >> 4;
    const int tx   = tid & 15;

    float acc[8][4];
#pragma unroll
    for (int i = 0; i < 8; ++i)
#pragma unroll
        for (int j = 0; j < 4; ++j) acc[i][j] = 0.f;

    for (int k0 = 0; k0 < K; k0 += 16) {
#pragma unroll
        for (int li = 0; li < 2; ++li) {
            int f  = tid + li * 256;
            int r  = f >> 2;
            int kq = (f & 3) << 2;
            float4 v = *reinterpret_cast<const float4*>(A + (size_t)(row0 + r) * K + k0 + kq);
            As[(kq + 0) * 132 + r] = v.x;
            As[(kq + 1) * 132 + r] = v.y;
            As[(kq + 2) * 132 + r] = v.z;
            As[(kq + 3) * 132 + r] = v.w;
        }
        {
            int n  = tid >> 2;
            int kq = (tid & 3) << 2;
            float4 v = *reinterpret_cast<const float4*>(W + (size_t)(col0 + n) * K + k0 + kq);
            Ws[(kq + 0) * 68 + n] = v.x;
            Ws[(kq + 1) * 68 + n] = v.y;
            Ws[(kq + 2) * 68 + n] = v.z;
            Ws[(kq + 3) * 68 + n] = v.w;
        }
        __syncthreads();
#pragma unroll
        for (int k = 0; k < 16; ++k) {
            const float4 a0 = *reinterpret_cast<const float4*>(&As[k * 132 + ty * 8]);
            const float4 a1 = *reinterpret_cast<const float4*>(&As[k * 132 + ty * 8 + 4]);
            const float4 b0 = *reinterpret_cast<const float4*>(&Ws[k * 68 + tx * 4]);
            float av[8] = {a0.x, a0.y, a0.z, a0.w, a1.x, a1.y, a1.z, a1.w};
            float bv[4] = {b0.x, b0.y, b0.z, b0.w};
#pragma unroll
            for (int i = 0; i < 8; ++i)
#pragma unroll
                for (int j = 0; j < 4; ++j) acc[i][j] = fmaf(av[i], bv[j], acc[i][j]);
        }
        __syncthreads();
    }

#pragma unroll
    for (int j = 0; j < 4; ++j) {
        int n = col0 + tx * 4 + j;
        float bias = 0.f;
        if (b1) bias += b1[n];
        if (b2) bias += b2[n];
#pragma unroll
        for (int i = 0; i < 8; ++i) {
            float v = acc[i][j] + bias;
            if (act == 1) v = fmaxf(v, 0.f);
            else if (act == 2) v = tanhf(v);
            out[(size_t)(row0 + ty * 8 + i) * N + n] = v;
        }
    }
}

// ---------------------------------------------------------------------------
// bf16 MFMA GEMM: out[M,N] = A[M,K] @ W[N,K]^T + bias, optional relu.
// A, W are fp32 in global; converted to bf16 during LDS staging.
// Tile 128x128, BK=32, 256 threads = 4 waves (2x2 of 64x64 per wave),
// per wave 4x4 fragments of mfma_f32_16x16x32_bf16.
// LDS layout: [kc-plane 0..3][row 0..127] 16B chunks (8 bf16 = 8 k-elems).
// Requires M%128==0, N%128==0, K%32==0.
// ---------------------------------------------------------------------------
__global__ __launch_bounds__(256) void gemm_mfma_bt(
    const float* __restrict__ A, const float* __restrict__ W,
    const float* __restrict__ bias, float* __restrict__ out,
    int M, int N, int K, int relu)
{
    __shared__ __align__(16) unsigned short As[4096];   // 8 KB
    __shared__ __align__(16) unsigned short Bs[4096];   // 8 KB
    const int tid  = threadIdx.x;
    const int lane = tid & 63;
    const int wave = tid >> 6;
    const int row0 = blockIdx.y * 128;
    const int col0 = blockIdx.x * 128;
    const int m0 = (wave >> 1) * 64;
    const int n0 = (wave & 1) * 64;
    const int lrow = lane & 15;
    const int kc   = lane >> 4;          // 0..3  (k-chunk of 8)

    const int srow = tid >> 1;           // staging row 0..127
    const int skh  = tid & 1;            // k half (16 elems)

    f32x4 acc[4][4];
#pragma unroll
    for (int i = 0; i < 4; ++i)
#pragma unroll
        for (int j = 0; j < 4; ++j) acc[i][j] = (f32x4){0.f, 0.f, 0.f, 0.f};

    const float* gA = A + (size_t)(row0 + srow) * K + skh * 16;
    const float* gW = W + (size_t)(col0 + srow) * K + skh * 16;

    for (int k0 = 0; k0 < K; k0 += 32) {
        // ---- stage A,W (f32 -> bf16) into LDS ----
        {
            float4 v0 = *reinterpret_cast<const float4*>(gA + k0);
            float4 v1 = *reinterpret_cast<const float4*>(gA + k0 + 4);
            float4 v2 = *reinterpret_cast<const float4*>(gA + k0 + 8);
            float4 v3 = *reinterpret_cast<const float4*>(gA + k0 + 12);
            us8 c0 = {f2bf(v0.x), f2bf(v0.y), f2bf(v0.z), f2bf(v0.w),
                      f2bf(v1.x), f2bf(v1.y), f2bf(v1.z), f2bf(v1.w)};
            us8 c1 = {f2bf(v2.x), f2bf(v2.y), f2bf(v2.z), f2bf(v2.w),
                      f2bf(v3.x), f2bf(v3.y), f2bf(v3.z), f2bf(v3.w)};
            *reinterpret_cast<us8*>(&As[((skh * 2 + 0) * 128 + srow) * 8]) = c0;
            *reinterpret_cast<us8*>(&As[((skh * 2 + 1) * 128 + srow) * 8]) = c1;
            float4 w0 = *reinterpret_cast<const float4*>(gW + k0);
            float4 w1 = *reinterpret_cast<const float4*>(gW + k0 + 4);
            float4 w2 = *reinterpret_cast<const float4*>(gW + k0 + 8);
            float4 w3 = *reinterpret_cast<const float4*>(gW + k0 + 12);
            us8 d0 = {f2bf(w0.x), f2bf(w0.y), f2bf(w0.z), f2bf(w0.w),
                      f2bf(w1.x), f2bf(w1.y), f2bf(w1.z), f2bf(w1.w)};
            us8 d1 = {f2bf(w2.x), f2bf(w2.y), f2bf(w2.z), f2bf(w2.w),
                      f2bf(w3.x), f2bf(w3.y), f2bf(w3.z), f2bf(w3.w)};
            *reinterpret_cast<us8*>(&Bs[((skh * 2 + 0) * 128 + srow) * 8]) = d0;
            *reinterpret_cast<us8*>(&Bs[((skh * 2 + 1) * 128 + srow) * 8]) = d1;
        }
        __syncthreads();
        // ---- fragments + MFMA ----
        us8 a[4], b[4];
#pragma unroll
        for (int f = 0; f < 4; ++f) {
            a[f] = *reinterpret_cast<const us8*>(&As[(kc * 128 + m0 + f * 16 + lrow) * 8]);
            b[f] = *reinterpret_cast<const us8*>(&Bs[(kc * 128 + n0 + f * 16 + lrow) * 8]);
        }
#pragma unroll
        for (int fi = 0; fi < 4; ++fi)
#pragma unroll
            for (int fj = 0; fj < 4; ++fj)
                acc[fi][fj] = __builtin_amdgcn_mfma_f32_16x16x32_bf16(
                    __builtin_bit_cast(bf16x8, a[fi]),
                    __builtin_bit_cast(bf16x8, b[fj]),
                    acc[fi][fj], 0, 0, 0);
        __syncthreads();
    }

    // ---- epilogue: C/D layout col=lane&15, row=(lane>>4)*4+j ----
#pragma unroll
    for (int fi = 0; fi < 4; ++fi)
#pragma unroll
        for (int fj = 0; fj < 4; ++fj) {
            int cN = col0 + n0 + fj * 16 + lrow;
            float bv = bias ? bias[cN] : 0.f;
#pragma unroll
            for (int j = 0; j < 4; ++j) {
                int r = row0 + m0 + fi * 16 + (lane >> 4) * 4 + j;
                float v = acc[fi][fj][j] + bv;
                if (relu) v = fmaxf(v, 0.f);
                out[(size_t)r * N + cN] = v;
            }
        }
}

// ---------------------------------------------------------------------------
// Embedding lookup + input-feeding concat
// ---------------------------------------------------------------------------
__global__ void embed_concat_kernel(const float* __restrict__ emb,
                                    const float* __restrict__ ctxin,
                                    const int* __restrict__ tw,
                                    float* __restrict__ x)
{
    const size_t total = (size_t)2048 * 2048;
    for (size_t idx = (size_t)blockIdx.x * blockDim.x + threadIdx.x; idx < total;
         idx += (size_t)gridDim.x * blockDim.x) {
        int h = (int)(idx & 2047);
        size_t row = idx >> 11;
        float v;
        if (h < HID) v = emb[(size_t)tw[row] * HID + h];
        else         v = ctxin[row * HID + (h - HID)];
        x[idx] = v;
    }
}

// ---------------------------------------------------------------------------
// LSTM step v2: 256 blocks x 256 threads. Block owns 4 h-columns
// (j = blk*4 + c), i.e. 16 Whh rows. Full h staged in LDS (f32, stride 1028).
// Thread = (b = t>>3, c = (t>>2)&1? no: c = t&3, kh = (t>>2)&1); each thread
// accumulates 4 gates over its 512-k half; k-halves combined via shfl_xor(4).
// ---------------------------------------------------------------------------
#define HSTR 1028
__global__ __launch_bounds__(256) void lstm_step_v2(
    const float* __restrict__ gpre,   // [32,4096] slice at t
    const float* __restrict__ Whh,    // [4096,1024]
    const float* __restrict__ h_in,   // [32,1024]
    float* __restrict__ c_io,         // [32,1024]
    float* __restrict__ h_out,        // [32,1024]
    float* __restrict__ y_out)        // [32,1024]
{
    __shared__ __align__(16) float hs[32 * HSTR];   // ~131.6 KB
    const int tid = threadIdx.x;
    const int b  = tid >> 3;          // 0..31
    const int c  = tid & 3;           // 0..3
    const int kh = (tid >> 2) & 1;    // 0..1
    const int j  = blockIdx.x * 4 + c;

    // stage h: 8192 float4, coalesced, consecutive lanes -> consecutive chunks
    for (int i = tid; i < 8192; i += 256) {
        int row = i >> 8;
        int k4  = i & 255;
        *reinterpret_cast<float4*>(&hs[row * HSTR + k4 * 4]) =
            *reinterpret_cast<const float4*>(&h_in[(size_t)row * HID + k4 * 4]);
    }
    __syncthreads();

    const float* w0 = Whh + (size_t)(0 * HID + j) * HID + kh * 512;
    const float* w1 = Whh + (size_t)(1 * HID + j) * HID + kh * 512;
    const float* w2 = Whh + (size_t)(2 * HID + j) * HID + kh * 512;
    const float* w3 = Whh + (size_t)(3 * HID + j) * HID + kh * 512;
    const float* hv = &hs[b * HSTR + kh * 512];

    float a0 = 0.f, a1 = 0.f, a2 = 0.f, a3 = 0.f;
#pragma unroll 4
    for (int q = 0; q < 128; ++q) {
        float4 h4 = *reinterpret_cast<const float4*>(hv + q * 4);
        float4 x0 = *reinterpret_cast<const float4*>(w0 + q * 4);
        float4 x1 = *reinterpret_cast<const float4*>(w1 + q * 4);
        float4 x2 = *reinterpret_cast<const float4*>(w2 + q * 4);
        float4 x3 = *reinterpret_cast<const float4*>(w3 + q * 4);
        a0 += h4.x * x0.x + h4.y * x0.y + h4.z * x0.z + h4.w * x0.w;
        a1 += h4.x * x1.x + h4.y * x1.y + h4.z * x1.z + h4.w * x1.w;
        a2 += h4.x * x2.x + h4.y * x2.y + h4.z * x2.z + h4.w * x2.w;
        a3 += h4.x * x3.x + h4.y * x3.y + h4.z * x3.z + h4.w * x3.w;
    }

    // combine the two k-halves: lanes t and t^4 hold the same (b, c)
    a0 += __shfl_xor(a0, 4);
    a1 += __shfl_xor(a1, 4);
    a2 += __shfl_xor(a2, 4);
    a3 += __shfl_xor(a3, 4);

    if (kh == 0) {
        const int bi = b * 4096;
        float pi = gpre[bi + j]            + a0;
        float pf = gpre[bi + HID + j]      + a1;
        float pg = gpre[bi + 2 * HID + j]  + a2;
        float po = gpre[bi + 3 * HID + j]  + a3;
        float ig = 1.f / (1.f + expf(-pi));
        float fg = 1.f / (1.f + expf(-pf));
        float gg = tanhf(pg);
        float og = 1.f / (1.f + expf(-po));
        float cv = fg * c_io[b * HID + j] + ig * gg;
        c_io[b * HID + j] = cv;
        float h  = og * tanhf(cv);
        h_out[b * HID + j] = h;
        y_out[b * HID + j] = h;
    }
}

// ---------------------------------------------------------------------------
// Attention p
// ---------------------------------------------------------------------------
__global__ __launch_bounds__(64) void attn_p_kernel(
    const float* __restrict__ hidden1, const float* __restrict__ aw2,
    const float* __restrict__ ab2, const int* __restrict__ lengths,
    float* __restrict__ p_arr, int* __restrict__ win_arr)
{
    const int row = blockIdx.x;
    const int lane = threadIdx.x;
    float s = 0.f;
    for (int i = lane; i < 512; i += 64) s += hidden1[(size_t)row * 512 + i] * aw2[i];
    for (int off = 32; off > 0; off >>= 1) s += __shfl_down(s, off);
    if (lane == 0) {
        float v = s + ab2[0];
        float sig = 1.f / (1.f + expf(-v));
        int b = row & 31;
        float lf = (float)lengths[b];
        p_arr[row] = (float)WSZ_ + lf * sig;
        win_arr[row] = (int)rintf(lf * sig);
    }
}

__global__ void sel_gather_kernel(const float* __restrict__ enc,
                                  const int* __restrict__ win_arr,
                                  float* __restrict__ sel)
{
    const int total = BATCH * WLEN_ * HID;
    for (int idx = blockIdx.x * blockDim.x + threadIdx.x; idx < total;
         idx += gridDim.x * blockDim.x) {
        int h = idx & 1023;
        int w = (idx >> 10) % WLEN_;
        int b = idx / (WLEN_ * HID);
        int s = win_arr[(T_STEPS - 1) * BATCH + b] + w;
        sel[idx] = enc[((size_t)s * BATCH + b) * HID + h];
    }
}

__global__ __launch_bounds__(128) void attn_fused_kernel(
    const float* __restrict__ y1, const float* __restrict__ sel,
    const float* __restrict__ p_arr, const int* __restrict__ win_arr,
    const int* __restrict__ lengths, float* __restrict__ ctx)
{
    __shared__ __align__(16) float yl[1024];
    __shared__ float sv[WLEN_];
    __shared__ float av[WLEN_];
    const int row = blockIdx.x;
    const int b   = row & 31;
    const int tid = threadIdx.x;

    for (int i = tid; i < 1024; i += 128) yl[i] = y1[(size_t)row * HID + i];
    __syncthreads();

    const int win = win_arr[row];
    const float p = p_arr[row];
    const int len = lengths[b];

    if (tid < WLEN_) {
        const float4* s4 = reinterpret_cast<const float4*>(sel + ((size_t)b * WLEN_ + tid) * HID);
        const float4* y4 = reinterpret_cast<const float4*>(yl);
        float acc = 0.f;
        for (int q = 0; q < 256; ++q) {
            float4 a = s4[q]; float4 yy = y4[q];
            acc += a.x * yy.x + a.y * yy.y + a.z * yy.z + a.w * yy.w;
        }
        bool lo = tid < (WSZ_ - win);
        bool hi = tid >= (len + WSZ_ - win);
        sv[tid] = (lo || hi) ? 1e-14f : acc;
    }
    __syncthreads();

    float mx = -1e30f;
    for (int w = 0; w < WLEN_; ++w) mx = fmaxf(mx, sv[w]);
    float sum = 0.f;
    for (int w = 0; w < WLEN_; ++w) sum += expf(sv[w] - mx);
    if (tid < WLEN_) {
        float e = expf(sv[tid] - mx) / sum;
        float d = (float)(win + tid) - p;
        av[tid] = e * expf(-(d * d) / 1250.f);
    }
    __syncthreads();

    float acc[8] = {0, 0, 0, 0, 0, 0, 0, 0};
    for (int w = 0; w < WLEN_; ++w) {
        float a = av[w];
        const float* srow = sel + ((size_t)b * WLEN_ + w) * HID;
#pragma unroll
        for (int i = 0; i < 8; ++i) acc[i] += a * srow[tid + 128 * i];
    }
    for (int i = 0; i < 8; ++i) ctx[(size_t)row * HID + tid + 128 * i] = acc[i];
}

__global__ void concat_fin_kernel(const float* __restrict__ ctx,
                                  const float* __restrict__ y1,
                                  float* __restrict__ fin)
{
    const size_t total = (size_t)2048 * 2048;
    for (size_t idx = (size_t)blockIdx.x * blockDim.x + threadIdx.x; idx < total;
         idx += (size_t)gridDim.x * blockDim.x) {
        int h = (int)(idx & 2047);
        size_t row = idx >> 11;
        fin[idx] = (h < HID) ? ctx[row * HID + h] : y1[row * HID + (h - HID)];
    }
}

__global__ void copy_kernel(const float* __restrict__ src, float* __restrict__ dst, int n)
{
    int i = blockIdx.x * blockDim.x + threadIdx.x;
    if (i < n) dst[i] = src[i];
}

// ---------------------------------------------------------------------------
extern "C" void kernel_launch(void* const* d_in, const int* in_sizes, int n_in,
                              void* d_out, int out_size, void* d_ws, size_t ws_size,
                              hipStream_t stream)
{
    const float* enc   = (const float*)d_in[0];
    const float* ctxin = (const float*)d_in[1];
    const float* h0    = (const float*)d_in[2];
    const float* c0    = (const float*)d_in[3];
    const float* emb   = (const float*)d_in[4];
    const float* aw1   = (const float*)d_in[5];
    const float* ab1   = (const float*)d_in[6];
    const float* aw2   = (const float*)d_in[7];
    const float* ab2   = (const float*)d_in[8];
    const float* Wih0  = (const float*)d_in[9];
    const float* Whh0  = (const float*)d_in[10];
    const float* bih0  = (const float*)d_in[11];
    const float* bhh0  = (const float*)d_in[12];
    const float* Wih1  = (const float*)d_in[13];
    const float* Whh1  = (const float*)d_in[14];
    const float* bih1  = (const float*)d_in[15];
    const float* bhh1  = (const float*)d_in[16];
    const float* fc1w  = (const float*)d_in[17];
    const float* fc1b  = (const float*)d_in[18];
    const float* fc2w  = (const float*)d_in[19];
    const float* fc2b  = (const float*)d_in[20];
    const int*   tw    = (const int*)d_in[21];
    const int*   lens  = (const int*)d_in[22];

    float* ws = (float*)d_ws;
    float* buf_x       = ws;                         // x; later fc1out
    float* buf_gates   = ws + 4194304;               // gates; later fin
    float* buf_y0      = ws + 12582912;
    float* buf_y1      = ws + 14680064;
    float* buf_hA      = ws + 16777216;
    float* buf_hB      = ws + 16809984;
    float* buf_c       = ws + 16842752;
    float* buf_hidden1 = ws + 16875520;
    float* buf_p       = ws + 17924096;
    int*   buf_win     = (int*)(ws + 17926144);
    float* buf_sel     = ws + 17928192;
    float* buf_fin     = buf_gates;
    float* buf_fc1out  = buf_x;

    float* out   = (float*)d_out;
    float* out_hn  = out + Y_SZ;
    float* out_cn  = out + Y_SZ + HN_SZ;
    float* out_ctx = out + CTX_OFF;

    const int HC = BATCH * HID;

    // 1. x = [embedding[tw], context]
    embed_concat_kernel<<<4096, 256, 0, stream>>>(emb, ctxin, tw, buf_x);

    // 2. gates0_pre = x @ Wih0^T + bih0 + bhh0   (fp32, feeds exact h/c path)
    gemm_bt<<<dim3(4096 / 64, 2048 / 128), 256, 0, stream>>>(
        buf_x, Wih0, bih0, bhh0, buf_gates, 2048, 4096, 2048, 0);

    // 3. LSTM layer 0
    copy_kernel<<<128, 256, 0, stream>>>(h0, buf_hA, HC);
    copy_kernel<<<128, 256, 0, stream>>>(c0, buf_c, HC);
    for (int t = 0; t < T_STEPS; ++t) {
        const float* hin = (t & 1) ? buf_hB : buf_hA;
        float* hout      = (t & 1) ? buf_hA : buf_hB;
        lstm_step_v2<<<256, 256, 0, stream>>>(
            buf_gates + (size_t)t * BATCH * 4096, Whh0, hin, buf_c, hout,
            buf_y0 + (size_t)t * HC);
    }
    copy_kernel<<<128, 256, 0, stream>>>(buf_hA, out_hn, HC);
    copy_kernel<<<128, 256, 0, stream>>>(buf_c, out_cn, HC);

    // 4. gates1_pre = y0 @ Wih1^T + bih1 + bhh1
    gemm_bt<<<dim3(4096 / 64, 2048 / 128), 256, 0, stream>>>(
        buf_y0, Wih1, bih1, bhh1, buf_gates, 2048, 4096, 1024, 0);

    // 5. LSTM layer 1
    copy_kernel<<<128, 256, 0, stream>>>(h0 + HC, buf_hA, HC);
    copy_kernel<<<128, 256, 0, stream>>>(c0 + HC, buf_c, HC);
    for (int t = 0; t < T_STEPS; ++t) {
        const float* hin = (t & 1) ? buf_hB : buf_hA;
        float* hout      = (t & 1) ? buf_hA : buf_hB;
        lstm_step_v2<<<256, 256, 0, stream>>>(
            buf_gates + (size_t)t * BATCH * 4096, Whh1, hin, buf_c, hout,
            buf_y1 + (size_t)t * HC);
    }
    copy_kernel<<<128, 256, 0, stream>>>(buf_hA, out_hn + HC, HC);
    copy_kernel<<<128, 256, 0, stream>>>(buf_c, out_cn + HC, HC);

    // 6. Attention (fp32, feeds exact ctx output)
    gemm_bt<<<dim3(512 / 64, 2048 / 128), 256, 0, stream>>>(
        buf_y1, aw1, ab1, nullptr, buf_hidden1, 2048, 512, 1024, 2 /*tanh*/);
    attn_p_kernel<<<2048, 64, 0, stream>>>(buf_hidden1, aw2, ab2, lens, buf_p, buf_win);
    sel_gather_kernel<<<2048, 256, 0, stream>>>(enc, buf_win, buf_sel);
    attn_fused_kernel<<<2048, 128, 0, stream>>>(buf_y1, buf_sel, buf_p, buf_win, lens, out_ctx);

    // 7. fc1 (bf16 MFMA): relu(concat([ctx, y1]) @ fc1_w^T + fc1_b)
    concat_fin_kernel<<<4096, 256, 0, stream>>>(out_ctx, buf_y1, buf_fin);
    gemm_mfma_bt<<<dim3(1024 / 128, 2048 / 128), 256, 0, stream>>>(
        buf_fin, fc1w, fc1b, buf_fc1out, 2048, 1024, 2048, 1 /*relu*/);

    // 8. fc2 (bf16 MFMA): y = fc1out @ fc2_w^T + fc2_b
    gemm_mfma_bt<<<dim3(VOCAB / 128, 2048 / 128), 256, 0, stream>>>(
        buf_fc1out, fc2w, fc2b, out, 2048, VOCAB, 1024, 0);
}

// Round 3
// 3997.910 us; speedup vs baseline: 2.5487x; 2.5487x over previous
//
#include <hip/hip_runtime.h>
#include <hip/hip_bf16.h>

// Problem constants
#define T_STEPS 64
#define BATCH   32
#define HID     1024
#define VOCAB   32000
#define WLEN_   101
#define WSZ_    50
#define SENC    229
#define NBLK    128     // persistent LSTM grid size (co-resident on 256 CUs)

static const size_t Y_SZ   = (size_t)T_STEPS * BATCH * VOCAB;   // 65,536,000
static const size_t HN_SZ  = (size_t)2 * BATCH * HID;           // 65,536
static const size_t CTX_OFF = Y_SZ + 2 * HN_SZ;                 // y + h_n + c_n

typedef __attribute__((ext_vector_type(8)))  unsigned short us8;
typedef __attribute__((ext_vector_type(8)))  __bf16 bf16x8;
typedef __attribute__((ext_vector_type(4)))  float f32x4;
typedef __attribute__((ext_vector_type(16))) float f32x16;

static __device__ inline unsigned short f2bf(float x) {
    __hip_bfloat16 b = __float2bfloat16(x);
    return __builtin_bit_cast(unsigned short, b);
}

// ---------------------------------------------------------------------------
// fp32 GEMM (gates/attn-proj paths): out[M,N] = A[M,K] @ W[N,K]^T
// ---------------------------------------------------------------------------
__global__ __launch_bounds__(256) void gemm_bt(
    const float* __restrict__ A, const float* __restrict__ W,
    const float* __restrict__ b1, const float* __restrict__ b2,
    float* __restrict__ out, int M, int N, int K, int act)
{
    __shared__ __align__(16) float As[16 * 132];
    __shared__ __align__(16) float Ws[16 * 68];
    const int tid  = threadIdx.x;
    const int col0 = blockIdx.x * 64;
    const int row0 = blockIdx.y * 128;
    const int ty   = tid >> 4;
    const int tx   = tid & 15;

    float acc[8][4];
#pragma unroll
    for (int i = 0; i < 8; ++i)
#pragma unroll
        for (int j = 0; j < 4; ++j) acc[i][j] = 0.f;

    for (int k0 = 0; k0 < K; k0 += 16) {
#pragma unroll
        for (int li = 0; li < 2; ++li) {
            int f  = tid + li * 256;
            int r  = f >> 2;
            int kq = (f & 3) << 2;
            float4 v = *reinterpret_cast<const float4*>(A + (size_t)(row0 + r) * K + k0 + kq);
            As[(kq + 0) * 132 + r] = v.x;
            As[(kq + 1) * 132 + r] = v.y;
            As[(kq + 2) * 132 + r] = v.z;
            As[(kq + 3) * 132 + r] = v.w;
        }
        {
            int n  = tid >> 2;
            int kq = (tid & 3) << 2;
            float4 v = *reinterpret_cast<const float4*>(W + (size_t)(col0 + n) * K + k0 + kq);
            Ws[(kq + 0) * 68 + n] = v.x;
            Ws[(kq + 1) * 68 + n] = v.y;
            Ws[(kq + 2) * 68 + n] = v.z;
            Ws[(kq + 3) * 68 + n] = v.w;
        }
        __syncthreads();
#pragma unroll
        for (int k = 0; k < 16; ++k) {
            const float4 a0 = *reinterpret_cast<const float4*>(&As[k * 132 + ty * 8]);
            const float4 a1 = *reinterpret_cast<const float4*>(&As[k * 132 + ty * 8 + 4]);
            const float4 b0 = *reinterpret_cast<const float4*>(&Ws[k * 68 + tx * 4]);
            float av[8] = {a0.x, a0.y, a0.z, a0.w, a1.x, a1.y, a1.z, a1.w};
            float bv[4] = {b0.x, b0.y, b0.z, b0.w};
#pragma unroll
            for (int i = 0; i < 8; ++i)
#pragma unroll
                for (int j = 0; j < 4; ++j) acc[i][j] = fmaf(av[i], bv[j], acc[i][j]);
        }
        __syncthreads();
    }

#pragma unroll
    for (int j = 0; j < 4; ++j) {
        int n = col0 + tx * 4 + j;
        float bias = 0.f;
        if (b1) bias += b1[n];
        if (b2) bias += b2[n];
#pragma unroll
        for (int i = 0; i < 8; ++i) {
            float v = acc[i][j] + bias;
            if (act == 1) v = fmaxf(v, 0.f);
            else if (act == 2) v = tanhf(v);
            out[(size_t)(row0 + ty * 8 + i) * N + n] = v;
        }
    }
}

// ---------------------------------------------------------------------------
// bf16 MFMA GEMM (fc1/fc2): out[M,N] = A[M,K] @ W[N,K]^T + bias, optional relu.
// ---------------------------------------------------------------------------
__global__ __launch_bounds__(256) void gemm_mfma_bt(
    const float* __restrict__ A, const float* __restrict__ W,
    const float* __restrict__ bias, float* __restrict__ out,
    int M, int N, int K, int relu)
{
    __shared__ __align__(16) unsigned short As[4096];
    __shared__ __align__(16) unsigned short Bs[4096];
    const int tid  = threadIdx.x;
    const int lane = tid & 63;
    const int wave = tid >> 6;
    const int row0 = blockIdx.y * 128;
    const int col0 = blockIdx.x * 128;
    const int m0 = (wave >> 1) * 64;
    const int n0 = (wave & 1) * 64;
    const int lrow = lane & 15;
    const int kc   = lane >> 4;

    const int srow = tid >> 1;
    const int skh  = tid & 1;

    f32x4 acc[4][4];
#pragma unroll
    for (int i = 0; i < 4; ++i)
#pragma unroll
        for (int j = 0; j < 4; ++j) acc[i][j] = (f32x4){0.f, 0.f, 0.f, 0.f};

    const float* gA = A + (size_t)(row0 + srow) * K + skh * 16;
    const float* gW = W + (size_t)(col0 + srow) * K + skh * 16;

    for (int k0 = 0; k0 < K; k0 += 32) {
        {
            float4 v0 = *reinterpret_cast<const float4*>(gA + k0);
            float4 v1 = *reinterpret_cast<const float4*>(gA + k0 + 4);
            float4 v2 = *reinterpret_cast<const float4*>(gA + k0 + 8);
            float4 v3 = *reinterpret_cast<const float4*>(gA + k0 + 12);
            us8 c0 = {f2bf(v0.x), f2bf(v0.y), f2bf(v0.z), f2bf(v0.w),
                      f2bf(v1.x), f2bf(v1.y), f2bf(v1.z), f2bf(v1.w)};
            us8 c1 = {f2bf(v2.x), f2bf(v2.y), f2bf(v2.z), f2bf(v2.w),
                      f2bf(v3.x), f2bf(v3.y), f2bf(v3.z), f2bf(v3.w)};
            *reinterpret_cast<us8*>(&As[((skh * 2 + 0) * 128 + srow) * 8]) = c0;
            *reinterpret_cast<us8*>(&As[((skh * 2 + 1) * 128 + srow) * 8]) = c1;
            float4 w0 = *reinterpret_cast<const float4*>(gW + k0);
            float4 w1 = *reinterpret_cast<const float4*>(gW + k0 + 4);
            float4 w2 = *reinterpret_cast<const float4*>(gW + k0 + 8);
            float4 w3 = *reinterpret_cast<const float4*>(gW + k0 + 12);
            us8 d0 = {f2bf(w0.x), f2bf(w0.y), f2bf(w0.z), f2bf(w0.w),
                      f2bf(w1.x), f2bf(w1.y), f2bf(w1.z), f2bf(w1.w)};
            us8 d1 = {f2bf(w2.x), f2bf(w2.y), f2bf(w2.z), f2bf(w2.w),
                      f2bf(w3.x), f2bf(w3.y), f2bf(w3.z), f2bf(w3.w)};
            *reinterpret_cast<us8*>(&Bs[((skh * 2 + 0) * 128 + srow) * 8]) = d0;
            *reinterpret_cast<us8*>(&Bs[((skh * 2 + 1) * 128 + srow) * 8]) = d1;
        }
        __syncthreads();
        us8 a[4], b[4];
#pragma unroll
        for (int f = 0; f < 4; ++f) {
            a[f] = *reinterpret_cast<const us8*>(&As[(kc * 128 + m0 + f * 16 + lrow) * 8]);
            b[f] = *reinterpret_cast<const us8*>(&Bs[(kc * 128 + n0 + f * 16 + lrow) * 8]);
        }
#pragma unroll
        for (int fi = 0; fi < 4; ++fi)
#pragma unroll
            for (int fj = 0; fj < 4; ++fj)
                acc[fi][fj] = __builtin_amdgcn_mfma_f32_16x16x32_bf16(
                    __builtin_bit_cast(bf16x8, a[fi]),
                    __builtin_bit_cast(bf16x8, b[fj]),
                    acc[fi][fj], 0, 0, 0);
        __syncthreads();
    }

#pragma unroll
    for (int fi = 0; fi < 4; ++fi)
#pragma unroll
        for (int fj = 0; fj < 4; ++fj) {
            int cN = col0 + n0 + fj * 16 + lrow;
            float bv = bias ? bias[cN] : 0.f;
#pragma unroll
            for (int j = 0; j < 4; ++j) {
                int r = row0 + m0 + fi * 16 + (lane >> 4) * 4 + j;
                float v = acc[fi][fj][j] + bv;
                if (relu) v = fmaxf(v, 0.f);
                out[(size_t)r * N + cN] = v;
            }
        }
}

// ---------------------------------------------------------------------------
// Embedding lookup + input-feeding concat
// ---------------------------------------------------------------------------
__global__ void embed_concat_kernel(const float* __restrict__ emb,
                                    const float* __restrict__ ctxin,
                                    const int* __restrict__ tw,
                                    float* __restrict__ x)
{
    const size_t total = (size_t)2048 * 2048;
    for (size_t idx = (size_t)blockIdx.x * blockDim.x + threadIdx.x; idx < total;
         idx += (size_t)gridDim.x * blockDim.x) {
        int h = (int)(idx & 2047);
        size_t row = idx >> 11;
        float v;
        if (h < HID) v = emb[(size_t)tw[row] * HID + h];
        else         v = ctxin[row * HID + (h - HID)];
        x[idx] = v;
    }
}

__global__ void zero_bar_kernel(int* p)
{
    if (threadIdx.x < 2) p[threadIdx.x] = 0;
}

// ---------------------------------------------------------------------------
// Persistent LSTM layer: one launch runs all 64 steps.
// Grid: 128 blocks x 256 threads (4 waves). Block owns 8 hidden columns
// j0..j0+7 => 32 gate rows of Whh (order n = g*8+jj). Whh slice packed ONCE
// into LDS as bf16 MFMA B-fragments in lane-linear order (conflict-free
// ds_read_b128). Per step: A = h (bf16, double-buffered global), 4 waves
// split K=1024 -> 16 x mfma_f32_32x32x16_bf16 each, LDS reduce (stride 132),
// fp32 gpre + elementwise, c in LDS. Grid-wide sync: device-scope atomic
// spin barrier (counter pre-zeroed per call; 128 blocks always co-resident).
// ---------------------------------------------------------------------------
__global__ __launch_bounds__(256) void lstm_persist(
    const float* __restrict__ gpre,   // [64*32, 4096]
    const float* __restrict__ Whh,    // [4096, 1024]
    const float* __restrict__ h0l,    // [32,1024] this layer's h0
    const float* __restrict__ c0l,    // [32,1024] this layer's c0
    float* __restrict__ y_out,        // [64][32][1024]
    float* __restrict__ hn,           // [32,1024]
    float* __restrict__ cn,           // [32,1024]
    unsigned short* __restrict__ hbf, // [2][32*1024] bf16 ping-pong
    int* __restrict__ bar)            // barrier counter (zeroed)
{
    __shared__ __align__(16) us8 Bfrag[4096];      // 64 KB: [wave][frag][lane]
    __shared__ float red2[32 * 132];               // 16.9 KB: [m][w*32+n]
    __shared__ float csh[256];                     // c state [b*8+jj]

    const int tid  = threadIdx.x;
    const int lane = tid & 63;
    const int w    = tid >> 6;        // wave 0..3 (K-slice)
    const int n    = lane & 31;       // local gate-row / batch row
    const int kh   = lane >> 5;       // k-half within frag
    const int j0   = blockIdx.x * 8;
    const int b    = tid >> 3;        // elementwise batch
    const int jj   = tid & 7;         // elementwise column

    // ---- setup: pack B fragments (Whh -> bf16, lane-linear) ----
    {
        const int grow = (n >> 3) * HID + j0 + (n & 7);   // g*1024 + j
        const float* wrow = Whh + (size_t)grow * HID;
#pragma unroll
        for (int f = 0; f < 16; ++f) {
            int k = w * 256 + f * 16 + kh * 8;
            float4 v0 = *reinterpret_cast<const float4*>(wrow + k);
            float4 v1 = *reinterpret_cast<const float4*>(wrow + k + 4);
            us8 c = {f2bf(v0.x), f2bf(v0.y), f2bf(v0.z), f2bf(v0.w),
                     f2bf(v1.x), f2bf(v1.y), f2bf(v1.z), f2bf(v1.w)};
            Bfrag[w * 1024 + f * 64 + lane] = c;
        }
    }
    // ---- c init + h0 -> hbf[0] (cooperative) ----
    csh[tid] = c0l[b * HID + j0 + jj];
    {
        int idx = blockIdx.x * 256 + tid;   // covers 128*256 = 32768
        hbf[idx] = f2bf(h0l[idx]);
    }
    // ---- init barrier ----
    __threadfence();
    __syncthreads();
    if (tid == 0) {
        __hip_atomic_fetch_add(bar, 1, __ATOMIC_ACQ_REL, __HIP_MEMORY_SCOPE_AGENT);
        while (__hip_atomic_load(bar, __ATOMIC_ACQUIRE, __HIP_MEMORY_SCOPE_AGENT) < NBLK)
            __builtin_amdgcn_s_sleep(1);
    }
    __syncthreads();

    for (int t = 0; t < T_STEPS; ++t) {
        const unsigned short* hin = hbf + (t & 1) * 32768;
        unsigned short* hout      = hbf + ((t + 1) & 1) * 32768;

        // gpre prefetch (fp32, issue early)
        const float* gp = gpre + (size_t)(t * BATCH + b) * 4096 + j0 + jj;
        float gp0 = gp[0], gp1 = gp[1024], gp2 = gp[2048], gp3 = gp[3072];

        // A fragments: lane n = batch row, this wave's K slice
        const unsigned short* hrow = hin + n * HID + w * 256 + kh * 8;
        us8 aF[16];
#pragma unroll
        for (int f = 0; f < 16; ++f)
            aF[f] = *reinterpret_cast<const us8*>(hrow + f * 16);

        f32x16 acc = {};
#pragma unroll
        for (int f = 0; f < 16; ++f)
            acc = __builtin_amdgcn_mfma_f32_32x32x16_bf16(
                __builtin_bit_cast(bf16x8, aF[f]),
                __builtin_bit_cast(bf16x8, Bfrag[w * 1024 + f * 64 + lane]),
                acc, 0, 0, 0);

        // partial C -> LDS (D layout: col=lane&31, row=(r&3)+8*(r>>2)+4*(lane>>5))
#pragma unroll
        for (int r = 0; r < 16; ++r) {
            int m = (r & 3) + 8 * (r >> 2) + 4 * kh;
            red2[m * 132 + w * 32 + n] = acc[r];
        }
        __syncthreads();

        // reduce 4 waves + elementwise for (b, jj)
        float s0 = gp0, s1 = gp1, s2 = gp2, s3 = gp3;
#pragma unroll
        for (int w2 = 0; w2 < 4; ++w2) {
            const float* rr = &red2[b * 132 + w2 * 32 + jj];
            s0 += rr[0];
            s1 += rr[8];
            s2 += rr[16];
            s3 += rr[24];
        }
        float ig = 1.f / (1.f + expf(-s0));
        float fg = 1.f / (1.f + expf(-s1));
        float gg = tanhf(s2);
        float og = 1.f / (1.f + expf(-s3));
        float cv = fg * csh[tid] + ig * gg;
        csh[tid] = cv;
        float h = og * tanhf(cv);
        int gj = j0 + jj;
        y_out[(size_t)t * (BATCH * HID) + b * HID + gj] = h;
        if (t == T_STEPS - 1) {
            hn[b * HID + gj] = h;
            cn[b * HID + gj] = cv;
        } else {
            hout[b * HID + gj] = f2bf(h);
            // grid barrier before next step reads hout
            __threadfence();
            __syncthreads();
            if (tid == 0) {
                __hip_atomic_fetch_add(bar, 1, __ATOMIC_ACQ_REL, __HIP_MEMORY_SCOPE_AGENT);
                int target = NBLK * (t + 2);
                while (__hip_atomic_load(bar, __ATOMIC_ACQUIRE, __HIP_MEMORY_SCOPE_AGENT) < target)
                    __builtin_amdgcn_s_sleep(1);
            }
            __syncthreads();
        }
    }
}

// ---------------------------------------------------------------------------
// Attention p
// ---------------------------------------------------------------------------
__global__ __launch_bounds__(64) void attn_p_kernel(
    const float* __restrict__ hidden1, const float* __restrict__ aw2,
    const float* __restrict__ ab2, const int* __restrict__ lengths,
    float* __restrict__ p_arr, int* __restrict__ win_arr)
{
    const int row = blockIdx.x;
    const int lane = threadIdx.x;
    float s = 0.f;
    for (int i = lane; i < 512; i += 64) s += hidden1[(size_t)row * 512 + i] * aw2[i];
    for (int off = 32; off > 0; off >>= 1) s += __shfl_down(s, off);
    if (lane == 0) {
        float v = s + ab2[0];
        float sig = 1.f / (1.f + expf(-v));
        int b = row & 31;
        float lf = (float)lengths[b];
        p_arr[row] = (float)WSZ_ + lf * sig;
        win_arr[row] = (int)rintf(lf * sig);
    }
}

__global__ void sel_gather_kernel(const float* __restrict__ enc,
                                  const int* __restrict__ win_arr,
                                  float* __restrict__ sel)
{
    const int total = BATCH * WLEN_ * HID;
    for (int idx = blockIdx.x * blockDim.x + threadIdx.x; idx < total;
         idx += gridDim.x * blockDim.x) {
        int h = idx & 1023;
        int w = (idx >> 10) % WLEN_;
        int b = idx / (WLEN_ * HID);
        int s = win_arr[(T_STEPS - 1) * BATCH + b] + w;
        sel[idx] = enc[((size_t)s * BATCH + b) * HID + h];
    }
}

__global__ __launch_bounds__(128) void attn_fused_kernel(
    const float* __restrict__ y1, const float* __restrict__ sel,
    const float* __restrict__ p_arr, const int* __restrict__ win_arr,
    const int* __restrict__ lengths, float* __restrict__ ctx)
{
    __shared__ __align__(16) float yl[1024];
    __shared__ float sv[WLEN_];
    __shared__ float av[WLEN_];
    const int row = blockIdx.x;
    const int b   = row & 31;
    const int tid = threadIdx.x;

    for (int i = tid; i < 1024; i += 128) yl[i] = y1[(size_t)row * HID + i];
    __syncthreads();

    const int win = win_arr[row];
    const float p = p_arr[row];
    const int len = lengths[b];

    if (tid < WLEN_) {
        const float4* s4 = reinterpret_cast<const float4*>(sel + ((size_t)b * WLEN_ + tid) * HID);
        const float4* y4 = reinterpret_cast<const float4*>(yl);
        float acc = 0.f;
        for (int q = 0; q < 256; ++q) {
            float4 a = s4[q]; float4 yy = y4[q];
            acc += a.x * yy.x + a.y * yy.y + a.z * yy.z + a.w * yy.w;
        }
        bool lo = tid < (WSZ_ - win);
        bool hi = tid >= (len + WSZ_ - win);
        sv[tid] = (lo || hi) ? 1e-14f : acc;
    }
    __syncthreads();

    float mx = -1e30f;
    for (int w = 0; w < WLEN_; ++w) mx = fmaxf(mx, sv[w]);
    float sum = 0.f;
    for (int w = 0; w < WLEN_; ++w) sum += expf(sv[w] - mx);
    if (tid < WLEN_) {
        float e = expf(sv[tid] - mx) / sum;
        float d = (float)(win + tid) - p;
        av[tid] = e * expf(-(d * d) / 1250.f);
    }
    __syncthreads();

    float acc[8] = {0, 0, 0, 0, 0, 0, 0, 0};
    for (int w = 0; w < WLEN_; ++w) {
        float a = av[w];
        const float* srow = sel + ((size_t)b * WLEN_ + w) * HID;
#pragma unroll
        for (int i = 0; i < 8; ++i) acc[i] += a * srow[tid + 128 * i];
    }
    for (int i = 0; i < 8; ++i) ctx[(size_t)row * HID + tid + 128 * i] = acc[i];
}

__global__ void concat_fin_kernel(const float* __restrict__ ctx,
                                  const float* __restrict__ y1,
                                  float* __restrict__ fin)
{
    const size_t total = (size_t)2048 * 2048;
    for (size_t idx = (size_t)blockIdx.x * blockDim.x + threadIdx.x; idx < total;
         idx += (size_t)gridDim.x * blockDim.x) {
        int h = (int)(idx & 2047);
        size_t row = idx >> 11;
        fin[idx] = (h < HID) ? ctx[row * HID + h] : y1[row * HID + (h - HID)];
    }
}

// ---------------------------------------------------------------------------
extern "C" void kernel_launch(void* const* d_in, const int* in_sizes, int n_in,
                              void* d_out, int out_size, void* d_ws, size_t ws_size,
                              hipStream_t stream)
{
    const float* enc   = (const float*)d_in[0];
    const float* ctxin = (const float*)d_in[1];
    const float* h0    = (const float*)d_in[2];
    const float* c0    = (const float*)d_in[3];
    const float* emb   = (const float*)d_in[4];
    const float* aw1   = (const float*)d_in[5];
    const float* ab1   = (const float*)d_in[6];
    const float* aw2   = (const float*)d_in[7];
    const float* ab2   = (const float*)d_in[8];
    const float* Wih0  = (const float*)d_in[9];
    const float* Whh0  = (const float*)d_in[10];
    const float* bih0  = (const float*)d_in[11];
    const float* bhh0  = (const float*)d_in[12];
    const float* Wih1  = (const float*)d_in[13];
    const float* Whh1  = (const float*)d_in[14];
    const float* bih1  = (const float*)d_in[15];
    const float* bhh1  = (const float*)d_in[16];
    const float* fc1w  = (const float*)d_in[17];
    const float* fc1b  = (const float*)d_in[18];
    const float* fc2w  = (const float*)d_in[19];
    const float* fc2b  = (const float*)d_in[20];
    const int*   tw    = (const int*)d_in[21];
    const int*   lens  = (const int*)d_in[22];

    float* ws = (float*)d_ws;
    float* buf_x       = ws;                         // x; later fc1out
    float* buf_gates   = ws + 4194304;               // gates; later fin
    float* buf_y0      = ws + 12582912;
    float* buf_y1      = ws + 14680064;
    unsigned short* buf_hbf = (unsigned short*)(ws + 16777216);  // 2x32768 bf16 = 128KB
    int*   buf_bar     = (int*)(ws + 16809984);      // 2 ints
    float* buf_hidden1 = ws + 16875520;
    float* buf_p       = ws + 17924096;
    int*   buf_win     = (int*)(ws + 17926144);
    float* buf_sel     = ws + 17928192;
    float* buf_fin     = buf_gates;
    float* buf_fc1out  = buf_x;

    float* out   = (float*)d_out;
    float* out_hn  = out + Y_SZ;
    float* out_cn  = out + Y_SZ + HN_SZ;
    float* out_ctx = out + CTX_OFF;

    const int HC = BATCH * HID;

    // 1. x = [embedding[tw], context]
    embed_concat_kernel<<<4096, 256, 0, stream>>>(emb, ctxin, tw, buf_x);

    // 2. gates0_pre = x @ Wih0^T + bih0 + bhh0   (fp32)
    gemm_bt<<<dim3(4096 / 64, 2048 / 128), 256, 0, stream>>>(
        buf_x, Wih0, bih0, bhh0, buf_gates, 2048, 4096, 2048, 0);

    // 3. LSTM layer 0 (persistent)
    zero_bar_kernel<<<1, 64, 0, stream>>>(buf_bar);
    lstm_persist<<<NBLK, 256, 0, stream>>>(
        buf_gates, Whh0, h0, c0, buf_y0, out_hn, out_cn, buf_hbf, buf_bar);

    // 4. gates1_pre = y0 @ Wih1^T + bih1 + bhh1
    gemm_bt<<<dim3(4096 / 64, 2048 / 128), 256, 0, stream>>>(
        buf_y0, Wih1, bih1, bhh1, buf_gates, 2048, 4096, 1024, 0);

    // 5. LSTM layer 1 (persistent)
    lstm_persist<<<NBLK, 256, 0, stream>>>(
        buf_gates, Whh1, h0 + HC, c0 + HC, buf_y1, out_hn + HC, out_cn + HC,
        buf_hbf, buf_bar + 1);

    // 6. Attention (fp32)
    gemm_bt<<<dim3(512 / 64, 2048 / 128), 256, 0, stream>>>(
        buf_y1, aw1, ab1, nullptr, buf_hidden1, 2048, 512, 1024, 2 /*tanh*/);
    attn_p_kernel<<<2048, 64, 0, stream>>>(buf_hidden1, aw2, ab2, lens, buf_p, buf_win);
    sel_gather_kernel<<<2048, 256, 0, stream>>>(enc, buf_win, buf_sel);
    attn_fused_kernel<<<2048, 128, 0, stream>>>(buf_y1, buf_sel, buf_p, buf_win, lens, out_ctx);

    // 7. fc1 (bf16 MFMA)
    concat_fin_kernel<<<4096, 256, 0, stream>>>(out_ctx, buf_y1, buf_fin);
    gemm_mfma_bt<<<dim3(1024 / 128, 2048 / 128), 256, 0, stream>>>(
        buf_fin, fc1w, fc1b, buf_fc1out, 2048, 1024, 2048, 1 /*relu*/);

    // 8. fc2 (bf16 MFMA)
    gemm_mfma_bt<<<dim3(VOCAB / 128, 2048 / 128), 256, 0, stream>>>(
        buf_fc1out, fc2w, fc2b, out, 2048, VOCAB, 1024, 0);
}

// Round 4
// 1949.498 us; speedup vs baseline: 5.2267x; 2.0507x over previous
//
#include <hip/hip_runtime.h>
#include <hip/hip_bf16.h>

// Problem constants
#define T_STEPS 64
#define BATCH   32
#define HID     1024
#define VOCAB   32000
#define WLEN_   101
#define WSZ_    50
#define SENC    229
#define NBLK    128     // persistent LSTM grid size (co-resident on 256 CUs)

static const size_t Y_SZ   = (size_t)T_STEPS * BATCH * VOCAB;   // 65,536,000
static const size_t HN_SZ  = (size_t)2 * BATCH * HID;           // 65,536
static const size_t CTX_OFF = Y_SZ + 2 * HN_SZ;                 // y + h_n + c_n

typedef __attribute__((ext_vector_type(8)))  unsigned short us8;
typedef __attribute__((ext_vector_type(8)))  __bf16 bf16x8;
typedef __attribute__((ext_vector_type(4)))  float f32x4;
typedef __attribute__((ext_vector_type(16))) float f32x16;

static __device__ inline unsigned short f2bf(float x) {
    __hip_bfloat16 b = __float2bfloat16(x);
    return __builtin_bit_cast(unsigned short, b);
}

// ---------------------------------------------------------------------------
// fp32 GEMM (attn-proj path only): out[M,N] = A[M,K] @ W[N,K]^T
// ---------------------------------------------------------------------------
__global__ __launch_bounds__(256) void gemm_bt(
    const float* __restrict__ A, const float* __restrict__ W,
    const float* __restrict__ b1, const float* __restrict__ b2,
    float* __restrict__ out, int M, int N, int K, int act)
{
    __shared__ __align__(16) float As[16 * 132];
    __shared__ __align__(16) float Ws[16 * 68];
    const int tid  = threadIdx.x;
    const int col0 = blockIdx.x * 64;
    const int row0 = blockIdx.y * 128;
    const int ty   = tid >> 4;
    const int tx   = tid & 15;

    float acc[8][4];
#pragma unroll
    for (int i = 0; i < 8; ++i)
#pragma unroll
        for (int j = 0; j < 4; ++j) acc[i][j] = 0.f;

    for (int k0 = 0; k0 < K; k0 += 16) {
#pragma unroll
        for (int li = 0; li < 2; ++li) {
            int f  = tid + li * 256;
            int r  = f >> 2;
            int kq = (f & 3) << 2;
            float4 v = *reinterpret_cast<const float4*>(A + (size_t)(row0 + r) * K + k0 + kq);
            As[(kq + 0) * 132 + r] = v.x;
            As[(kq + 1) * 132 + r] = v.y;
            As[(kq + 2) * 132 + r] = v.z;
            As[(kq + 3) * 132 + r] = v.w;
        }
        {
            int n  = tid >> 2;
            int kq = (tid & 3) << 2;
            float4 v = *reinterpret_cast<const float4*>(W + (size_t)(col0 + n) * K + k0 + kq);
            Ws[(kq + 0) * 68 + n] = v.x;
            Ws[(kq + 1) * 68 + n] = v.y;
            Ws[(kq + 2) * 68 + n] = v.z;
            Ws[(kq + 3) * 68 + n] = v.w;
        }
        __syncthreads();
#pragma unroll
        for (int k = 0; k < 16; ++k) {
            const float4 a0 = *reinterpret_cast<const float4*>(&As[k * 132 + ty * 8]);
            const float4 a1 = *reinterpret_cast<const float4*>(&As[k * 132 + ty * 8 + 4]);
            const float4 b0 = *reinterpret_cast<const float4*>(&Ws[k * 68 + tx * 4]);
            float av[8] = {a0.x, a0.y, a0.z, a0.w, a1.x, a1.y, a1.z, a1.w};
            float bv[4] = {b0.x, b0.y, b0.z, b0.w};
#pragma unroll
            for (int i = 0; i < 8; ++i)
#pragma unroll
                for (int j = 0; j < 4; ++j) acc[i][j] = fmaf(av[i], bv[j], acc[i][j]);
        }
        __syncthreads();
    }

#pragma unroll
    for (int j = 0; j < 4; ++j) {
        int n = col0 + tx * 4 + j;
        float bias = 0.f;
        if (b1) bias += b1[n];
        if (b2) bias += b2[n];
#pragma unroll
        for (int i = 0; i < 8; ++i) {
            float v = acc[i][j] + bias;
            if (act == 1) v = fmaxf(v, 0.f);
            else if (act == 2) v = tanhf(v);
            out[(size_t)(row0 + ty * 8 + i) * N + n] = v;
        }
    }
}

// ---------------------------------------------------------------------------
// bf16 MFMA GEMM (gates/fc1/fc2): out[M,N] = A[M,K] @ W[N,K]^T + b1 + b2.
// Tile 128x128, BK=32, 4 waves, 4x4 frags of mfma_f32_16x16x32_bf16.
// ---------------------------------------------------------------------------
__global__ __launch_bounds__(256) void gemm_mfma_bt(
    const float* __restrict__ A, const float* __restrict__ W,
    const float* __restrict__ b1, const float* __restrict__ b2,
    float* __restrict__ out, int M, int N, int K, int relu)
{
    __shared__ __align__(16) unsigned short As[4096];
    __shared__ __align__(16) unsigned short Bs[4096];
    const int tid  = threadIdx.x;
    const int lane = tid & 63;
    const int wave = tid >> 6;
    const int row0 = blockIdx.y * 128;
    const int col0 = blockIdx.x * 128;
    const int m0 = (wave >> 1) * 64;
    const int n0 = (wave & 1) * 64;
    const int lrow = lane & 15;
    const int kc   = lane >> 4;

    const int srow = tid >> 1;
    const int skh  = tid & 1;

    f32x4 acc[4][4];
#pragma unroll
    for (int i = 0; i < 4; ++i)
#pragma unroll
        for (int j = 0; j < 4; ++j) acc[i][j] = (f32x4){0.f, 0.f, 0.f, 0.f};

    const float* gA = A + (size_t)(row0 + srow) * K + skh * 16;
    const float* gW = W + (size_t)(col0 + srow) * K + skh * 16;

    for (int k0 = 0; k0 < K; k0 += 32) {
        {
            float4 v0 = *reinterpret_cast<const float4*>(gA + k0);
            float4 v1 = *reinterpret_cast<const float4*>(gA + k0 + 4);
            float4 v2 = *reinterpret_cast<const float4*>(gA + k0 + 8);
            float4 v3 = *reinterpret_cast<const float4*>(gA + k0 + 12);
            us8 c0 = {f2bf(v0.x), f2bf(v0.y), f2bf(v0.z), f2bf(v0.w),
                      f2bf(v1.x), f2bf(v1.y), f2bf(v1.z), f2bf(v1.w)};
            us8 c1 = {f2bf(v2.x), f2bf(v2.y), f2bf(v2.z), f2bf(v2.w),
                      f2bf(v3.x), f2bf(v3.y), f2bf(v3.z), f2bf(v3.w)};
            *reinterpret_cast<us8*>(&As[((skh * 2 + 0) * 128 + srow) * 8]) = c0;
            *reinterpret_cast<us8*>(&As[((skh * 2 + 1) * 128 + srow) * 8]) = c1;
            float4 w0 = *reinterpret_cast<const float4*>(gW + k0);
            float4 w1 = *reinterpret_cast<const float4*>(gW + k0 + 4);
            float4 w2 = *reinterpret_cast<const float4*>(gW + k0 + 8);
            float4 w3 = *reinterpret_cast<const float4*>(gW + k0 + 12);
            us8 d0 = {f2bf(w0.x), f2bf(w0.y), f2bf(w0.z), f2bf(w0.w),
                      f2bf(w1.x), f2bf(w1.y), f2bf(w1.z), f2bf(w1.w)};
            us8 d1 = {f2bf(w2.x), f2bf(w2.y), f2bf(w2.z), f2bf(w2.w),
                      f2bf(w3.x), f2bf(w3.y), f2bf(w3.z), f2bf(w3.w)};
            *reinterpret_cast<us8*>(&Bs[((skh * 2 + 0) * 128 + srow) * 8]) = d0;
            *reinterpret_cast<us8*>(&Bs[((skh * 2 + 1) * 128 + srow) * 8]) = d1;
        }
        __syncthreads();
        us8 a[4], b[4];
#pragma unroll
        for (int f = 0; f < 4; ++f) {
            a[f] = *reinterpret_cast<const us8*>(&As[(kc * 128 + m0 + f * 16 + lrow) * 8]);
            b[f] = *reinterpret_cast<const us8*>(&Bs[(kc * 128 + n0 + f * 16 + lrow) * 8]);
        }
#pragma unroll
        for (int fi = 0; fi < 4; ++fi)
#pragma unroll
            for (int fj = 0; fj < 4; ++fj)
                acc[fi][fj] = __builtin_amdgcn_mfma_f32_16x16x32_bf16(
                    __builtin_bit_cast(bf16x8, a[fi]),
                    __builtin_bit_cast(bf16x8, b[fj]),
                    acc[fi][fj], 0, 0, 0);
        __syncthreads();
    }

#pragma unroll
    for (int fi = 0; fi < 4; ++fi)
#pragma unroll
        for (int fj = 0; fj < 4; ++fj) {
            int cN = col0 + n0 + fj * 16 + lrow;
            float bv = 0.f;
            if (b1) bv += b1[cN];
            if (b2) bv += b2[cN];
#pragma unroll
            for (int j = 0; j < 4; ++j) {
                int r = row0 + m0 + fi * 16 + (lane >> 4) * 4 + j;
                float v = acc[fi][fj][j] + bv;
                if (relu) v = fmaxf(v, 0.f);
                out[(size_t)r * N + cN] = v;
            }
        }
}

// ---------------------------------------------------------------------------
// Embedding lookup + input-feeding concat
// ---------------------------------------------------------------------------
__global__ void embed_concat_kernel(const float* __restrict__ emb,
                                    const float* __restrict__ ctxin,
                                    const int* __restrict__ tw,
                                    float* __restrict__ x)
{
    const size_t total = (size_t)2048 * 2048;
    for (size_t idx = (size_t)blockIdx.x * blockDim.x + threadIdx.x; idx < total;
         idx += (size_t)gridDim.x * blockDim.x) {
        int h = (int)(idx & 2047);
        size_t row = idx >> 11;
        float v;
        if (h < HID) v = emb[(size_t)tw[row] * HID + h];
        else         v = ctxin[row * HID + (h - HID)];
        x[idx] = v;
    }
}

__global__ void zero_flags_kernel(int* p, int n)
{
    int i = blockIdx.x * blockDim.x + threadIdx.x;
    if (i < n) p[i] = 0;
}

// ---------------------------------------------------------------------------
// Distributed-flag grid barrier helpers (no hot-counter contention).
// flags[i*32] holds block i's phase; 128-B spacing avoids false sharing.
// ---------------------------------------------------------------------------
static __device__ inline void grid_arrive(int* __restrict__ flags, int phase, int tid)
{
    // callers must __syncthreads() first (drains this block's stores to L2)
    if (tid == 0) {
        __builtin_amdgcn_fence(__ATOMIC_RELEASE, "agent");   // writeback L2
        __hip_atomic_store(&flags[blockIdx.x * 32], phase,
                           __ATOMIC_RELAXED, __HIP_MEMORY_SCOPE_AGENT);
    }
}

static __device__ inline void grid_wait(int* __restrict__ flags, int phase, int tid)
{
    if (tid < 64) {
        const int i1 = tid * 32, i2 = (tid + 64) * 32;
        for (;;) {
            int f1 = __hip_atomic_load(&flags[i1], __ATOMIC_RELAXED, __HIP_MEMORY_SCOPE_AGENT);
            int f2 = __hip_atomic_load(&flags[i2], __ATOMIC_RELAXED, __HIP_MEMORY_SCOPE_AGENT);
            if (__all(f1 >= phase && f2 >= phase)) break;
            __builtin_amdgcn_s_sleep(2);
        }
        __builtin_amdgcn_fence(__ATOMIC_ACQUIRE, "agent");   // invalidate caches
    }
    __syncthreads();
}

// ---------------------------------------------------------------------------
// Persistent LSTM layer: one launch runs all 64 steps.
// 128 blocks x 256 threads. Block owns 8 hidden columns (32 gate rows).
// Whh slice packed once into LDS as bf16 MFMA B-fragments. Per step:
// A = h (bf16 ping-pong in global), 4-wave K-split, 16x mfma_32x32x16_bf16,
// LDS reduce, fp32 gpre + elementwise, c in LDS. Grid sync: flag barrier.
// ---------------------------------------------------------------------------
__global__ __launch_bounds__(256) void lstm_persist(
    const float* __restrict__ gpre,   // [64*32, 4096]
    const float* __restrict__ Whh,    // [4096, 1024]
    const float* __restrict__ h0l,    // [32,1024]
    const float* __restrict__ c0l,    // [32,1024]
    float* __restrict__ y_out,        // [64][32][1024]
    float* __restrict__ hn,           // [32,1024]
    float* __restrict__ cn,           // [32,1024]
    unsigned short* __restrict__ hbf, // [2][32*1024] bf16 ping-pong
    int* __restrict__ flags)          // [128*32] zeroed
{
    __shared__ __align__(16) us8 Bfrag[4096];      // 64 KB
    __shared__ float red2[32 * 132];               // 16.9 KB
    __shared__ float csh[256];

    const int tid  = threadIdx.x;
    const int lane = tid & 63;
    const int w    = tid >> 6;        // wave 0..3 (K-slice)
    const int n    = lane & 31;       // gate-row / batch row within wave
    const int kh   = lane >> 5;       // k-half within frag
    const int j0   = blockIdx.x * 8;
    const int b    = tid >> 3;        // elementwise batch
    const int jj   = tid & 7;         // elementwise column

    // ---- setup: pack B fragments (Whh -> bf16, lane-linear) ----
    {
        const int grow = (n >> 3) * HID + j0 + (n & 7);   // g*1024 + j
        const float* wrow = Whh + (size_t)grow * HID;
#pragma unroll
        for (int f = 0; f < 16; ++f) {
            int k = w * 256 + f * 16 + kh * 8;
            float4 v0 = *reinterpret_cast<const float4*>(wrow + k);
            float4 v1 = *reinterpret_cast<const float4*>(wrow + k + 4);
            us8 c = {f2bf(v0.x), f2bf(v0.y), f2bf(v0.z), f2bf(v0.w),
                     f2bf(v1.x), f2bf(v1.y), f2bf(v1.z), f2bf(v1.w)};
            Bfrag[w * 1024 + f * 64 + lane] = c;
        }
    }
    csh[tid] = c0l[b * HID + j0 + jj];
    {
        int idx = blockIdx.x * 256 + tid;   // covers 128*256 = 32768
        hbf[idx] = f2bf(h0l[idx]);
    }
    // prefetch gpre for t=0 (hides under init barrier)
    const float* gp0p = gpre + (size_t)b * 4096 + j0 + jj;
    float gp0 = gp0p[0], gp1 = gp0p[1024], gp2 = gp0p[2048], gp3 = gp0p[3072];

    __syncthreads();
    grid_arrive(flags, 1, tid);
    grid_wait(flags, 1, tid);

    for (int t = 0; t < T_STEPS; ++t) {
        const unsigned short* hin = hbf + (t & 1) * 32768;
        unsigned short* hout      = hbf + ((t + 1) & 1) * 32768;

        // A fragments: lane n = batch row, this wave's K slice
        const unsigned short* hrow = hin + n * HID + w * 256 + kh * 8;
        us8 aF[16];
#pragma unroll
        for (int f = 0; f < 16; ++f)
            aF[f] = *reinterpret_cast<const us8*>(hrow + f * 16);

        f32x16 acc = {};
#pragma unroll
        for (int f = 0; f < 16; ++f)
            acc = __builtin_amdgcn_mfma_f32_32x32x16_bf16(
                __builtin_bit_cast(bf16x8, aF[f]),
                __builtin_bit_cast(bf16x8, Bfrag[w * 1024 + f * 64 + lane]),
                acc, 0, 0, 0);

        // partial C -> LDS (D layout: col=lane&31, row=(r&3)+8*(r>>2)+4*(lane>>5))
#pragma unroll
        for (int r = 0; r < 16; ++r) {
            int m = (r & 3) + 8 * (r >> 2) + 4 * kh;
            red2[m * 132 + w * 32 + n] = acc[r];
        }
        __syncthreads();

        float s0 = gp0, s1 = gp1, s2 = gp2, s3 = gp3;
#pragma unroll
        for (int w2 = 0; w2 < 4; ++w2) {
            const float* rr = &red2[b * 132 + w2 * 32 + jj];
            s0 += rr[0];
            s1 += rr[8];
            s2 += rr[16];
            s3 += rr[24];
        }
        float ig = 1.f / (1.f + expf(-s0));
        float fg = 1.f / (1.f + expf(-s1));
        float gg = tanhf(s2);
        float og = 1.f / (1.f + expf(-s3));
        float cv = fg * csh[tid] + ig * gg;
        csh[tid] = cv;
        float h = og * tanhf(cv);
        int gj = j0 + jj;
        y_out[(size_t)t * (BATCH * HID) + b * HID + gj] = h;
        if (t == T_STEPS - 1) {
            hn[b * HID + gj] = h;
            cn[b * HID + gj] = cv;
        } else {
            hout[b * HID + gj] = f2bf(h);
            __syncthreads();                 // drain stores (incl. red2 reuse)
            grid_arrive(flags, t + 2, tid);
            // prefetch next gpre while spinning
            const float* gp = gpre + (size_t)((t + 1) * BATCH + b) * 4096 + j0 + jj;
            gp0 = gp[0]; gp1 = gp[1024]; gp2 = gp[2048]; gp3 = gp[3072];
            grid_wait(flags, t + 2, tid);
        }
    }
}

// ---------------------------------------------------------------------------
// Attention p
// ---------------------------------------------------------------------------
__global__ __launch_bounds__(64) void attn_p_kernel(
    const float* __restrict__ hidden1, const float* __restrict__ aw2,
    const float* __restrict__ ab2, const int* __restrict__ lengths,
    float* __restrict__ p_arr, int* __restrict__ win_arr)
{
    const int row = blockIdx.x;
    const int lane = threadIdx.x;
    float s = 0.f;
    for (int i = lane; i < 512; i += 64) s += hidden1[(size_t)row * 512 + i] * aw2[i];
    for (int off = 32; off > 0; off >>= 1) s += __shfl_down(s, off);
    if (lane == 0) {
        float v = s + ab2[0];
        float sig = 1.f / (1.f + expf(-v));
        int b = row & 31;
        float lf = (float)lengths[b];
        p_arr[row] = (float)WSZ_ + lf * sig;
        win_arr[row] = (int)rintf(lf * sig);
    }
}

__global__ void sel_gather_kernel(const float* __restrict__ enc,
                                  const int* __restrict__ win_arr,
                                  float* __restrict__ sel)
{
    const int total = BATCH * WLEN_ * HID;
    for (int idx = blockIdx.x * blockDim.x + threadIdx.x; idx < total;
         idx += gridDim.x * blockDim.x) {
        int h = idx & 1023;
        int w = (idx >> 10) % WLEN_;
        int b = idx / (WLEN_ * HID);
        int s = win_arr[(T_STEPS - 1) * BATCH + b] + w;
        sel[idx] = enc[((size_t)s * BATCH + b) * HID + h];
    }
}

__global__ __launch_bounds__(128) void attn_fused_kernel(
    const float* __restrict__ y1, const float* __restrict__ sel,
    const float* __restrict__ p_arr, const int* __restrict__ win_arr,
    const int* __restrict__ lengths, float* __restrict__ ctx)
{
    __shared__ __align__(16) float yl[1024];
    __shared__ float sv[WLEN_];
    __shared__ float av[WLEN_];
    const int row = blockIdx.x;
    const int b   = row & 31;
    const int tid = threadIdx.x;

    for (int i = tid; i < 1024; i += 128) yl[i] = y1[(size_t)row * HID + i];
    __syncthreads();

    const int win = win_arr[row];
    const float p = p_arr[row];
    const int len = lengths[b];

    if (tid < WLEN_) {
        const float4* s4 = reinterpret_cast<const float4*>(sel + ((size_t)b * WLEN_ + tid) * HID);
        const float4* y4 = reinterpret_cast<const float4*>(yl);
        float acc = 0.f;
        for (int q = 0; q < 256; ++q) {
            float4 a = s4[q]; float4 yy = y4[q];
            acc += a.x * yy.x + a.y * yy.y + a.z * yy.z + a.w * yy.w;
        }
        bool lo = tid < (WSZ_ - win);
        bool hi = tid >= (len + WSZ_ - win);
        sv[tid] = (lo || hi) ? 1e-14f : acc;
    }
    __syncthreads();

    float mx = -1e30f;
    for (int w = 0; w < WLEN_; ++w) mx = fmaxf(mx, sv[w]);
    float sum = 0.f;
    for (int w = 0; w < WLEN_; ++w) sum += expf(sv[w] - mx);
    if (tid < WLEN_) {
        float e = expf(sv[tid] - mx) / sum;
        float d = (float)(win + tid) - p;
        av[tid] = e * expf(-(d * d) / 1250.f);
    }
    __syncthreads();

    float acc[8] = {0, 0, 0, 0, 0, 0, 0, 0};
    for (int w = 0; w < WLEN_; ++w) {
        float a = av[w];
        const float* srow = sel + ((size_t)b * WLEN_ + w) * HID;
#pragma unroll
        for (int i = 0; i < 8; ++i) acc[i] += a * srow[tid + 128 * i];
    }
    for (int i = 0; i < 8; ++i) ctx[(size_t)row * HID + tid + 128 * i] = acc[i];
}

__global__ void concat_fin_kernel(const float* __restrict__ ctx,
                                  const float* __restrict__ y1,
                                  float* __restrict__ fin)
{
    const size_t total = (size_t)2048 * 2048;
    for (size_t idx = (size_t)blockIdx.x * blockDim.x + threadIdx.x; idx < total;
         idx += (size_t)gridDim.x * blockDim.x) {
        int h = (int)(idx & 2047);
        size_t row = idx >> 11;
        fin[idx] = (h < HID) ? ctx[row * HID + h] : y1[row * HID + (h - HID)];
    }
}

// ---------------------------------------------------------------------------
extern "C" void kernel_launch(void* const* d_in, const int* in_sizes, int n_in,
                              void* d_out, int out_size, void* d_ws, size_t ws_size,
                              hipStream_t stream)
{
    const float* enc   = (const float*)d_in[0];
    const float* ctxin = (const float*)d_in[1];
    const float* h0    = (const float*)d_in[2];
    const float* c0    = (const float*)d_in[3];
    const float* emb   = (const float*)d_in[4];
    const float* aw1   = (const float*)d_in[5];
    const float* ab1   = (const float*)d_in[6];
    const float* aw2   = (const float*)d_in[7];
    const float* ab2   = (const float*)d_in[8];
    const float* Wih0  = (const float*)d_in[9];
    const float* Whh0  = (const float*)d_in[10];
    const float* bih0  = (const float*)d_in[11];
    const float* bhh0  = (const float*)d_in[12];
    const float* Wih1  = (const float*)d_in[13];
    const float* Whh1  = (const float*)d_in[14];
    const float* bih1  = (const float*)d_in[15];
    const float* bhh1  = (const float*)d_in[16];
    const float* fc1w  = (const float*)d_in[17];
    const float* fc1b  = (const float*)d_in[18];
    const float* fc2w  = (const float*)d_in[19];
    const float* fc2b  = (const float*)d_in[20];
    const int*   tw    = (const int*)d_in[21];
    const int*   lens  = (const int*)d_in[22];

    float* ws = (float*)d_ws;
    float* buf_x       = ws;                         // x; later fc1out
    float* buf_gates   = ws + 4194304;               // gates; later fin
    float* buf_y0      = ws + 12582912;
    float* buf_y1      = ws + 14680064;
    unsigned short* buf_hbf = (unsigned short*)(ws + 16777216);  // 128 KB
    int*   buf_flags   = (int*)(ws + 16809984);      // 2 x 128 x 32 ints
    float* buf_hidden1 = ws + 16875520;
    float* buf_p       = ws + 17924096;
    int*   buf_win     = (int*)(ws + 17926144);
    float* buf_sel     = ws + 17928192;
    float* buf_fin     = buf_gates;
    float* buf_fc1out  = buf_x;

    float* out   = (float*)d_out;
    float* out_hn  = out + Y_SZ;
    float* out_cn  = out + Y_SZ + HN_SZ;
    float* out_ctx = out + CTX_OFF;

    const int HC = BATCH * HID;

    // 0. zero both barrier flag arrays (8192 ints)
    zero_flags_kernel<<<32, 256, 0, stream>>>(buf_flags, 8192);

    // 1. x = [embedding[tw], context]
    embed_concat_kernel<<<4096, 256, 0, stream>>>(emb, ctxin, tw, buf_x);

    // 2. gates0_pre = x @ Wih0^T + bih0 + bhh0   (bf16 MFMA)
    gemm_mfma_bt<<<dim3(4096 / 128, 2048 / 128), 256, 0, stream>>>(
        buf_x, Wih0, bih0, bhh0, buf_gates, 2048, 4096, 2048, 0);

    // 3. LSTM layer 0 (persistent, flag barrier)
    lstm_persist<<<NBLK, 256, 0, stream>>>(
        buf_gates, Whh0, h0, c0, buf_y0, out_hn, out_cn, buf_hbf, buf_flags);

    // 4. gates1_pre = y0 @ Wih1^T + bih1 + bhh1   (bf16 MFMA)
    gemm_mfma_bt<<<dim3(4096 / 128, 2048 / 128), 256, 0, stream>>>(
        buf_y0, Wih1, bih1, bhh1, buf_gates, 2048, 4096, 1024, 0);

    // 5. LSTM layer 1 (persistent)
    lstm_persist<<<NBLK, 256, 0, stream>>>(
        buf_gates, Whh1, h0 + HC, c0 + HC, buf_y1, out_hn + HC, out_cn + HC,
        buf_hbf, buf_flags + 128 * 32);

    // 6. Attention (fp32, exact window/p path)
    gemm_bt<<<dim3(512 / 64, 2048 / 128), 256, 0, stream>>>(
        buf_y1, aw1, ab1, nullptr, buf_hidden1, 2048, 512, 1024, 2 /*tanh*/);
    attn_p_kernel<<<2048, 64, 0, stream>>>(buf_hidden1, aw2, ab2, lens, buf_p, buf_win);
    sel_gather_kernel<<<2048, 256, 0, stream>>>(enc, buf_win, buf_sel);
    attn_fused_kernel<<<2048, 128, 0, stream>>>(buf_y1, buf_sel, buf_p, buf_win, lens, out_ctx);

    // 7. fc1 (bf16 MFMA)
    concat_fin_kernel<<<4096, 256, 0, stream>>>(out_ctx, buf_y1, buf_fin);
    gemm_mfma_bt<<<dim3(1024 / 128, 2048 / 128), 256, 0, stream>>>(
        buf_fin, fc1w, fc1b, nullptr, buf_fc1out, 2048, 1024, 2048, 1 /*relu*/);

    // 8. fc2 (bf16 MFMA)
    gemm_mfma_bt<<<dim3(VOCAB / 128, 2048 / 128), 256, 0, stream>>>(
        buf_fc1out, fc2w, fc2b, nullptr, out, 2048, VOCAB, 1024, 0);
}

// Round 5
// 1678.046 us; speedup vs baseline: 6.0722x; 1.1618x over previous
//
#include <hip/hip_runtime.h>
#include <hip/hip_bf16.h>

// Problem constants
#define T_STEPS 64
#define BATCH   32
#define HID     1024
#define VOCAB   32000
#define WLEN_   101
#define WSZ_    50
#define SENC    229
#define NBLK    128     // blocks per LSTM layer; fused grid = 2*NBLK = 256 = #CUs

static const size_t Y_SZ   = (size_t)T_STEPS * BATCH * VOCAB;   // 65,536,000
static const size_t HN_SZ  = (size_t)2 * BATCH * HID;           // 65,536
static const size_t CTX_OFF = Y_SZ + 2 * HN_SZ;                 // y + h_n + c_n

typedef __attribute__((ext_vector_type(8)))  unsigned short us8;
typedef __attribute__((ext_vector_type(8)))  __bf16 bf16x8;
typedef __attribute__((ext_vector_type(4)))  float f32x4;
typedef __attribute__((ext_vector_type(16))) float f32x16;

static __device__ inline unsigned short f2bf(float x) {
    __hip_bfloat16 b = __float2bfloat16(x);
    return __builtin_bit_cast(unsigned short, b);
}

// ---------------------------------------------------------------------------
// fp32 GEMM (attn-proj path only — keeps window indices exact)
// ---------------------------------------------------------------------------
__global__ __launch_bounds__(256) void gemm_bt(
    const float* __restrict__ A, const float* __restrict__ W,
    const float* __restrict__ b1, const float* __restrict__ b2,
    float* __restrict__ out, int M, int N, int K, int act)
{
    __shared__ __align__(16) float As[16 * 132];
    __shared__ __align__(16) float Ws[16 * 68];
    const int tid  = threadIdx.x;
    const int col0 = blockIdx.x * 64;
    const int row0 = blockIdx.y * 128;
    const int ty   = tid >> 4;
    const int tx   = tid & 15;

    float acc[8][4];
#pragma unroll
    for (int i = 0; i < 8; ++i)
#pragma unroll
        for (int j = 0; j < 4; ++j) acc[i][j] = 0.f;

    for (int k0 = 0; k0 < K; k0 += 16) {
#pragma unroll
        for (int li = 0; li < 2; ++li) {
            int f  = tid + li * 256;
            int r  = f >> 2;
            int kq = (f & 3) << 2;
            float4 v = *reinterpret_cast<const float4*>(A + (size_t)(row0 + r) * K + k0 + kq);
            As[(kq + 0) * 132 + r] = v.x;
            As[(kq + 1) * 132 + r] = v.y;
            As[(kq + 2) * 132 + r] = v.z;
            As[(kq + 3) * 132 + r] = v.w;
        }
        {
            int n  = tid >> 2;
            int kq = (tid & 3) << 2;
            float4 v = *reinterpret_cast<const float4*>(W + (size_t)(col0 + n) * K + k0 + kq);
            Ws[(kq + 0) * 68 + n] = v.x;
            Ws[(kq + 1) * 68 + n] = v.y;
            Ws[(kq + 2) * 68 + n] = v.z;
            Ws[(kq + 3) * 68 + n] = v.w;
        }
        __syncthreads();
#pragma unroll
        for (int k = 0; k < 16; ++k) {
            const float4 a0 = *reinterpret_cast<const float4*>(&As[k * 132 + ty * 8]);
            const float4 a1 = *reinterpret_cast<const float4*>(&As[k * 132 + ty * 8 + 4]);
            const float4 b0 = *reinterpret_cast<const float4*>(&Ws[k * 68 + tx * 4]);
            float av[8] = {a0.x, a0.y, a0.z, a0.w, a1.x, a1.y, a1.z, a1.w};
            float bv[4] = {b0.x, b0.y, b0.z, b0.w};
#pragma unroll
            for (int i = 0; i < 8; ++i)
#pragma unroll
                for (int j = 0; j < 4; ++j) acc[i][j] = fmaf(av[i], bv[j], acc[i][j]);
        }
        __syncthreads();
    }

#pragma unroll
    for (int j = 0; j < 4; ++j) {
        int n = col0 + tx * 4 + j;
        float bias = 0.f;
        if (b1) bias += b1[n];
        if (b2) bias += b2[n];
#pragma unroll
        for (int i = 0; i < 8; ++i) {
            float v = acc[i][j] + bias;
            if (act == 1) v = fmaxf(v, 0.f);
            else if (act == 2) v = tanhf(v);
            out[(size_t)(row0 + ty * 8 + i) * N + n] = v;
        }
    }
}

// ---------------------------------------------------------------------------
// bf16 MFMA GEMM (gates0/fc1/fc2): out[M,N] = A[M,K] @ W[N,K]^T + b1 + b2.
// ---------------------------------------------------------------------------
__global__ __launch_bounds__(256) void gemm_mfma_bt(
    const float* __restrict__ A, const float* __restrict__ W,
    const float* __restrict__ b1, const float* __restrict__ b2,
    float* __restrict__ out, int M, int N, int K, int relu)
{
    __shared__ __align__(16) unsigned short As[4096];
    __shared__ __align__(16) unsigned short Bs[4096];
    const int tid  = threadIdx.x;
    const int lane = tid & 63;
    const int wave = tid >> 6;
    const int row0 = blockIdx.y * 128;
    const int col0 = blockIdx.x * 128;
    const int m0 = (wave >> 1) * 64;
    const int n0 = (wave & 1) * 64;
    const int lrow = lane & 15;
    const int kc   = lane >> 4;

    const int srow = tid >> 1;
    const int skh  = tid & 1;

    f32x4 acc[4][4];
#pragma unroll
    for (int i = 0; i < 4; ++i)
#pragma unroll
        for (int j = 0; j < 4; ++j) acc[i][j] = (f32x4){0.f, 0.f, 0.f, 0.f};

    const float* gA = A + (size_t)(row0 + srow) * K + skh * 16;
    const float* gW = W + (size_t)(col0 + srow) * K + skh * 16;

    for (int k0 = 0; k0 < K; k0 += 32) {
        {
            float4 v0 = *reinterpret_cast<const float4*>(gA + k0);
            float4 v1 = *reinterpret_cast<const float4*>(gA + k0 + 4);
            float4 v2 = *reinterpret_cast<const float4*>(gA + k0 + 8);
            float4 v3 = *reinterpret_cast<const float4*>(gA + k0 + 12);
            us8 c0 = {f2bf(v0.x), f2bf(v0.y), f2bf(v0.z), f2bf(v0.w),
                      f2bf(v1.x), f2bf(v1.y), f2bf(v1.z), f2bf(v1.w)};
            us8 c1 = {f2bf(v2.x), f2bf(v2.y), f2bf(v2.z), f2bf(v2.w),
                      f2bf(v3.x), f2bf(v3.y), f2bf(v3.z), f2bf(v3.w)};
            *reinterpret_cast<us8*>(&As[((skh * 2 + 0) * 128 + srow) * 8]) = c0;
            *reinterpret_cast<us8*>(&As[((skh * 2 + 1) * 128 + srow) * 8]) = c1;
            float4 w0 = *reinterpret_cast<const float4*>(gW + k0);
            float4 w1 = *reinterpret_cast<const float4*>(gW + k0 + 4);
            float4 w2 = *reinterpret_cast<const float4*>(gW + k0 + 8);
            float4 w3 = *reinterpret_cast<const float4*>(gW + k0 + 12);
            us8 d0 = {f2bf(w0.x), f2bf(w0.y), f2bf(w0.z), f2bf(w0.w),
                      f2bf(w1.x), f2bf(w1.y), f2bf(w1.z), f2bf(w1.w)};
            us8 d1 = {f2bf(w2.x), f2bf(w2.y), f2bf(w2.z), f2bf(w2.w),
                      f2bf(w3.x), f2bf(w3.y), f2bf(w3.z), f2bf(w3.w)};
            *reinterpret_cast<us8*>(&Bs[((skh * 2 + 0) * 128 + srow) * 8]) = d0;
            *reinterpret_cast<us8*>(&Bs[((skh * 2 + 1) * 128 + srow) * 8]) = d1;
        }
        __syncthreads();
        us8 a[4], b[4];
#pragma unroll
        for (int f = 0; f < 4; ++f) {
            a[f] = *reinterpret_cast<const us8*>(&As[(kc * 128 + m0 + f * 16 + lrow) * 8]);
            b[f] = *reinterpret_cast<const us8*>(&Bs[(kc * 128 + n0 + f * 16 + lrow) * 8]);
        }
#pragma unroll
        for (int fi = 0; fi < 4; ++fi)
#pragma unroll
            for (int fj = 0; fj < 4; ++fj)
                acc[fi][fj] = __builtin_amdgcn_mfma_f32_16x16x32_bf16(
                    __builtin_bit_cast(bf16x8, a[fi]),
                    __builtin_bit_cast(bf16x8, b[fj]),
                    acc[fi][fj], 0, 0, 0);
        __syncthreads();
    }

#pragma unroll
    for (int fi = 0; fi < 4; ++fi)
#pragma unroll
        for (int fj = 0; fj < 4; ++fj) {
            int cN = col0 + n0 + fj * 16 + lrow;
            float bv = 0.f;
            if (b1) bv += b1[cN];
            if (b2) bv += b2[cN];
#pragma unroll
            for (int j = 0; j < 4; ++j) {
                int r = row0 + m0 + fi * 16 + (lane >> 4) * 4 + j;
                float v = acc[fi][fj][j] + bv;
                if (relu) v = fmaxf(v, 0.f);
                out[(size_t)r * N + cN] = v;
            }
        }
}

// ---------------------------------------------------------------------------
// Embedding lookup + input-feeding concat
// ---------------------------------------------------------------------------
__global__ void embed_concat_kernel(const float* __restrict__ emb,
                                    const float* __restrict__ ctxin,
                                    const int* __restrict__ tw,
                                    float* __restrict__ x)
{
    const size_t total = (size_t)2048 * 2048;
    for (size_t idx = (size_t)blockIdx.x * blockDim.x + threadIdx.x; idx < total;
         idx += (size_t)gridDim.x * blockDim.x) {
        int h = (int)(idx & 2047);
        size_t row = idx >> 11;
        float v;
        if (h < HID) v = emb[(size_t)tw[row] * HID + h];
        else         v = ctxin[row * HID + (h - HID)];
        x[idx] = v;
    }
}

__global__ void zero_flags_kernel(int* p, int n)
{
    int i = blockIdx.x * blockDim.x + threadIdx.x;
    if (i < n) p[i] = 0;
}

// ---------------------------------------------------------------------------
// Distributed-flag grid barrier (256 blocks). flags[i*32]: block i's phase.
// ---------------------------------------------------------------------------
static __device__ inline void grid_arrive(int* __restrict__ flags, int phase, int tid)
{
    // callers must __syncthreads() first (drains this block's stores to L2)
    if (tid == 0) {
        __builtin_amdgcn_fence(__ATOMIC_RELEASE, "agent");   // L2 writeback
        __hip_atomic_store(&flags[blockIdx.x * 32], phase,
                           __ATOMIC_RELAXED, __HIP_MEMORY_SCOPE_AGENT);
    }
}

static __device__ inline void grid_wait(int* __restrict__ flags, int phase, int tid)
{
    if (tid < 64) {
        const int i1 = tid * 32, i2 = (tid + 64) * 32;
        const int i3 = (tid + 128) * 32, i4 = (tid + 192) * 32;
        for (;;) {
            int f1 = __hip_atomic_load(&flags[i1], __ATOMIC_RELAXED, __HIP_MEMORY_SCOPE_AGENT);
            int f2 = __hip_atomic_load(&flags[i2], __ATOMIC_RELAXED, __HIP_MEMORY_SCOPE_AGENT);
            int f3 = __hip_atomic_load(&flags[i3], __ATOMIC_RELAXED, __HIP_MEMORY_SCOPE_AGENT);
            int f4 = __hip_atomic_load(&flags[i4], __ATOMIC_RELAXED, __HIP_MEMORY_SCOPE_AGENT);
            if (__all(f1 >= phase && f2 >= phase && f3 >= phase && f4 >= phase)) break;
            __builtin_amdgcn_s_sleep(2);
        }
        __builtin_amdgcn_fence(__ATOMIC_ACQUIRE, "agent");   // invalidate caches
    }
    __syncthreads();
}

// ---------------------------------------------------------------------------
// Fused 2-layer persistent LSTM, 1-step software pipeline.
// Grid = 256 blocks x 256 threads, exactly 1 block/CU (LDS-limited).
// Blocks 0..127: layer 0 (step t=s).  Blocks 128..255: layer 1 (step t=s-1),
// reading y0[t] as bf16 straight from layer 0's ping-pong buffer and folding
// y0@Wih1^T + h1@Whh1^T into one MFMA accumulator. 65 phases, one flag
// barrier each. y1 written via nontemporal stores (keeps the release-fence
// L2 writeback small).
// ---------------------------------------------------------------------------
__global__ __launch_bounds__(256) void lstm_fused(
    const float* __restrict__ gpre0,  // [64*32,4096] layer-0 pre-gates
    const float* __restrict__ Whh0,   // [4096,1024]
    const float* __restrict__ Wih1,   // [4096,1024]
    const float* __restrict__ Whh1,   // [4096,1024]
    const float* __restrict__ bih1, const float* __restrict__ bhh1,
    const float* __restrict__ h0all,  // [2,32,1024]
    const float* __restrict__ c0all,  // [2,32,1024]
    float* __restrict__ y1o,          // [64][32][1024] fp32
    float* __restrict__ hn,           // [2,32,1024]
    float* __restrict__ cn,           // [2,32,1024]
    unsigned short* __restrict__ hbf, // [2 layers][2 bufs][32768] bf16
    int* __restrict__ flags)          // [256*32] zeroed
{
    __shared__ __align__(16) us8 WB[8192];   // 128 KB: L0 uses [0,4096); L1 ih [0,4096) + hh [4096,8192)
    __shared__ float red2[32 * 132];         // 16.9 KB
    __shared__ float csh[256];

    const int tid  = threadIdx.x;
    const int lane = tid & 63;
    const int w    = tid >> 6;        // wave = K-quarter
    const int n    = lane & 31;
    const int kh   = lane >> 5;
    const bool isL1 = (blockIdx.x >= NBLK);
    const int lb   = isL1 ? (int)blockIdx.x - NBLK : (int)blockIdx.x;
    const int j0   = lb * 8;
    const int b    = tid >> 3;        // elementwise batch
    const int jj   = tid & 7;         // elementwise column
    const int gj   = j0 + jj;

    unsigned short* hb0 = hbf;            // layer-0 ping-pong
    unsigned short* hb1 = hbf + 65536;    // layer-1 ping-pong

    // ---- pack weights into LDS (bf16, MFMA-fragment lane-linear) ----
    const int grow = (n >> 3) * HID + j0 + (n & 7);   // gate-row g*1024 + j
    if (!isL1) {
        const float* wr = Whh0 + (size_t)grow * HID;
#pragma unroll
        for (int f = 0; f < 16; ++f) {
            int k = w * 256 + f * 16 + kh * 8;
            float4 v0 = *reinterpret_cast<const float4*>(wr + k);
            float4 v1 = *reinterpret_cast<const float4*>(wr + k + 4);
            WB[w * 1024 + f * 64 + lane] =
                (us8){f2bf(v0.x), f2bf(v0.y), f2bf(v0.z), f2bf(v0.w),
                      f2bf(v1.x), f2bf(v1.y), f2bf(v1.z), f2bf(v1.w)};
        }
    } else {
        const float* wi = Wih1 + (size_t)grow * HID;
        const float* wh = Whh1 + (size_t)grow * HID;
#pragma unroll
        for (int f = 0; f < 16; ++f) {
            int k = w * 256 + f * 16 + kh * 8;
            float4 v0 = *reinterpret_cast<const float4*>(wi + k);
            float4 v1 = *reinterpret_cast<const float4*>(wi + k + 4);
            WB[w * 1024 + f * 64 + lane] =
                (us8){f2bf(v0.x), f2bf(v0.y), f2bf(v0.z), f2bf(v0.w),
                      f2bf(v1.x), f2bf(v1.y), f2bf(v1.z), f2bf(v1.w)};
            float4 u0 = *reinterpret_cast<const float4*>(wh + k);
            float4 u1 = *reinterpret_cast<const float4*>(wh + k + 4);
            WB[4096 + w * 1024 + f * 64 + lane] =
                (us8){f2bf(u0.x), f2bf(u0.y), f2bf(u0.z), f2bf(u0.w),
                      f2bf(u1.x), f2bf(u1.y), f2bf(u1.z), f2bf(u1.w)};
        }
    }

    // ---- state init ----
    csh[tid] = c0all[(isL1 ? 32768 : 0) + b * HID + gj];
    {
        int idx = lb * 256 + tid;      // 128 blocks x 256 = full 32768
        (isL1 ? hb1 : hb0)[idx] = f2bf(h0all[(isL1 ? 32768 : 0) + idx]);
    }

    float bb0 = 0, bb1 = 0, bb2 = 0, bb3 = 0;
    float gp0 = 0, gp1 = 0, gp2 = 0, gp3 = 0;
    if (isL1) {
        bb0 = bih1[gj]            + bhh1[gj];
        bb1 = bih1[HID + gj]      + bhh1[HID + gj];
        bb2 = bih1[2 * HID + gj]  + bhh1[2 * HID + gj];
        bb3 = bih1[3 * HID + gj]  + bhh1[3 * HID + gj];
    } else {
        const float* gp = gpre0 + (size_t)b * 4096 + gj;
        gp0 = gp[0]; gp1 = gp[1024]; gp2 = gp[2048]; gp3 = gp[3072];
    }

    __syncthreads();
    grid_arrive(flags, 1, tid);
    grid_wait(flags, 1, tid);

    for (int s = 0; s <= T_STEPS; ++s) {
        const bool active = isL1 ? (s >= 1) : (s < T_STEPS);
        const int t = isL1 ? s - 1 : s;
        if (active) {
            f32x16 acc = {};
            if (!isL1) {
                const unsigned short* hr = hb0 + (t & 1) * 32768 + n * HID + w * 256 + kh * 8;
                us8 aF[16];
#pragma unroll
                for (int f = 0; f < 16; ++f)
                    aF[f] = *reinterpret_cast<const us8*>(hr + f * 16);
#pragma unroll
                for (int f = 0; f < 16; ++f)
                    acc = __builtin_amdgcn_mfma_f32_32x32x16_bf16(
                        __builtin_bit_cast(bf16x8, aF[f]),
                        __builtin_bit_cast(bf16x8, WB[w * 1024 + f * 64 + lane]),
                        acc, 0, 0, 0);
            } else {
                const unsigned short* yr = hb0 + (s & 1) * 32768 + n * HID + w * 256 + kh * 8;
                us8 aF[16];
#pragma unroll
                for (int f = 0; f < 16; ++f)
                    aF[f] = *reinterpret_cast<const us8*>(yr + f * 16);
#pragma unroll
                for (int f = 0; f < 16; ++f)
                    acc = __builtin_amdgcn_mfma_f32_32x32x16_bf16(
                        __builtin_bit_cast(bf16x8, aF[f]),
                        __builtin_bit_cast(bf16x8, WB[w * 1024 + f * 64 + lane]),
                        acc, 0, 0, 0);
                const unsigned short* hr = hb1 + (t & 1) * 32768 + n * HID + w * 256 + kh * 8;
#pragma unroll
                for (int f = 0; f < 16; ++f)
                    aF[f] = *reinterpret_cast<const us8*>(hr + f * 16);
#pragma unroll
                for (int f = 0; f < 16; ++f)
                    acc = __builtin_amdgcn_mfma_f32_32x32x16_bf16(
                        __builtin_bit_cast(bf16x8, aF[f]),
                        __builtin_bit_cast(bf16x8, WB[4096 + w * 1024 + f * 64 + lane]),
                        acc, 0, 0, 0);
            }
            // D layout: col(lane&31)=gate-row, row=(r&3)+8*(r>>2)+4*kh=batch
#pragma unroll
            for (int r = 0; r < 16; ++r) {
                int m = (r & 3) + 8 * (r >> 2) + 4 * kh;
                red2[m * 132 + w * 32 + n] = acc[r];
            }
        }
        __syncthreads();
        if (active) {
            float s0, s1v, s2v, s3v;
            if (isL1) { s0 = bb0; s1v = bb1; s2v = bb2; s3v = bb3; }
            else      { s0 = gp0; s1v = gp1; s2v = gp2; s3v = gp3; }
#pragma unroll
            for (int w2 = 0; w2 < 4; ++w2) {
                const float* rr = &red2[b * 132 + w2 * 32 + jj];
                s0  += rr[0];
                s1v += rr[8];
                s2v += rr[16];
                s3v += rr[24];
            }
            float ig = 1.f / (1.f + expf(-s0));
            float fg = 1.f / (1.f + expf(-s1v));
            float gg = tanhf(s2v);
            float og = 1.f / (1.f + expf(-s3v));
            float cv = fg * csh[tid] + ig * gg;
            csh[tid] = cv;
            float h = og * tanhf(cv);
            if (!isL1) {
                hb0[((t + 1) & 1) * 32768 + b * HID + gj] = f2bf(h);   // feeds L1 even at t=63
                if (t == T_STEPS - 1) {
                    hn[b * HID + gj] = h;
                    cn[b * HID + gj] = cv;
                }
            } else {
                __builtin_nontemporal_store(h, &y1o[(size_t)t * (BATCH * HID) + b * HID + gj]);
                if (t == T_STEPS - 1) {
                    hn[32768 + b * HID + gj] = h;
                    cn[32768 + b * HID + gj] = cv;
                } else {
                    hb1[((t + 1) & 1) * 32768 + b * HID + gj] = f2bf(h);
                }
            }
        }
        if (s < T_STEPS) {
            __syncthreads();                 // red2 reads done; h stores issued
            grid_arrive(flags, s + 2, tid);
            if (!isL1 && s + 1 < T_STEPS) {  // prefetch next gpre under the spin
                const float* gp = gpre0 + (size_t)((s + 1) * BATCH + b) * 4096 + gj;
                gp0 = gp[0]; gp1 = gp[1024]; gp2 = gp[2048]; gp3 = gp[3072];
            }
            grid_wait(flags, s + 2, tid);
        }
    }
}

// ---------------------------------------------------------------------------
// Attention p
// ---------------------------------------------------------------------------
__global__ __launch_bounds__(64) void attn_p_kernel(
    const float* __restrict__ hidden1, const float* __restrict__ aw2,
    const float* __restrict__ ab2, const int* __restrict__ lengths,
    float* __restrict__ p_arr, int* __restrict__ win_arr)
{
    const int row = blockIdx.x;
    const int lane = threadIdx.x;
    float s = 0.f;
    for (int i = lane; i < 512; i += 64) s += hidden1[(size_t)row * 512 + i] * aw2[i];
    for (int off = 32; off > 0; off >>= 1) s += __shfl_down(s, off);
    if (lane == 0) {
        float v = s + ab2[0];
        float sig = 1.f / (1.f + expf(-v));
        int b = row & 31;
        float lf = (float)lengths[b];
        p_arr[row] = (float)WSZ_ + lf * sig;
        win_arr[row] = (int)rintf(lf * sig);
    }
}

__global__ void sel_gather_kernel(const float* __restrict__ enc,
                                  const int* __restrict__ win_arr,
                                  float* __restrict__ sel)
{
    const int total = BATCH * WLEN_ * HID;
    for (int idx = blockIdx.x * blockDim.x + threadIdx.x; idx < total;
         idx += gridDim.x * blockDim.x) {
        int h = idx & 1023;
        int w = (idx >> 10) % WLEN_;
        int b = idx / (WLEN_ * HID);
        int s = win_arr[(T_STEPS - 1) * BATCH + b] + w;
        sel[idx] = enc[((size_t)s * BATCH + b) * HID + h];
    }
}

__global__ __launch_bounds__(128) void attn_fused_kernel(
    const float* __restrict__ y1, const float* __restrict__ sel,
    const float* __restrict__ p_arr, const int* __restrict__ win_arr,
    const int* __restrict__ lengths, float* __restrict__ ctx)
{
    __shared__ __align__(16) float yl[1024];
    __shared__ float sv[WLEN_];
    __shared__ float av[WLEN_];
    const int row = blockIdx.x;
    const int b   = row & 31;
    const int tid = threadIdx.x;

    for (int i = tid; i < 1024; i += 128) yl[i] = y1[(size_t)row * HID + i];
    __syncthreads();

    const int win = win_arr[row];
    const float p = p_arr[row];
    const int len = lengths[b];

    if (tid < WLEN_) {
        const float4* s4 = reinterpret_cast<const float4*>(sel + ((size_t)b * WLEN_ + tid) * HID);
        const float4* y4 = reinterpret_cast<const float4*>(yl);
        float acc = 0.f;
        for (int q = 0; q < 256; ++q) {
            float4 a = s4[q]; float4 yy = y4[q];
            acc += a.x * yy.x + a.y * yy.y + a.z * yy.z + a.w * yy.w;
        }
        bool lo = tid < (WSZ_ - win);
        bool hi = tid >= (len + WSZ_ - win);
        sv[tid] = (lo || hi) ? 1e-14f : acc;
    }
    __syncthreads();

    float mx = -1e30f;
    for (int w = 0; w < WLEN_; ++w) mx = fmaxf(mx, sv[w]);
    float sum = 0.f;
    for (int w = 0; w < WLEN_; ++w) sum += expf(sv[w] - mx);
    if (tid < WLEN_) {
        float e = expf(sv[tid] - mx) / sum;
        float d = (float)(win + tid) - p;
        av[tid] = e * expf(-(d * d) / 1250.f);
    }
    __syncthreads();

    float acc[8] = {0, 0, 0, 0, 0, 0, 0, 0};
    for (int w = 0; w < WLEN_; ++w) {
        float a = av[w];
        const float* srow = sel + ((size_t)b * WLEN_ + w) * HID;
#pragma unroll
        for (int i = 0; i < 8; ++i) acc[i] += a * srow[tid + 128 * i];
    }
    for (int i = 0; i < 8; ++i) ctx[(size_t)row * HID + tid + 128 * i] = acc[i];
}

__global__ void concat_fin_kernel(const float* __restrict__ ctx,
                                  const float* __restrict__ y1,
                                  float* __restrict__ fin)
{
    const size_t total = (size_t)2048 * 2048;
    for (size_t idx = (size_t)blockIdx.x * blockDim.x + threadIdx.x; idx < total;
         idx += (size_t)gridDim.x * blockDim.x) {
        int h = (int)(idx & 2047);
        size_t row = idx >> 11;
        fin[idx] = (h < HID) ? ctx[row * HID + h] : y1[row * HID + (h - HID)];
    }
}

// ---------------------------------------------------------------------------
extern "C" void kernel_launch(void* const* d_in, const int* in_sizes, int n_in,
                              void* d_out, int out_size, void* d_ws, size_t ws_size,
                              hipStream_t stream)
{
    const float* enc   = (const float*)d_in[0];
    const float* ctxin = (const float*)d_in[1];
    const float* h0    = (const float*)d_in[2];
    const float* c0    = (const float*)d_in[3];
    const float* emb   = (const float*)d_in[4];
    const float* aw1   = (const float*)d_in[5];
    const float* ab1   = (const float*)d_in[6];
    const float* aw2   = (const float*)d_in[7];
    const float* ab2   = (const float*)d_in[8];
    const float* Wih0  = (const float*)d_in[9];
    const float* Whh0  = (const float*)d_in[10];
    const float* bih0  = (const float*)d_in[11];
    const float* bhh0  = (const float*)d_in[12];
    const float* Wih1  = (const float*)d_in[13];
    const float* Whh1  = (const float*)d_in[14];
    const float* bih1  = (const float*)d_in[15];
    const float* bhh1  = (const float*)d_in[16];
    const float* fc1w  = (const float*)d_in[17];
    const float* fc1b  = (const float*)d_in[18];
    const float* fc2w  = (const float*)d_in[19];
    const float* fc2b  = (const float*)d_in[20];
    const int*   tw    = (const int*)d_in[21];
    const int*   lens  = (const int*)d_in[22];

    float* ws = (float*)d_ws;
    float* buf_x       = ws;                         // x; later fc1out
    float* buf_gates   = ws + 4194304;               // gates0; later fin
    float* buf_y1      = ws + 14680064;
    unsigned short* buf_hbf = (unsigned short*)(ws + 16777216);  // 4 x 32768 bf16 = 256 KB
    int*   buf_flags   = (int*)(ws + 16842752);      // 256*32 ints
    float* buf_hidden1 = ws + 16875520;
    float* buf_p       = ws + 17924096;
    int*   buf_win     = (int*)(ws + 17926144);
    float* buf_sel     = ws + 17928192;
    float* buf_fin     = buf_gates;
    float* buf_fc1out  = buf_x;

    float* out   = (float*)d_out;
    float* out_hn  = out + Y_SZ;
    float* out_cn  = out + Y_SZ + HN_SZ;
    float* out_ctx = out + CTX_OFF;

    // 0. zero barrier flags (256*32 ints)
    zero_flags_kernel<<<32, 256, 0, stream>>>(buf_flags, 8192);

    // 1. x = [embedding[tw], context]
    embed_concat_kernel<<<4096, 256, 0, stream>>>(emb, ctxin, tw, buf_x);

    // 2. gates0_pre = x @ Wih0^T + bih0 + bhh0   (bf16 MFMA)
    gemm_mfma_bt<<<dim3(4096 / 128, 2048 / 128), 256, 0, stream>>>(
        buf_x, Wih0, bih0, bhh0, buf_gates, 2048, 4096, 2048, 0);

    // 3+4+5. Both LSTM layers, fused persistent pipeline
    lstm_fused<<<2 * NBLK, 256, 0, stream>>>(
        buf_gates, Whh0, Wih1, Whh1, bih1, bhh1, h0, c0,
        buf_y1, out_hn, out_cn, buf_hbf, buf_flags);

    // 6. Attention (fp32, exact window/p path)
    gemm_bt<<<dim3(512 / 64, 2048 / 128), 256, 0, stream>>>(
        buf_y1, aw1, ab1, nullptr, buf_hidden1, 2048, 512, 1024, 2 /*tanh*/);
    attn_p_kernel<<<2048, 64, 0, stream>>>(buf_hidden1, aw2, ab2, lens, buf_p, buf_win);
    sel_gather_kernel<<<2048, 256, 0, stream>>>(enc, buf_win, buf_sel);
    attn_fused_kernel<<<2048, 128, 0, stream>>>(buf_y1, buf_sel, buf_p, buf_win, lens, out_ctx);

    // 7. fc1 (bf16 MFMA)
    concat_fin_kernel<<<4096, 256, 0, stream>>>(out_ctx, buf_y1, buf_fin);
    gemm_mfma_bt<<<dim3(1024 / 128, 2048 / 128), 256, 0, stream>>>(
        buf_fin, fc1w, fc1b, nullptr, buf_fc1out, 2048, 1024, 2048, 1 /*relu*/);

    // 8. fc2 (bf16 MFMA)
    gemm_mfma_bt<<<dim3(VOCAB / 128, 2048 / 128), 256, 0, stream>>>(
        buf_fc1out, fc2w, fc2b, nullptr, out, 2048, VOCAB, 1024, 0);
}

// Round 6
// 1307.836 us; speedup vs baseline: 7.7910x; 1.2831x over previous
//
#include <hip/hip_runtime.h>
#include <hip/hip_bf16.h>

// Problem constants
#define T_STEPS 64
#define BATCH   32
#define HID     1024
#define VOCAB   32000
#define WLEN_   101
#define WSZ_    50
#define SENC    229
#define NBLK    128     // blocks per LSTM layer; fused grid = 2*NBLK = 256 = #CUs

static const size_t Y_SZ   = (size_t)T_STEPS * BATCH * VOCAB;   // 65,536,000
static const size_t HN_SZ  = (size_t)2 * BATCH * HID;           // 65,536
static const size_t CTX_OFF = Y_SZ + 2 * HN_SZ;                 // y + h_n + c_n

typedef __attribute__((ext_vector_type(8)))  unsigned short us8;
typedef __attribute__((ext_vector_type(8)))  __bf16 bf16x8;
typedef __attribute__((ext_vector_type(4)))  float f32x4;
typedef __attribute__((ext_vector_type(16))) float f32x16;

static __device__ inline unsigned short f2bf(float x) {
    __hip_bfloat16 b = __float2bfloat16(x);
    return __builtin_bit_cast(unsigned short, b);
}

// Coherence-point (Infinity-Cache) accesses: bypass L1+L2 on both sides, so
// no buffer_wbl2 / buffer_inv cache maintenance is needed for cross-XCD
// visibility (same mechanism agent-scope atomics use).
#define GLD_US8_SC(dst, ptr) \
    asm volatile("global_load_dwordx4 %0, %1, off sc0 sc1" : "=v"(dst) : "v"(ptr) : "memory")
#define GST_U16_SC(ptr, val) \
    asm volatile("global_store_short %0, %1, off sc0 sc1" :: "v"(ptr), "v"(val) : "memory")
#define WAIT_VM0() asm volatile("s_waitcnt vmcnt(0)" ::: "memory")

// ---------------------------------------------------------------------------
// fp32 GEMM (attn-proj path only — keeps window indices exact)
// ---------------------------------------------------------------------------
__global__ __launch_bounds__(256) void gemm_bt(
    const float* __restrict__ A, const float* __restrict__ W,
    const float* __restrict__ b1, const float* __restrict__ b2,
    float* __restrict__ out, int M, int N, int K, int act)
{
    __shared__ __align__(16) float As[16 * 132];
    __shared__ __align__(16) float Ws[16 * 68];
    const int tid  = threadIdx.x;
    const int col0 = blockIdx.x * 64;
    const int row0 = blockIdx.y * 128;
    const int ty   = tid >> 4;
    const int tx   = tid & 15;

    float acc[8][4];
#pragma unroll
    for (int i = 0; i < 8; ++i)
#pragma unroll
        for (int j = 0; j < 4; ++j) acc[i][j] = 0.f;

    for (int k0 = 0; k0 < K; k0 += 16) {
#pragma unroll
        for (int li = 0; li < 2; ++li) {
            int f  = tid + li * 256;
            int r  = f >> 2;
            int kq = (f & 3) << 2;
            float4 v = *reinterpret_cast<const float4*>(A + (size_t)(row0 + r) * K + k0 + kq);
            As[(kq + 0) * 132 + r] = v.x;
            As[(kq + 1) * 132 + r] = v.y;
            As[(kq + 2) * 132 + r] = v.z;
            As[(kq + 3) * 132 + r] = v.w;
        }
        {
            int n  = tid >> 2;
            int kq = (tid & 3) << 2;
            float4 v = *reinterpret_cast<const float4*>(W + (size_t)(col0 + n) * K + k0 + kq);
            Ws[(kq + 0) * 68 + n] = v.x;
            Ws[(kq + 1) * 68 + n] = v.y;
            Ws[(kq + 2) * 68 + n] = v.z;
            Ws[(kq + 3) * 68 + n] = v.w;
        }
        __syncthreads();
#pragma unroll
        for (int k = 0; k < 16; ++k) {
            const float4 a0 = *reinterpret_cast<const float4*>(&As[k * 132 + ty * 8]);
            const float4 a1 = *reinterpret_cast<const float4*>(&As[k * 132 + ty * 8 + 4]);
            const float4 b0 = *reinterpret_cast<const float4*>(&Ws[k * 68 + tx * 4]);
            float av[8] = {a0.x, a0.y, a0.z, a0.w, a1.x, a1.y, a1.z, a1.w};
            float bv[4] = {b0.x, b0.y, b0.z, b0.w};
#pragma unroll
            for (int i = 0; i < 8; ++i)
#pragma unroll
                for (int j = 0; j < 4; ++j) acc[i][j] = fmaf(av[i], bv[j], acc[i][j]);
        }
        __syncthreads();
    }

#pragma unroll
    for (int j = 0; j < 4; ++j) {
        int n = col0 + tx * 4 + j;
        float bias = 0.f;
        if (b1) bias += b1[n];
        if (b2) bias += b2[n];
#pragma unroll
        for (int i = 0; i < 8; ++i) {
            float v = acc[i][j] + bias;
            if (act == 1) v = fmaxf(v, 0.f);
            else if (act == 2) v = tanhf(v);
            out[(size_t)(row0 + ty * 8 + i) * N + n] = v;
        }
    }
}

// ---------------------------------------------------------------------------
// bf16 MFMA GEMM (gates0/fc1/fc2): out[M,N] = A[M,K] @ W[N,K]^T + b1 + b2.
// ---------------------------------------------------------------------------
__global__ __launch_bounds__(256) void gemm_mfma_bt(
    const float* __restrict__ A, const float* __restrict__ W,
    const float* __restrict__ b1, const float* __restrict__ b2,
    float* __restrict__ out, int M, int N, int K, int relu)
{
    __shared__ __align__(16) unsigned short As[4096];
    __shared__ __align__(16) unsigned short Bs[4096];
    const int tid  = threadIdx.x;
    const int lane = tid & 63;
    const int wave = tid >> 6;
    const int row0 = blockIdx.y * 128;
    const int col0 = blockIdx.x * 128;
    const int m0 = (wave >> 1) * 64;
    const int n0 = (wave & 1) * 64;
    const int lrow = lane & 15;
    const int kc   = lane >> 4;

    const int srow = tid >> 1;
    const int skh  = tid & 1;

    f32x4 acc[4][4];
#pragma unroll
    for (int i = 0; i < 4; ++i)
#pragma unroll
        for (int j = 0; j < 4; ++j) acc[i][j] = (f32x4){0.f, 0.f, 0.f, 0.f};

    const float* gA = A + (size_t)(row0 + srow) * K + skh * 16;
    const float* gW = W + (size_t)(col0 + srow) * K + skh * 16;

    for (int k0 = 0; k0 < K; k0 += 32) {
        {
            float4 v0 = *reinterpret_cast<const float4*>(gA + k0);
            float4 v1 = *reinterpret_cast<const float4*>(gA + k0 + 4);
            float4 v2 = *reinterpret_cast<const float4*>(gA + k0 + 8);
            float4 v3 = *reinterpret_cast<const float4*>(gA + k0 + 12);
            us8 c0 = {f2bf(v0.x), f2bf(v0.y), f2bf(v0.z), f2bf(v0.w),
                      f2bf(v1.x), f2bf(v1.y), f2bf(v1.z), f2bf(v1.w)};
            us8 c1 = {f2bf(v2.x), f2bf(v2.y), f2bf(v2.z), f2bf(v2.w),
                      f2bf(v3.x), f2bf(v3.y), f2bf(v3.z), f2bf(v3.w)};
            *reinterpret_cast<us8*>(&As[((skh * 2 + 0) * 128 + srow) * 8]) = c0;
            *reinterpret_cast<us8*>(&As[((skh * 2 + 1) * 128 + srow) * 8]) = c1;
            float4 w0 = *reinterpret_cast<const float4*>(gW + k0);
            float4 w1 = *reinterpret_cast<const float4*>(gW + k0 + 4);
            float4 w2 = *reinterpret_cast<const float4*>(gW + k0 + 8);
            float4 w3 = *reinterpret_cast<const float4*>(gW + k0 + 12);
            us8 d0 = {f2bf(w0.x), f2bf(w0.y), f2bf(w0.z), f2bf(w0.w),
                      f2bf(w1.x), f2bf(w1.y), f2bf(w1.z), f2bf(w1.w)};
            us8 d1 = {f2bf(w2.x), f2bf(w2.y), f2bf(w2.z), f2bf(w2.w),
                      f2bf(w3.x), f2bf(w3.y), f2bf(w3.z), f2bf(w3.w)};
            *reinterpret_cast<us8*>(&Bs[((skh * 2 + 0) * 128 + srow) * 8]) = d0;
            *reinterpret_cast<us8*>(&Bs[((skh * 2 + 1) * 128 + srow) * 8]) = d1;
        }
        __syncthreads();
        us8 a[4], b[4];
#pragma unroll
        for (int f = 0; f < 4; ++f) {
            a[f] = *reinterpret_cast<const us8*>(&As[(kc * 128 + m0 + f * 16 + lrow) * 8]);
            b[f] = *reinterpret_cast<const us8*>(&Bs[(kc * 128 + n0 + f * 16 + lrow) * 8]);
        }
#pragma unroll
        for (int fi = 0; fi < 4; ++fi)
#pragma unroll
            for (int fj = 0; fj < 4; ++fj)
                acc[fi][fj] = __builtin_amdgcn_mfma_f32_16x16x32_bf16(
                    __builtin_bit_cast(bf16x8, a[fi]),
                    __builtin_bit_cast(bf16x8, b[fj]),
                    acc[fi][fj], 0, 0, 0);
        __syncthreads();
    }

#pragma unroll
    for (int fi = 0; fi < 4; ++fi)
#pragma unroll
        for (int fj = 0; fj < 4; ++fj) {
            int cN = col0 + n0 + fj * 16 + lrow;
            float bv = 0.f;
            if (b1) bv += b1[cN];
            if (b2) bv += b2[cN];
#pragma unroll
            for (int j = 0; j < 4; ++j) {
                int r = row0 + m0 + fi * 16 + (lane >> 4) * 4 + j;
                float v = acc[fi][fj][j] + bv;
                if (relu) v = fmaxf(v, 0.f);
                out[(size_t)r * N + cN] = v;
            }
        }
}

// ---------------------------------------------------------------------------
// Embedding lookup + input-feeding concat
// ---------------------------------------------------------------------------
__global__ void embed_concat_kernel(const float* __restrict__ emb,
                                    const float* __restrict__ ctxin,
                                    const int* __restrict__ tw,
                                    float* __restrict__ x)
{
    const size_t total = (size_t)2048 * 2048;
    for (size_t idx = (size_t)blockIdx.x * blockDim.x + threadIdx.x; idx < total;
         idx += (size_t)gridDim.x * blockDim.x) {
        int h = (int)(idx & 2047);
        size_t row = idx >> 11;
        float v;
        if (h < HID) v = emb[(size_t)tw[row] * HID + h];
        else         v = ctxin[row * HID + (h - HID)];
        x[idx] = v;
    }
}

__global__ void zero_flags_kernel(int* p, int n)
{
    int i = blockIdx.x * blockDim.x + threadIdx.x;
    if (i < n) p[i] = 0;
}

// ---------------------------------------------------------------------------
// Fenceless distributed-flag grid barrier (256 blocks).
// Callers: per-thread WAIT_VM0() + __syncthreads() BEFORE arrive (all the
// block's sc-stores have reached the coherence point); flag ops are relaxed
// agent-scope atomics (hardware-coherent at LLC); exchanged data is sc0sc1
// on both sides, so no buffer_wbl2 / buffer_inv is needed anywhere.
// ---------------------------------------------------------------------------
static __device__ inline void grid_arrive_nf(int* __restrict__ flags, int phase, int tid)
{
    if (tid == 0)
        __hip_atomic_store(&flags[blockIdx.x * 32], phase,
                           __ATOMIC_RELAXED, __HIP_MEMORY_SCOPE_AGENT);
}

static __device__ inline void grid_wait_nf(int* __restrict__ flags, int phase, int tid)
{
    // thread i polls block i's flag (256 threads = 256 blocks)
    for (;;) {
        int f = __hip_atomic_load(&flags[tid * 32], __ATOMIC_RELAXED, __HIP_MEMORY_SCOPE_AGENT);
        if (f >= phase) break;
        __builtin_amdgcn_s_sleep(2);
    }
    __syncthreads();
}

// ---------------------------------------------------------------------------
// Fused 2-layer persistent LSTM, 1-step software pipeline, fenceless sync.
// Grid = 256 blocks x 256 threads, 1 block/CU (LDS-limited).
// Blocks 0..127: layer 0 (step t=s).  Blocks 128..255: layer 1 (step t=s-1),
// folding y0@Wih1^T + h1@Whh1^T into one MFMA accumulator. h/y ping-pong
// buffers are exchanged via sc0sc1 (LLC-coherent) loads/stores.
// ---------------------------------------------------------------------------
__global__ __launch_bounds__(256) void lstm_fused(
    const float* __restrict__ gpre0,  // [64*32,4096] layer-0 pre-gates
    const float* __restrict__ Whh0,   // [4096,1024]
    const float* __restrict__ Wih1,   // [4096,1024]
    const float* __restrict__ Whh1,   // [4096,1024]
    const float* __restrict__ bih1, const float* __restrict__ bhh1,
    const float* __restrict__ h0all,  // [2,32,1024]
    const float* __restrict__ c0all,  // [2,32,1024]
    float* __restrict__ y1o,          // [64][32][1024] fp32
    float* __restrict__ hn,           // [2,32,1024]
    float* __restrict__ cn,           // [2,32,1024]
    unsigned short* __restrict__ hbf, // [2 layers][2 bufs][32768] bf16
    int* __restrict__ flags)          // [256*32] zeroed
{
    __shared__ __align__(16) us8 WB[8192];   // 128 KB
    __shared__ float red2[32 * 132];         // 16.9 KB
    __shared__ float csh[256];

    const int tid  = threadIdx.x;
    const int lane = tid & 63;
    const int w    = tid >> 6;        // wave = K-quarter
    const int n    = lane & 31;
    const int kh   = lane >> 5;
    const bool isL1 = (blockIdx.x >= NBLK);
    const int lb   = isL1 ? (int)blockIdx.x - NBLK : (int)blockIdx.x;
    const int j0   = lb * 8;
    const int b    = tid >> 3;        // elementwise batch
    const int jj   = tid & 7;         // elementwise column
    const int gj   = j0 + jj;

    unsigned short* hb0 = hbf;            // layer-0 ping-pong
    unsigned short* hb1 = hbf + 65536;    // layer-1 ping-pong

    // ---- pack weights into LDS (bf16, MFMA-fragment lane-linear) ----
    const int grow = (n >> 3) * HID + j0 + (n & 7);   // gate-row g*1024 + j
    if (!isL1) {
        const float* wr = Whh0 + (size_t)grow * HID;
#pragma unroll
        for (int f = 0; f < 16; ++f) {
            int k = w * 256 + f * 16 + kh * 8;
            float4 v0 = *reinterpret_cast<const float4*>(wr + k);
            float4 v1 = *reinterpret_cast<const float4*>(wr + k + 4);
            WB[w * 1024 + f * 64 + lane] =
                (us8){f2bf(v0.x), f2bf(v0.y), f2bf(v0.z), f2bf(v0.w),
                      f2bf(v1.x), f2bf(v1.y), f2bf(v1.z), f2bf(v1.w)};
        }
    } else {
        const float* wi = Wih1 + (size_t)grow * HID;
        const float* wh = Whh1 + (size_t)grow * HID;
#pragma unroll
        for (int f = 0; f < 16; ++f) {
            int k = w * 256 + f * 16 + kh * 8;
            float4 v0 = *reinterpret_cast<const float4*>(wi + k);
            float4 v1 = *reinterpret_cast<const float4*>(wi + k + 4);
            WB[w * 1024 + f * 64 + lane] =
                (us8){f2bf(v0.x), f2bf(v0.y), f2bf(v0.z), f2bf(v0.w),
                      f2bf(v1.x), f2bf(v1.y), f2bf(v1.z), f2bf(v1.w)};
            float4 u0 = *reinterpret_cast<const float4*>(wh + k);
            float4 u1 = *reinterpret_cast<const float4*>(wh + k + 4);
            WB[4096 + w * 1024 + f * 64 + lane] =
                (us8){f2bf(u0.x), f2bf(u0.y), f2bf(u0.z), f2bf(u0.w),
                      f2bf(u1.x), f2bf(u1.y), f2bf(u1.z), f2bf(u1.w)};
        }
    }

    // ---- state init (h0 -> ping-pong via sc stores: cross-block data) ----
    csh[tid] = c0all[(isL1 ? 32768 : 0) + b * HID + gj];
    {
        int idx = lb * 256 + tid;      // 128 blocks x 256 = full 32768
        unsigned int hv = f2bf(h0all[(isL1 ? 32768 : 0) + idx]);
        GST_U16_SC((isL1 ? hb1 : hb0) + idx, hv);
    }

    float bb0 = 0, bb1 = 0, bb2 = 0, bb3 = 0;
    float gp0 = 0, gp1 = 0, gp2 = 0, gp3 = 0;
    if (isL1) {
        bb0 = bih1[gj]            + bhh1[gj];
        bb1 = bih1[HID + gj]      + bhh1[HID + gj];
        bb2 = bih1[2 * HID + gj]  + bhh1[2 * HID + gj];
        bb3 = bih1[3 * HID + gj]  + bhh1[3 * HID + gj];
    } else {
        const float* gp = gpre0 + (size_t)b * 4096 + gj;
        gp0 = gp[0]; gp1 = gp[1024]; gp2 = gp[2048]; gp3 = gp[3072];
    }

    WAIT_VM0();
    __syncthreads();
    grid_arrive_nf(flags, 1, tid);
    grid_wait_nf(flags, 1, tid);

    for (int s = 0; s <= T_STEPS; ++s) {
        const bool active = isL1 ? (s >= 1) : (s < T_STEPS);
        const int t = isL1 ? s - 1 : s;
        if (active) {
            f32x16 acc = {};
            if (!isL1) {
                const unsigned short* hr = hb0 + (t & 1) * 32768 + n * HID + w * 256 + kh * 8;
                us8 aF[16];
#pragma unroll
                for (int f = 0; f < 16; ++f)
                    GLD_US8_SC(aF[f], hr + f * 16);
                WAIT_VM0();
                __builtin_amdgcn_sched_barrier(0);
#pragma unroll
                for (int f = 0; f < 16; ++f)
                    acc = __builtin_amdgcn_mfma_f32_32x32x16_bf16(
                        __builtin_bit_cast(bf16x8, aF[f]),
                        __builtin_bit_cast(bf16x8, WB[w * 1024 + f * 64 + lane]),
                        acc, 0, 0, 0);
            } else {
                const unsigned short* yr = hb0 + (s & 1) * 32768 + n * HID + w * 256 + kh * 8;
                const unsigned short* hr = hb1 + (t & 1) * 32768 + n * HID + w * 256 + kh * 8;
                us8 aY[16], aH[16];
#pragma unroll
                for (int f = 0; f < 16; ++f)
                    GLD_US8_SC(aY[f], yr + f * 16);
#pragma unroll
                for (int f = 0; f < 16; ++f)
                    GLD_US8_SC(aH[f], hr + f * 16);
                WAIT_VM0();
                __builtin_amdgcn_sched_barrier(0);
#pragma unroll
                for (int f = 0; f < 16; ++f)
                    acc = __builtin_amdgcn_mfma_f32_32x32x16_bf16(
                        __builtin_bit_cast(bf16x8, aY[f]),
                        __builtin_bit_cast(bf16x8, WB[w * 1024 + f * 64 + lane]),
                        acc, 0, 0, 0);
#pragma unroll
                for (int f = 0; f < 16; ++f)
                    acc = __builtin_amdgcn_mfma_f32_32x32x16_bf16(
                        __builtin_bit_cast(bf16x8, aH[f]),
                        __builtin_bit_cast(bf16x8, WB[4096 + w * 1024 + f * 64 + lane]),
                        acc, 0, 0, 0);
            }
            // D layout: col(lane&31)=gate-row, row=(r&3)+8*(r>>2)+4*kh=batch
#pragma unroll
            for (int r = 0; r < 16; ++r) {
                int m = (r & 3) + 8 * (r >> 2) + 4 * kh;
                red2[m * 132 + w * 32 + n] = acc[r];
            }
        }
        __syncthreads();
        if (active) {
            float s0, s1v, s2v, s3v;
            if (isL1) { s0 = bb0; s1v = bb1; s2v = bb2; s3v = bb3; }
            else      { s0 = gp0; s1v = gp1; s2v = gp2; s3v = gp3; }
#pragma unroll
            for (int w2 = 0; w2 < 4; ++w2) {
                const float* rr = &red2[b * 132 + w2 * 32 + jj];
                s0  += rr[0];
                s1v += rr[8];
                s2v += rr[16];
                s3v += rr[24];
            }
            float ig = 1.f / (1.f + expf(-s0));
            float fg = 1.f / (1.f + expf(-s1v));
            float gg = tanhf(s2v);
            float og = 1.f / (1.f + expf(-s3v));
            float cv = fg * csh[tid] + ig * gg;
            csh[tid] = cv;
            float h = og * tanhf(cv);
            if (!isL1) {
                unsigned int hv = f2bf(h);
                GST_U16_SC(hb0 + ((t + 1) & 1) * 32768 + b * HID + gj, hv);  // feeds L1 even at t=63
                if (t == T_STEPS - 1) {
                    hn[b * HID + gj] = h;
                    cn[b * HID + gj] = cv;
                }
            } else {
                __builtin_nontemporal_store(h, &y1o[(size_t)t * (BATCH * HID) + b * HID + gj]);
                if (t == T_STEPS - 1) {
                    hn[32768 + b * HID + gj] = h;
                    cn[32768 + b * HID + gj] = cv;
                } else {
                    unsigned int hv = f2bf(h);
                    GST_U16_SC(hb1 + ((t + 1) & 1) * 32768 + b * HID + gj, hv);
                }
            }
        }
        if (s < T_STEPS) {
            WAIT_VM0();                      // sc-stores at coherence point
            __syncthreads();                 // whole block drained; red2 reads done
            grid_arrive_nf(flags, s + 2, tid);
            if (!isL1 && s + 1 < T_STEPS) {  // prefetch next gpre under the spin
                const float* gp = gpre0 + (size_t)((s + 1) * BATCH + b) * 4096 + gj;
                gp0 = gp[0]; gp1 = gp[1024]; gp2 = gp[2048]; gp3 = gp[3072];
            }
            grid_wait_nf(flags, s + 2, tid);
        }
    }
}

// ---------------------------------------------------------------------------
// Attention p
// ---------------------------------------------------------------------------
__global__ __launch_bounds__(64) void attn_p_kernel(
    const float* __restrict__ hidden1, const float* __restrict__ aw2,
    const float* __restrict__ ab2, const int* __restrict__ lengths,
    float* __restrict__ p_arr, int* __restrict__ win_arr)
{
    const int row = blockIdx.x;
    const int lane = threadIdx.x;
    float s = 0.f;
    for (int i = lane; i < 512; i += 64) s += hidden1[(size_t)row * 512 + i] * aw2[i];
    for (int off = 32; off > 0; off >>= 1) s += __shfl_down(s, off);
    if (lane == 0) {
        float v = s + ab2[0];
        float sig = 1.f / (1.f + expf(-v));
        int b = row & 31;
        float lf = (float)lengths[b];
        p_arr[row] = (float)WSZ_ + lf * sig;
        win_arr[row] = (int)rintf(lf * sig);
    }
}

__global__ void sel_gather_kernel(const float* __restrict__ enc,
                                  const int* __restrict__ win_arr,
                                  float* __restrict__ sel)
{
    const int total = BATCH * WLEN_ * HID;
    for (int idx = blockIdx.x * blockDim.x + threadIdx.x; idx < total;
         idx += gridDim.x * blockDim.x) {
        int h = idx & 1023;
        int w = (idx >> 10) % WLEN_;
        int b = idx / (WLEN_ * HID);
        int s = win_arr[(T_STEPS - 1) * BATCH + b] + w;
        sel[idx] = enc[((size_t)s * BATCH + b) * HID + h];
    }
}

__global__ __launch_bounds__(128) void attn_fused_kernel(
    const float* __restrict__ y1, const float* __restrict__ sel,
    const float* __restrict__ p_arr, const int* __restrict__ win_arr,
    const int* __restrict__ lengths, float* __restrict__ ctx)
{
    __shared__ __align__(16) float yl[1024];
    __shared__ float sv[WLEN_];
    __shared__ float av[WLEN_];
    const int row = blockIdx.x;
    const int b   = row & 31;
    const int tid = threadIdx.x;

    for (int i = tid; i < 1024; i += 128) yl[i] = y1[(size_t)row * HID + i];
    __syncthreads();

    const int win = win_arr[row];
    const float p = p_arr[row];
    const int len = lengths[b];

    if (tid < WLEN_) {
        const float4* s4 = reinterpret_cast<const float4*>(sel + ((size_t)b * WLEN_ + tid) * HID);
        const float4* y4 = reinterpret_cast<const float4*>(yl);
        float acc = 0.f;
        for (int q = 0; q < 256; ++q) {
            float4 a = s4[q]; float4 yy = y4[q];
            acc += a.x * yy.x + a.y * yy.y + a.z * yy.z + a.w * yy.w;
        }
        bool lo = tid < (WSZ_ - win);
        bool hi = tid >= (len + WSZ_ - win);
        sv[tid] = (lo || hi) ? 1e-14f : acc;
    }
    __syncthreads();

    float mx = -1e30f;
    for (int w = 0; w < WLEN_; ++w) mx = fmaxf(mx, sv[w]);
    float sum = 0.f;
    for (int w = 0; w < WLEN_; ++w) sum += expf(sv[w] - mx);
    if (tid < WLEN_) {
        float e = expf(sv[tid] - mx) / sum;
        float d = (float)(win + tid) - p;
        av[tid] = e * expf(-(d * d) / 1250.f);
    }
    __syncthreads();

    float acc[8] = {0, 0, 0, 0, 0, 0, 0, 0};
    for (int w = 0; w < WLEN_; ++w) {
        float a = av[w];
        const float* srow = sel + ((size_t)b * WLEN_ + w) * HID;
#pragma unroll
        for (int i = 0; i < 8; ++i) acc[i] += a * srow[tid + 128 * i];
    }
    for (int i = 0; i < 8; ++i) ctx[(size_t)row * HID + tid + 128 * i] = acc[i];
}

__global__ void concat_fin_kernel(const float* __restrict__ ctx,
                                  const float* __restrict__ y1,
                                  float* __restrict__ fin)
{
    const size_t total = (size_t)2048 * 2048;
    for (size_t idx = (size_t)blockIdx.x * blockDim.x + threadIdx.x; idx < total;
         idx += (size_t)gridDim.x * blockDim.x) {
        int h = (int)(idx & 2047);
        size_t row = idx >> 11;
        fin[idx] = (h < HID) ? ctx[row * HID + h] : y1[row * HID + (h - HID)];
    }
}

// ---------------------------------------------------------------------------
extern "C" void kernel_launch(void* const* d_in, const int* in_sizes, int n_in,
                              void* d_out, int out_size, void* d_ws, size_t ws_size,
                              hipStream_t stream)
{
    const float* enc   = (const float*)d_in[0];
    const float* ctxin = (const float*)d_in[1];
    const float* h0    = (const float*)d_in[2];
    const float* c0    = (const float*)d_in[3];
    const float* emb   = (const float*)d_in[4];
    const float* aw1   = (const float*)d_in[5];
    const float* ab1   = (const float*)d_in[6];
    const float* aw2   = (const float*)d_in[7];
    const float* ab2   = (const float*)d_in[8];
    const float* Wih0  = (const float*)d_in[9];
    const float* Whh0  = (const float*)d_in[10];
    const float* bih0  = (const float*)d_in[11];
    const float* bhh0  = (const float*)d_in[12];
    const float* Wih1  = (const float*)d_in[13];
    const float* Whh1  = (const float*)d_in[14];
    const float* bih1  = (const float*)d_in[15];
    const float* bhh1  = (const float*)d_in[16];
    const float* fc1w  = (const float*)d_in[17];
    const float* fc1b  = (const float*)d_in[18];
    const float* fc2w  = (const float*)d_in[19];
    const float* fc2b  = (const float*)d_in[20];
    const int*   tw    = (const int*)d_in[21];
    const int*   lens  = (const int*)d_in[22];

    float* ws = (float*)d_ws;
    float* buf_x       = ws;                         // x; later fc1out
    float* buf_gates   = ws + 4194304;               // gates0; later fin
    float* buf_y1      = ws + 14680064;
    unsigned short* buf_hbf = (unsigned short*)(ws + 16777216);  // 4 x 32768 bf16 = 256 KB
    int*   buf_flags   = (int*)(ws + 16842752);      // 256*32 ints
    float* buf_hidden1 = ws + 16875520;
    float* buf_p       = ws + 17924096;
    int*   buf_win     = (int*)(ws + 17926144);
    float* buf_sel     = ws + 17928192;
    float* buf_fin     = buf_gates;
    float* buf_fc1out  = buf_x;

    float* out   = (float*)d_out;
    float* out_hn  = out + Y_SZ;
    float* out_cn  = out + Y_SZ + HN_SZ;
    float* out_ctx = out + CTX_OFF;

    // 0. zero barrier flags (256*32 ints)
    zero_flags_kernel<<<32, 256, 0, stream>>>(buf_flags, 8192);

    // 1. x = [embedding[tw], context]
    embed_concat_kernel<<<4096, 256, 0, stream>>>(emb, ctxin, tw, buf_x);

    // 2. gates0_pre = x @ Wih0^T + bih0 + bhh0   (bf16 MFMA)
    gemm_mfma_bt<<<dim3(4096 / 128, 2048 / 128), 256, 0, stream>>>(
        buf_x, Wih0, bih0, bhh0, buf_gates, 2048, 4096, 2048, 0);

    // 3+4+5. Both LSTM layers, fused persistent pipeline (fenceless sync)
    lstm_fused<<<2 * NBLK, 256, 0, stream>>>(
        buf_gates, Whh0, Wih1, Whh1, bih1, bhh1, h0, c0,
        buf_y1, out_hn, out_cn, buf_hbf, buf_flags);

    // 6. Attention (fp32, exact window/p path)
    gemm_bt<<<dim3(512 / 64, 2048 / 128), 256, 0, stream>>>(
        buf_y1, aw1, ab1, nullptr, buf_hidden1, 2048, 512, 1024, 2 /*tanh*/);
    attn_p_kernel<<<2048, 64, 0, stream>>>(buf_hidden1, aw2, ab2, lens, buf_p, buf_win);
    sel_gather_kernel<<<2048, 256, 0, stream>>>(enc, buf_win, buf_sel);
    attn_fused_kernel<<<2048, 128, 0, stream>>>(buf_y1, buf_sel, buf_p, buf_win, lens, out_ctx);

    // 7. fc1 (bf16 MFMA)
    concat_fin_kernel<<<4096, 256, 0, stream>>>(out_ctx, buf_y1, buf_fin);
    gemm_mfma_bt<<<dim3(1024 / 128, 2048 / 128), 256, 0, stream>>>(
        buf_fin, fc1w, fc1b, nullptr, buf_fc1out, 2048, 1024, 2048, 1 /*relu*/);

    // 8. fc2 (bf16 MFMA)
    gemm_mfma_bt<<<dim3(VOCAB / 128, 2048 / 128), 256, 0, stream>>>(
        buf_fc1out, fc2w, fc2b, nullptr, out, 2048, VOCAB, 1024, 0);
}

// Round 7
// 1288.010 us; speedup vs baseline: 7.9109x; 1.0154x over previous
//
#include <hip/hip_runtime.h>
#include <hip/hip_bf16.h>

// Problem constants
#define T_STEPS 64
#define BATCH   32
#define HID     1024
#define VOCAB   32000
#define WLEN_   101
#define WSZ_    50
#define SENC    229
#define NBLK    128     // blocks per LSTM layer; fused grid = 2*NBLK = 256 = #CUs

static const size_t Y_SZ   = (size_t)T_STEPS * BATCH * VOCAB;   // 65,536,000
static const size_t HN_SZ  = (size_t)2 * BATCH * HID;           // 65,536
static const size_t CTX_OFF = Y_SZ + 2 * HN_SZ;                 // y + h_n + c_n

typedef __attribute__((ext_vector_type(8)))  unsigned short us8;
typedef __attribute__((ext_vector_type(8)))  __bf16 bf16x8;
typedef __attribute__((ext_vector_type(4)))  float f32x4;
typedef __attribute__((ext_vector_type(16))) float f32x16;

static __device__ inline unsigned short f2bf(float x) {
    __hip_bfloat16 b = __float2bfloat16(x);
    return __builtin_bit_cast(unsigned short, b);
}

// Coherence-point (Infinity-Cache) accesses: bypass L1+L2 on both sides, so
// no buffer_wbl2 / buffer_inv cache maintenance is needed for cross-XCD
// visibility (verified round 6: absmax unchanged, -43% barrier cost).
#define GLD_US8_SC(dst, ptr) \
    asm volatile("global_load_dwordx4 %0, %1, off sc0 sc1" : "=v"(dst) : "v"(ptr) : "memory")
#define GST_U16_SC(ptr, val) \
    asm volatile("global_store_short %0, %1, off sc0 sc1" :: "v"(ptr), "v"(val) : "memory")
#define WAIT_VM0() asm volatile("s_waitcnt vmcnt(0)" ::: "memory")

// ---------------------------------------------------------------------------
// fp32 GEMM (attn-proj path only — keeps window indices exact)
// ---------------------------------------------------------------------------
__global__ __launch_bounds__(256) void gemm_bt(
    const float* __restrict__ A, const float* __restrict__ W,
    const float* __restrict__ b1, const float* __restrict__ b2,
    float* __restrict__ out, int M, int N, int K, int act)
{
    __shared__ __align__(16) float As[16 * 132];
    __shared__ __align__(16) float Ws[16 * 68];
    const int tid  = threadIdx.x;
    const int col0 = blockIdx.x * 64;
    const int row0 = blockIdx.y * 128;
    const int ty   = tid >> 4;
    const int tx   = tid & 15;

    float acc[8][4];
#pragma unroll
    for (int i = 0; i < 8; ++i)
#pragma unroll
        for (int j = 0; j < 4; ++j) acc[i][j] = 0.f;

    for (int k0 = 0; k0 < K; k0 += 16) {
#pragma unroll
        for (int li = 0; li < 2; ++li) {
            int f  = tid + li * 256;
            int r  = f >> 2;
            int kq = (f & 3) << 2;
            float4 v = *reinterpret_cast<const float4*>(A + (size_t)(row0 + r) * K + k0 + kq);
            As[(kq + 0) * 132 + r] = v.x;
            As[(kq + 1) * 132 + r] = v.y;
            As[(kq + 2) * 132 + r] = v.z;
            As[(kq + 3) * 132 + r] = v.w;
        }
        {
            int n  = tid >> 2;
            int kq = (tid & 3) << 2;
            float4 v = *reinterpret_cast<const float4*>(W + (size_t)(col0 + n) * K + k0 + kq);
            Ws[(kq + 0) * 68 + n] = v.x;
            Ws[(kq + 1) * 68 + n] = v.y;
            Ws[(kq + 2) * 68 + n] = v.z;
            Ws[(kq + 3) * 68 + n] = v.w;
        }
        __syncthreads();
#pragma unroll
        for (int k = 0; k < 16; ++k) {
            const float4 a0 = *reinterpret_cast<const float4*>(&As[k * 132 + ty * 8]);
            const float4 a1 = *reinterpret_cast<const float4*>(&As[k * 132 + ty * 8 + 4]);
            const float4 b0 = *reinterpret_cast<const float4*>(&Ws[k * 68 + tx * 4]);
            float av[8] = {a0.x, a0.y, a0.z, a0.w, a1.x, a1.y, a1.z, a1.w};
            float bv[4] = {b0.x, b0.y, b0.z, b0.w};
#pragma unroll
            for (int i = 0; i < 8; ++i)
#pragma unroll
                for (int j = 0; j < 4; ++j) acc[i][j] = fmaf(av[i], bv[j], acc[i][j]);
        }
        __syncthreads();
    }

#pragma unroll
    for (int j = 0; j < 4; ++j) {
        int n = col0 + tx * 4 + j;
        float bias = 0.f;
        if (b1) bias += b1[n];
        if (b2) bias += b2[n];
#pragma unroll
        for (int i = 0; i < 8; ++i) {
            float v = acc[i][j] + bias;
            if (act == 1) v = fmaxf(v, 0.f);
            else if (act == 2) v = tanhf(v);
            out[(size_t)(row0 + ty * 8 + i) * N + n] = v;
        }
    }
}

// ---------------------------------------------------------------------------
// bf16 MFMA GEMM (fc2): out[M,N] = A[M,K] @ W[N,K]^T + b1 + b2.
// ---------------------------------------------------------------------------
__global__ __launch_bounds__(256) void gemm_mfma_bt(
    const float* __restrict__ A, const float* __restrict__ W,
    const float* __restrict__ b1, const float* __restrict__ b2,
    float* __restrict__ out, int M, int N, int K, int relu)
{
    __shared__ __align__(16) unsigned short As[4096];
    __shared__ __align__(16) unsigned short Bs[4096];
    const int tid  = threadIdx.x;
    const int lane = tid & 63;
    const int wave = tid >> 6;
    const int row0 = blockIdx.y * 128;
    const int col0 = blockIdx.x * 128;
    const int m0 = (wave >> 1) * 64;
    const int n0 = (wave & 1) * 64;
    const int lrow = lane & 15;
    const int kc   = lane >> 4;

    const int srow = tid >> 1;
    const int skh  = tid & 1;

    f32x4 acc[4][4];
#pragma unroll
    for (int i = 0; i < 4; ++i)
#pragma unroll
        for (int j = 0; j < 4; ++j) acc[i][j] = (f32x4){0.f, 0.f, 0.f, 0.f};

    const float* gA = A + (size_t)(row0 + srow) * K + skh * 16;
    const float* gW = W + (size_t)(col0 + srow) * K + skh * 16;

    for (int k0 = 0; k0 < K; k0 += 32) {
        {
            float4 v0 = *reinterpret_cast<const float4*>(gA + k0);
            float4 v1 = *reinterpret_cast<const float4*>(gA + k0 + 4);
            float4 v2 = *reinterpret_cast<const float4*>(gA + k0 + 8);
            float4 v3 = *reinterpret_cast<const float4*>(gA + k0 + 12);
            us8 c0 = {f2bf(v0.x), f2bf(v0.y), f2bf(v0.z), f2bf(v0.w),
                      f2bf(v1.x), f2bf(v1.y), f2bf(v1.z), f2bf(v1.w)};
            us8 c1 = {f2bf(v2.x), f2bf(v2.y), f2bf(v2.z), f2bf(v2.w),
                      f2bf(v3.x), f2bf(v3.y), f2bf(v3.z), f2bf(v3.w)};
            *reinterpret_cast<us8*>(&As[((skh * 2 + 0) * 128 + srow) * 8]) = c0;
            *reinterpret_cast<us8*>(&As[((skh * 2 + 1) * 128 + srow) * 8]) = c1;
            float4 w0 = *reinterpret_cast<const float4*>(gW + k0);
            float4 w1 = *reinterpret_cast<const float4*>(gW + k0 + 4);
            float4 w2 = *reinterpret_cast<const float4*>(gW + k0 + 8);
            float4 w3 = *reinterpret_cast<const float4*>(gW + k0 + 12);
            us8 d0 = {f2bf(w0.x), f2bf(w0.y), f2bf(w0.z), f2bf(w0.w),
                      f2bf(w1.x), f2bf(w1.y), f2bf(w1.z), f2bf(w1.w)};
            us8 d1 = {f2bf(w2.x), f2bf(w2.y), f2bf(w2.z), f2bf(w2.w),
                      f2bf(w3.x), f2bf(w3.y), f2bf(w3.z), f2bf(w3.w)};
            *reinterpret_cast<us8*>(&Bs[((skh * 2 + 0) * 128 + srow) * 8]) = d0;
            *reinterpret_cast<us8*>(&Bs[((skh * 2 + 1) * 128 + srow) * 8]) = d1;
        }
        __syncthreads();
        us8 a[4], b[4];
#pragma unroll
        for (int f = 0; f < 4; ++f) {
            a[f] = *reinterpret_cast<const us8*>(&As[(kc * 128 + m0 + f * 16 + lrow) * 8]);
            b[f] = *reinterpret_cast<const us8*>(&Bs[(kc * 128 + n0 + f * 16 + lrow) * 8]);
        }
#pragma unroll
        for (int fi = 0; fi < 4; ++fi)
#pragma unroll
            for (int fj = 0; fj < 4; ++fj)
                acc[fi][fj] = __builtin_amdgcn_mfma_f32_16x16x32_bf16(
                    __builtin_bit_cast(bf16x8, a[fi]),
                    __builtin_bit_cast(bf16x8, b[fj]),
                    acc[fi][fj], 0, 0, 0);
        __syncthreads();
    }

#pragma unroll
    for (int fi = 0; fi < 4; ++fi)
#pragma unroll
        for (int fj = 0; fj < 4; ++fj) {
            int cN = col0 + n0 + fj * 16 + lrow;
            float bv = 0.f;
            if (b1) bv += b1[cN];
            if (b2) bv += b2[cN];
#pragma unroll
            for (int j = 0; j < 4; ++j) {
                int r = row0 + m0 + fi * 16 + (lane >> 4) * 4 + j;
                float v = acc[fi][fj][j] + bv;
                if (relu) v = fmaxf(v, 0.f);
                out[(size_t)r * N + cN] = v;
            }
        }
}

// ---------------------------------------------------------------------------
// bf16 MFMA GEMM with concatenated A = [Alo | Ahi] (each K/2=1024 wide).
// If tw != null, Alo is row-indexed through tw (embedding gather).
// Used for gates0 (emb+ctx concat) and fc1 (attn-ctx + y1 concat).
// K must be 2048; 16-float staging chunks never straddle the 1024 boundary.
// ---------------------------------------------------------------------------
__global__ __launch_bounds__(256) void gemm_mfma_cat(
    const float* __restrict__ Alo, const float* __restrict__ Ahi,
    const int* __restrict__ tw, const float* __restrict__ W,
    const float* __restrict__ b1, const float* __restrict__ b2,
    float* __restrict__ out, int M, int N, int relu)
{
    const int K = 2048;
    __shared__ __align__(16) unsigned short As[4096];
    __shared__ __align__(16) unsigned short Bs[4096];
    const int tid  = threadIdx.x;
    const int lane = tid & 63;
    const int wave = tid >> 6;
    const int row0 = blockIdx.y * 128;
    const int col0 = blockIdx.x * 128;
    const int m0 = (wave >> 1) * 64;
    const int n0 = (wave & 1) * 64;
    const int lrow = lane & 15;
    const int kc   = lane >> 4;

    const int srow = tid >> 1;
    const int skh  = tid & 1;
    const int r    = row0 + srow;
    const int rlo  = tw ? tw[r] : r;

    f32x4 acc[4][4];
#pragma unroll
    for (int i = 0; i < 4; ++i)
#pragma unroll
        for (int j = 0; j < 4; ++j) acc[i][j] = (f32x4){0.f, 0.f, 0.f, 0.f};

    const float* gW = W + (size_t)(col0 + srow) * K + skh * 16;

    for (int k0 = 0; k0 < K; k0 += 32) {
        {
            int c = k0 + skh * 16;
            const float* gsrc = (c < 1024)
                ? Alo + (size_t)rlo * 1024 + c
                : Ahi + (size_t)r * 1024 + (c - 1024);
            float4 v0 = *reinterpret_cast<const float4*>(gsrc);
            float4 v1 = *reinterpret_cast<const float4*>(gsrc + 4);
            float4 v2 = *reinterpret_cast<const float4*>(gsrc + 8);
            float4 v3 = *reinterpret_cast<const float4*>(gsrc + 12);
            us8 c0 = {f2bf(v0.x), f2bf(v0.y), f2bf(v0.z), f2bf(v0.w),
                      f2bf(v1.x), f2bf(v1.y), f2bf(v1.z), f2bf(v1.w)};
            us8 c1 = {f2bf(v2.x), f2bf(v2.y), f2bf(v2.z), f2bf(v2.w),
                      f2bf(v3.x), f2bf(v3.y), f2bf(v3.z), f2bf(v3.w)};
            *reinterpret_cast<us8*>(&As[((skh * 2 + 0) * 128 + srow) * 8]) = c0;
            *reinterpret_cast<us8*>(&As[((skh * 2 + 1) * 128 + srow) * 8]) = c1;
            float4 w0 = *reinterpret_cast<const float4*>(gW + k0);
            float4 w1 = *reinterpret_cast<const float4*>(gW + k0 + 4);
            float4 w2 = *reinterpret_cast<const float4*>(gW + k0 + 8);
            float4 w3 = *reinterpret_cast<const float4*>(gW + k0 + 12);
            us8 d0 = {f2bf(w0.x), f2bf(w0.y), f2bf(w0.z), f2bf(w0.w),
                      f2bf(w1.x), f2bf(w1.y), f2bf(w1.z), f2bf(w1.w)};
            us8 d1 = {f2bf(w2.x), f2bf(w2.y), f2bf(w2.z), f2bf(w2.w),
                      f2bf(w3.x), f2bf(w3.y), f2bf(w3.z), f2bf(w3.w)};
            *reinterpret_cast<us8*>(&Bs[((skh * 2 + 0) * 128 + srow) * 8]) = d0;
            *reinterpret_cast<us8*>(&Bs[((skh * 2 + 1) * 128 + srow) * 8]) = d1;
        }
        __syncthreads();
        us8 a[4], b[4];
#pragma unroll
        for (int f = 0; f < 4; ++f) {
            a[f] = *reinterpret_cast<const us8*>(&As[(kc * 128 + m0 + f * 16 + lrow) * 8]);
            b[f] = *reinterpret_cast<const us8*>(&Bs[(kc * 128 + n0 + f * 16 + lrow) * 8]);
        }
#pragma unroll
        for (int fi = 0; fi < 4; ++fi)
#pragma unroll
            for (int fj = 0; fj < 4; ++fj)
                acc[fi][fj] = __builtin_amdgcn_mfma_f32_16x16x32_bf16(
                    __builtin_bit_cast(bf16x8, a[fi]),
                    __builtin_bit_cast(bf16x8, b[fj]),
                    acc[fi][fj], 0, 0, 0);
        __syncthreads();
    }

#pragma unroll
    for (int fi = 0; fi < 4; ++fi)
#pragma unroll
        for (int fj = 0; fj < 4; ++fj) {
            int cN = col0 + n0 + fj * 16 + lrow;
            float bv = 0.f;
            if (b1) bv += b1[cN];
            if (b2) bv += b2[cN];
#pragma unroll
            for (int j = 0; j < 4; ++j) {
                int rr = row0 + m0 + fi * 16 + (lane >> 4) * 4 + j;
                float v = acc[fi][fj][j] + bv;
                if (relu) v = fmaxf(v, 0.f);
                out[(size_t)rr * N + cN] = v;
            }
        }
}

__global__ void zero_flags_kernel(int* p, int n)
{
    int i = blockIdx.x * blockDim.x + threadIdx.x;
    if (i < n) p[i] = 0;
}

// ---------------------------------------------------------------------------
// Hierarchical fenceless grid barrier (256 blocks).
// Arrive: one relaxed store to this block's own flag line.
// Block 0 aggregates (256 threads x 1 flag) and broadcasts to 8 epoch lines;
// other blocks poll one epoch line with a single thread. Removes the
// 65K-concurrent-poll LLC flood of the flat barrier.
// ---------------------------------------------------------------------------
static __device__ inline void hier_arrive(int* __restrict__ flags, int phase, int tid)
{
    if (tid == 0)
        __hip_atomic_store(&flags[blockIdx.x * 32], phase,
                           __ATOMIC_RELAXED, __HIP_MEMORY_SCOPE_AGENT);
}

static __device__ inline void hier_wait(int* __restrict__ flags, int* __restrict__ epoch,
                                        int phase, int tid)
{
    if (blockIdx.x == 0) {
        // each thread polls one block's arrival flag
        while (__hip_atomic_load(&flags[tid * 32], __ATOMIC_RELAXED,
                                 __HIP_MEMORY_SCOPE_AGENT) < phase)
            __builtin_amdgcn_s_sleep(1);
        __syncthreads();
        if (tid < 8)
            __hip_atomic_store(&epoch[tid * 32], phase,
                               __ATOMIC_RELAXED, __HIP_MEMORY_SCOPE_AGENT);
    } else {
        if (tid == 0) {
            const int slot = (blockIdx.x & 7) * 32;
            while (__hip_atomic_load(&epoch[slot], __ATOMIC_RELAXED,
                                     __HIP_MEMORY_SCOPE_AGENT) < phase)
                __builtin_amdgcn_s_sleep(1);
        }
        __syncthreads();
    }
}

// ---------------------------------------------------------------------------
// Fused 2-layer persistent LSTM, 1-step software pipeline, fenceless sync.
// Grid = 256 blocks x 256 threads, 1 block/CU (LDS-limited).
// Blocks 0..127: layer 0 (step t=s).  Blocks 128..255: layer 1 (step t=s-1),
// folding y0@Wih1^T + h1@Whh1^T into one MFMA accumulator. h/y ping-pong
// buffers are exchanged via sc0sc1 (LLC-coherent) loads/stores.
// ---------------------------------------------------------------------------
__global__ __launch_bounds__(256) void lstm_fused(
    const float* __restrict__ gpre0,  // [64*32,4096] layer-0 pre-gates
    const float* __restrict__ Whh0,   // [4096,1024]
    const float* __restrict__ Wih1,   // [4096,1024]
    const float* __restrict__ Whh1,   // [4096,1024]
    const float* __restrict__ bih1, const float* __restrict__ bhh1,
    const float* __restrict__ h0all,  // [2,32,1024]
    const float* __restrict__ c0all,  // [2,32,1024]
    float* __restrict__ y1o,          // [64][32][1024] fp32
    float* __restrict__ hn,           // [2,32,1024]
    float* __restrict__ cn,           // [2,32,1024]
    unsigned short* __restrict__ hbf, // [2 layers][2 bufs][32768] bf16
    int* __restrict__ flags,          // [256*32] zeroed
    int* __restrict__ epoch)          // [8*32] zeroed
{
    __shared__ __align__(16) us8 WB[8192];   // 128 KB
    __shared__ float red2[32 * 132];         // 16.9 KB
    __shared__ float csh[256];

    const int tid  = threadIdx.x;
    const int lane = tid & 63;
    const int w    = tid >> 6;        // wave = K-quarter
    const int n    = lane & 31;
    const int kh   = lane >> 5;
    const bool isL1 = (blockIdx.x >= NBLK);
    const int lb   = isL1 ? (int)blockIdx.x - NBLK : (int)blockIdx.x;
    const int j0   = lb * 8;
    const int b    = tid >> 3;        // elementwise batch
    const int jj   = tid & 7;         // elementwise column
    const int gj   = j0 + jj;

    unsigned short* hb0 = hbf;            // layer-0 ping-pong
    unsigned short* hb1 = hbf + 65536;    // layer-1 ping-pong

    // ---- pack weights into LDS (bf16, MFMA-fragment lane-linear) ----
    const int grow = (n >> 3) * HID + j0 + (n & 7);   // gate-row g*1024 + j
    if (!isL1) {
        const float* wr = Whh0 + (size_t)grow * HID;
#pragma unroll
        for (int f = 0; f < 16; ++f) {
            int k = w * 256 + f * 16 + kh * 8;
            float4 v0 = *reinterpret_cast<const float4*>(wr + k);
            float4 v1 = *reinterpret_cast<const float4*>(wr + k + 4);
            WB[w * 1024 + f * 64 + lane] =
                (us8){f2bf(v0.x), f2bf(v0.y), f2bf(v0.z), f2bf(v0.w),
                      f2bf(v1.x), f2bf(v1.y), f2bf(v1.z), f2bf(v1.w)};
        }
    } else {
        const float* wi = Wih1 + (size_t)grow * HID;
        const float* wh = Whh1 + (size_t)grow * HID;
#pragma unroll
        for (int f = 0; f < 16; ++f) {
            int k = w * 256 + f * 16 + kh * 8;
            float4 v0 = *reinterpret_cast<const float4*>(wi + k);
            float4 v1 = *reinterpret_cast<const float4*>(wi + k + 4);
            WB[w * 1024 + f * 64 + lane] =
                (us8){f2bf(v0.x), f2bf(v0.y), f2bf(v0.z), f2bf(v0.w),
                      f2bf(v1.x), f2bf(v1.y), f2bf(v1.z), f2bf(v1.w)};
            float4 u0 = *reinterpret_cast<const float4*>(wh + k);
            float4 u1 = *reinterpret_cast<const float4*>(wh + k + 4);
            WB[4096 + w * 1024 + f * 64 + lane] =
                (us8){f2bf(u0.x), f2bf(u0.y), f2bf(u0.z), f2bf(u0.w),
                      f2bf(u1.x), f2bf(u1.y), f2bf(u1.z), f2bf(u1.w)};
        }
    }

    // ---- state init (h0 -> ping-pong via sc stores: cross-block data) ----
    csh[tid] = c0all[(isL1 ? 32768 : 0) + b * HID + gj];
    {
        int idx = lb * 256 + tid;      // 128 blocks x 256 = full 32768
        unsigned int hv = f2bf(h0all[(isL1 ? 32768 : 0) + idx]);
        GST_U16_SC((isL1 ? hb1 : hb0) + idx, hv);
    }

    float bb0 = 0, bb1 = 0, bb2 = 0, bb3 = 0;
    float gp0 = 0, gp1 = 0, gp2 = 0, gp3 = 0;
    if (isL1) {
        bb0 = bih1[gj]            + bhh1[gj];
        bb1 = bih1[HID + gj]      + bhh1[HID + gj];
        bb2 = bih1[2 * HID + gj]  + bhh1[2 * HID + gj];
        bb3 = bih1[3 * HID + gj]  + bhh1[3 * HID + gj];
    } else {
        const float* gp = gpre0 + (size_t)b * 4096 + gj;
        gp0 = gp[0]; gp1 = gp[1024]; gp2 = gp[2048]; gp3 = gp[3072];
    }

    WAIT_VM0();
    __syncthreads();
    hier_arrive(flags, 1, tid);
    hier_wait(flags, epoch, 1, tid);

    for (int s = 0; s <= T_STEPS; ++s) {
        const bool active = isL1 ? (s >= 1) : (s < T_STEPS);
        const int t = isL1 ? s - 1 : s;
        if (active) {
            f32x16 acc = {};
            if (!isL1) {
                const unsigned short* hr = hb0 + (t & 1) * 32768 + n * HID + w * 256 + kh * 8;
                us8 aF[16];
#pragma unroll
                for (int f = 0; f < 16; ++f)
                    GLD_US8_SC(aF[f], hr + f * 16);
                WAIT_VM0();
                __builtin_amdgcn_sched_barrier(0);
#pragma unroll
                for (int f = 0; f < 16; ++f)
                    acc = __builtin_amdgcn_mfma_f32_32x32x16_bf16(
                        __builtin_bit_cast(bf16x8, aF[f]),
                        __builtin_bit_cast(bf16x8, WB[w * 1024 + f * 64 + lane]),
                        acc, 0, 0, 0);
            } else {
                const unsigned short* yr = hb0 + (s & 1) * 32768 + n * HID + w * 256 + kh * 8;
                const unsigned short* hr = hb1 + (t & 1) * 32768 + n * HID + w * 256 + kh * 8;
                us8 aY[16], aH[16];
#pragma unroll
                for (int f = 0; f < 16; ++f)
                    GLD_US8_SC(aY[f], yr + f * 16);
#pragma unroll
                for (int f = 0; f < 16; ++f)
                    GLD_US8_SC(aH[f], hr + f * 16);
                WAIT_VM0();
                __builtin_amdgcn_sched_barrier(0);
#pragma unroll
                for (int f = 0; f < 16; ++f)
                    acc = __builtin_amdgcn_mfma_f32_32x32x16_bf16(
                        __builtin_bit_cast(bf16x8, aY[f]),
                        __builtin_bit_cast(bf16x8, WB[w * 1024 + f * 64 + lane]),
                        acc, 0, 0, 0);
#pragma unroll
                for (int f = 0; f < 16; ++f)
                    acc = __builtin_amdgcn_mfma_f32_32x32x16_bf16(
                        __builtin_bit_cast(bf16x8, aH[f]),
                        __builtin_bit_cast(bf16x8, WB[4096 + w * 1024 + f * 64 + lane]),
                        acc, 0, 0, 0);
            }
            // D layout: col(lane&31)=gate-row, row=(r&3)+8*(r>>2)+4*kh=batch
#pragma unroll
            for (int r = 0; r < 16; ++r) {
                int m = (r & 3) + 8 * (r >> 2) + 4 * kh;
                red2[m * 132 + w * 32 + n] = acc[r];
            }
        }
        __syncthreads();
        if (active) {
            float s0, s1v, s2v, s3v;
            if (isL1) { s0 = bb0; s1v = bb1; s2v = bb2; s3v = bb3; }
            else      { s0 = gp0; s1v = gp1; s2v = gp2; s3v = gp3; }
#pragma unroll
            for (int w2 = 0; w2 < 4; ++w2) {
                const float* rr = &red2[b * 132 + w2 * 32 + jj];
                s0  += rr[0];
                s1v += rr[8];
                s2v += rr[16];
                s3v += rr[24];
            }
            float ig = 1.f / (1.f + expf(-s0));
            float fg = 1.f / (1.f + expf(-s1v));
            float gg = tanhf(s2v);
            float og = 1.f / (1.f + expf(-s3v));
            float cv = fg * csh[tid] + ig * gg;
            csh[tid] = cv;
            float h = og * tanhf(cv);
            if (!isL1) {
                unsigned int hv = f2bf(h);
                GST_U16_SC(hb0 + ((t + 1) & 1) * 32768 + b * HID + gj, hv);  // feeds L1 even at t=63
                if (t == T_STEPS - 1) {
                    hn[b * HID + gj] = h;
                    cn[b * HID + gj] = cv;
                }
            } else {
                __builtin_nontemporal_store(h, &y1o[(size_t)t * (BATCH * HID) + b * HID + gj]);
                if (t == T_STEPS - 1) {
                    hn[32768 + b * HID + gj] = h;
                    cn[32768 + b * HID + gj] = cv;
                } else {
                    unsigned int hv = f2bf(h);
                    GST_U16_SC(hb1 + ((t + 1) & 1) * 32768 + b * HID + gj, hv);
                }
            }
        }
        if (s < T_STEPS) {
            WAIT_VM0();                      // sc-stores at coherence point
            __syncthreads();                 // whole block drained; red2 reads done
            hier_arrive(flags, s + 2, tid);
            if (!isL1 && s + 1 < T_STEPS) {  // prefetch next gpre under the spin
                const float* gp = gpre0 + (size_t)((s + 1) * BATCH + b) * 4096 + gj;
                gp0 = gp[0]; gp1 = gp[1024]; gp2 = gp[2048]; gp3 = gp[3072];
            }
            hier_wait(flags, epoch, s + 2, tid);
        }
    }
}

// ---------------------------------------------------------------------------
// Attention p
// ---------------------------------------------------------------------------
__global__ __launch_bounds__(64) void attn_p_kernel(
    const float* __restrict__ hidden1, const float* __restrict__ aw2,
    const float* __restrict__ ab2, const int* __restrict__ lengths,
    float* __restrict__ p_arr, int* __restrict__ win_arr)
{
    const int row = blockIdx.x;
    const int lane = threadIdx.x;
    float s = 0.f;
    for (int i = lane; i < 512; i += 64) s += hidden1[(size_t)row * 512 + i] * aw2[i];
    for (int off = 32; off > 0; off >>= 1) s += __shfl_down(s, off);
    if (lane == 0) {
        float v = s + ab2[0];
        float sig = 1.f / (1.f + expf(-v));
        int b = row & 31;
        float lf = (float)lengths[b];
        p_arr[row] = (float)WSZ_ + lf * sig;
        win_arr[row] = (int)rintf(lf * sig);
    }
}

__global__ void sel_gather_kernel(const float* __restrict__ enc,
                                  const int* __restrict__ win_arr,
                                  float* __restrict__ sel)
{
    const int total = BATCH * WLEN_ * HID;
    for (int idx = blockIdx.x * blockDim.x + threadIdx.x; idx < total;
         idx += gridDim.x * blockDim.x) {
        int h = idx & 1023;
        int w = (idx >> 10) % WLEN_;
        int b = idx / (WLEN_ * HID);
        int s = win_arr[(T_STEPS - 1) * BATCH + b] + w;
        sel[idx] = enc[((size_t)s * BATCH + b) * HID + h];
    }
}

__global__ __launch_bounds__(128) void attn_fused_kernel(
    const float* __restrict__ y1, const float* __restrict__ sel,
    const float* __restrict__ p_arr, const int* __restrict__ win_arr,
    const int* __restrict__ lengths, float* __restrict__ ctx)
{
    __shared__ __align__(16) float yl[1024];
    __shared__ float sv[WLEN_];
    __shared__ float av[WLEN_];
    const int row = blockIdx.x;
    const int b   = row & 31;
    const int tid = threadIdx.x;

    for (int i = tid; i < 1024; i += 128) yl[i] = y1[(size_t)row * HID + i];
    __syncthreads();

    const int win = win_arr[row];
    const float p = p_arr[row];
    const int len = lengths[b];

    if (tid < WLEN_) {
        const float4* s4 = reinterpret_cast<const float4*>(sel + ((size_t)b * WLEN_ + tid) * HID);
        const float4* y4 = reinterpret_cast<const float4*>(yl);
        float acc = 0.f;
        for (int q = 0; q < 256; ++q) {
            float4 a = s4[q]; float4 yy = y4[q];
            acc += a.x * yy.x + a.y * yy.y + a.z * yy.z + a.w * yy.w;
        }
        bool lo = tid < (WSZ_ - win);
        bool hi = tid >= (len + WSZ_ - win);
        sv[tid] = (lo || hi) ? 1e-14f : acc;
    }
    __syncthreads();

    float mx = -1e30f;
    for (int w = 0; w < WLEN_; ++w) mx = fmaxf(mx, sv[w]);
    float sum = 0.f;
    for (int w = 0; w < WLEN_; ++w) sum += expf(sv[w] - mx);
    if (tid < WLEN_) {
        float e = expf(sv[tid] - mx) / sum;
        float d = (float)(win + tid) - p;
        av[tid] = e * expf(-(d * d) / 1250.f);
    }
    __syncthreads();

    float acc[8] = {0, 0, 0, 0, 0, 0, 0, 0};
    for (int w = 0; w < WLEN_; ++w) {
        float a = av[w];
        const float* srow = sel + ((size_t)b * WLEN_ + w) * HID;
#pragma unroll
        for (int i = 0; i < 8; ++i) acc[i] += a * srow[tid + 128 * i];
    }
    for (int i = 0; i < 8; ++i) ctx[(size_t)row * HID + tid + 128 * i] = acc[i];
}

// ---------------------------------------------------------------------------
extern "C" void kernel_launch(void* const* d_in, const int* in_sizes, int n_in,
                              void* d_out, int out_size, void* d_ws, size_t ws_size,
                              hipStream_t stream)
{
    const float* enc   = (const float*)d_in[0];
    const float* ctxin = (const float*)d_in[1];
    const float* h0    = (const float*)d_in[2];
    const float* c0    = (const float*)d_in[3];
    const float* emb   = (const float*)d_in[4];
    const float* aw1   = (const float*)d_in[5];
    const float* ab1   = (const float*)d_in[6];
    const float* aw2   = (const float*)d_in[7];
    const float* ab2   = (const float*)d_in[8];
    const float* Wih0  = (const float*)d_in[9];
    const float* Whh0  = (const float*)d_in[10];
    const float* bih0  = (const float*)d_in[11];
    const float* bhh0  = (const float*)d_in[12];
    const float* Wih1  = (const float*)d_in[13];
    const float* Whh1  = (const float*)d_in[14];
    const float* bih1  = (const float*)d_in[15];
    const float* bhh1  = (const float*)d_in[16];
    const float* fc1w  = (const float*)d_in[17];
    const float* fc1b  = (const float*)d_in[18];
    const float* fc2w  = (const float*)d_in[19];
    const float* fc2b  = (const float*)d_in[20];
    const int*   tw    = (const int*)d_in[21];
    const int*   lens  = (const int*)d_in[22];

    float* ws = (float*)d_ws;
    float* buf_fc1out  = ws;                         // 2048x1024
    float* buf_gates   = ws + 4194304;               // gates0 2048x4096
    float* buf_y1      = ws + 14680064;              // 2048x1024
    unsigned short* buf_hbf = (unsigned short*)(ws + 16777216);  // 4 x 32768 bf16
    int*   buf_flags   = (int*)(ws + 16842752);      // 256*32 ints
    int*   buf_epoch   = buf_flags + 8192;           // 8*32 ints
    float* buf_hidden1 = ws + 16875520;
    float* buf_p       = ws + 17924096;
    int*   buf_win     = (int*)(ws + 17926144);
    float* buf_sel     = ws + 17928192;

    float* out   = (float*)d_out;
    float* out_hn  = out + Y_SZ;
    float* out_cn  = out + Y_SZ + HN_SZ;
    float* out_ctx = out + CTX_OFF;

    // 0. zero barrier flags + epoch (8192 + 256 ints)
    zero_flags_kernel<<<33, 256, 0, stream>>>(buf_flags, 8448);

    // 1. gates0_pre = [emb[tw], ctx] @ Wih0^T + bih0 + bhh0  (fused embed+concat)
    gemm_mfma_cat<<<dim3(4096 / 128, 2048 / 128), 256, 0, stream>>>(
        emb, ctxin, tw, Wih0, bih0, bhh0, buf_gates, 2048, 4096, 0);

    // 2. Both LSTM layers, fused persistent pipeline (hierarchical barrier)
    lstm_fused<<<2 * NBLK, 256, 0, stream>>>(
        buf_gates, Whh0, Wih1, Whh1, bih1, bhh1, h0, c0,
        buf_y1, out_hn, out_cn, buf_hbf, buf_flags, buf_epoch);

    // 3. Attention (fp32, exact window/p path)
    gemm_bt<<<dim3(512 / 64, 2048 / 128), 256, 0, stream>>>(
        buf_y1, aw1, ab1, nullptr, buf_hidden1, 2048, 512, 1024, 2 /*tanh*/);
    attn_p_kernel<<<2048, 64, 0, stream>>>(buf_hidden1, aw2, ab2, lens, buf_p, buf_win);
    sel_gather_kernel<<<2048, 256, 0, stream>>>(enc, buf_win, buf_sel);
    attn_fused_kernel<<<2048, 128, 0, stream>>>(buf_y1, buf_sel, buf_p, buf_win, lens, out_ctx);

    // 4. fc1 = relu([ctx, y1] @ fc1_w^T + fc1_b)  (fused concat)
    gemm_mfma_cat<<<dim3(1024 / 128, 2048 / 128), 256, 0, stream>>>(
        out_ctx, buf_y1, nullptr, fc1w, fc1b, nullptr, buf_fc1out, 2048, 1024, 1 /*relu*/);

    // 5. fc2: y = fc1out @ fc2_w^T + fc2_b
    gemm_mfma_bt<<<dim3(VOCAB / 128, 2048 / 128), 256, 0, stream>>>(
        buf_fc1out, fc2w, fc2b, nullptr, out, 2048, VOCAB, 1024, 0);
}

// Round 8
// 1142.625 us; speedup vs baseline: 8.9175x; 1.1272x over previous
//
#include <hip/hip_runtime.h>
#include <hip/hip_bf16.h>

// Problem constants
#define T_STEPS 64
#define BATCH   32
#define HID     1024
#define VOCAB   32000
#define WLEN_   101
#define WSZ_    50
#define SENC    229
#define NBLK    128     // blocks per LSTM layer; fused grid = 2*NBLK = 256 = #CUs

static const size_t Y_SZ   = (size_t)T_STEPS * BATCH * VOCAB;   // 65,536,000
static const size_t HN_SZ  = (size_t)2 * BATCH * HID;           // 65,536
static const size_t CTX_OFF = Y_SZ + 2 * HN_SZ;                 // y + h_n + c_n

typedef __attribute__((ext_vector_type(8)))  unsigned short us8;
typedef __attribute__((ext_vector_type(8)))  __bf16 bf16x8;
typedef __attribute__((ext_vector_type(4)))  float f32x4;
typedef __attribute__((ext_vector_type(16))) float f32x16;

static __device__ inline unsigned short f2bf(float x) {
    __hip_bfloat16 b = __float2bfloat16(x);
    return __builtin_bit_cast(unsigned short, b);
}

// Coherence-point (Infinity-Cache) accesses for the LSTM cross-block exchange.
#define GLD_US8_SC(dst, ptr) \
    asm volatile("global_load_dwordx4 %0, %1, off sc0 sc1" : "=v"(dst) : "v"(ptr) : "memory")
#define GST_U16_SC(ptr, val) \
    asm volatile("global_store_short %0, %1, off sc0 sc1" :: "v"(ptr), "v"(val) : "memory")
#define WAIT_VM0() asm volatile("s_waitcnt vmcnt(0)" ::: "memory")

// ---------------------------------------------------------------------------
// fp32 GEMM (attn-proj path only — keeps window indices exact)
// ---------------------------------------------------------------------------
__global__ __launch_bounds__(256) void gemm_bt(
    const float* __restrict__ A, const float* __restrict__ W,
    const float* __restrict__ b1, const float* __restrict__ b2,
    float* __restrict__ out, int M, int N, int K, int act)
{
    __shared__ __align__(16) float As[16 * 132];
    __shared__ __align__(16) float Ws[16 * 68];
    const int tid  = threadIdx.x;
    const int col0 = blockIdx.x * 64;
    const int row0 = blockIdx.y * 128;
    const int ty   = tid >> 4;
    const int tx   = tid & 15;

    float acc[8][4];
#pragma unroll
    for (int i = 0; i < 8; ++i)
#pragma unroll
        for (int j = 0; j < 4; ++j) acc[i][j] = 0.f;

    for (int k0 = 0; k0 < K; k0 += 16) {
#pragma unroll
        for (int li = 0; li < 2; ++li) {
            int f  = tid + li * 256;
            int r  = f >> 2;
            int kq = (f & 3) << 2;
            float4 v = *reinterpret_cast<const float4*>(A + (size_t)(row0 + r) * K + k0 + kq);
            As[(kq + 0) * 132 + r] = v.x;
            As[(kq + 1) * 132 + r] = v.y;
            As[(kq + 2) * 132 + r] = v.z;
            As[(kq + 3) * 132 + r] = v.w;
        }
        {
            int n  = tid >> 2;
            int kq = (tid & 3) << 2;
            float4 v = *reinterpret_cast<const float4*>(W + (size_t)(col0 + n) * K + k0 + kq);
            Ws[(kq + 0) * 68 + n] = v.x;
            Ws[(kq + 1) * 68 + n] = v.y;
            Ws[(kq + 2) * 68 + n] = v.z;
            Ws[(kq + 3) * 68 + n] = v.w;
        }
        __syncthreads();
#pragma unroll
        for (int k = 0; k < 16; ++k) {
            const float4 a0 = *reinterpret_cast<const float4*>(&As[k * 132 + ty * 8]);
            const float4 a1 = *reinterpret_cast<const float4*>(&As[k * 132 + ty * 8 + 4]);
            const float4 b0 = *reinterpret_cast<const float4*>(&Ws[k * 68 + tx * 4]);
            float av[8] = {a0.x, a0.y, a0.z, a0.w, a1.x, a1.y, a1.z, a1.w};
            float bv[4] = {b0.x, b0.y, b0.z, b0.w};
#pragma unroll
            for (int i = 0; i < 8; ++i)
#pragma unroll
                for (int j = 0; j < 4; ++j) acc[i][j] = fmaf(av[i], bv[j], acc[i][j]);
        }
        __syncthreads();
    }

#pragma unroll
    for (int j = 0; j < 4; ++j) {
        int n = col0 + tx * 4 + j;
        float bias = 0.f;
        if (b1) bias += b1[n];
        if (b2) bias += b2[n];
#pragma unroll
        for (int i = 0; i < 8; ++i) {
            float v = acc[i][j] + bias;
            if (act == 1) v = fmaxf(v, 0.f);
            else if (act == 2) v = tanhf(v);
            out[(size_t)(row0 + ty * 8 + i) * N + n] = v;
        }
    }
}

// ---------------------------------------------------------------------------
// bf16 MFMA GEMM, m97-style: pure-bf16 inputs, global_load_lds(16B) staging
// with pre-swizzled global source + XOR-swizzled ds_read (conflict-free),
// 128x128 tile, BK=64, 4 waves (2x2 of 64x64), bijective XCD swizzle with
// M-major ordering (same-W-column blocks land on one XCD's L2).
// out (fp32) and/or out_bf (bf16) may each be null.
// Requires M%128==0, N%128==0, K%64==0.
// ---------------------------------------------------------------------------
__global__ __launch_bounds__(256) void gemm_lds_bt(
    const unsigned short* __restrict__ A, const unsigned short* __restrict__ W,
    const float* __restrict__ b1, const float* __restrict__ b2,
    float* __restrict__ out, unsigned short* __restrict__ out_bf,
    int M, int N, int K, int relu)
{
    __shared__ __align__(16) unsigned short As[8192];   // [128 rows][64] bf16, 16 KB
    __shared__ __align__(16) unsigned short Ws[8192];
    const int tid  = threadIdx.x;
    const int lane = tid & 63;
    const int wave = tid >> 6;

    // bijective XCD swizzle (m204), M-major tile decomposition
    const int nwg = gridDim.x;
    const int bid = blockIdx.x;
    const int q = nwg >> 3, r8 = nwg & 7;
    const int xcd = bid & 7, sidx = bid >> 3;
    const int wgid = (xcd < r8 ? xcd * (q + 1) : r8 * (q + 1) + (xcd - r8) * q) + sidx;
    const int mt = M >> 7;
    const int row0 = (wgid % mt) << 7;
    const int col0 = (wgid / mt) << 7;

    const int m0   = (wave >> 1) * 64;
    const int n0   = (wave & 1) * 64;
    const int lrow = lane & 15;
    const int kc   = lane >> 4;

    f32x4 acc[4][4];
#pragma unroll
    for (int i = 0; i < 4; ++i)
#pragma unroll
        for (int j = 0; j < 4; ++j) acc[i][j] = (f32x4){0.f, 0.f, 0.f, 0.f};

    // staging: waves 0,1 -> A; waves 2,3 -> W. 8 insts x 64 lanes x 16B each.
    const bool isA = (wave < 2);
    const int  lw  = wave & 1;
    const unsigned short* gbase = isA ? (A + (size_t)row0 * K) : (W + (size_t)col0 * K);
    unsigned short* lbase = isA ? As : Ws;

    for (int k0 = 0; k0 < K; k0 += 64) {
#pragma unroll
        for (int i = 0; i < 8; ++i) {
            const int c    = lw * 512 + i * 64 + lane;   // chunk 0..1023
            const int row  = c >> 3;                      // 8 slots/row (128B row)
            const int slot = c & 7;
            // LDS[row][slot] receives global slot (slot ^ (row&7))  [involution]
            const unsigned short* src =
                gbase + (size_t)row * K + k0 + ((slot ^ (row & 7)) << 3);
            __builtin_amdgcn_global_load_lds(
                (const __attribute__((address_space(1))) void*)src,
                (__attribute__((address_space(3))) void*)(lbase + (size_t)(lw * 512 + i * 64) * 8),
                16, 0, 0);
        }
        __syncthreads();
#pragma unroll
        for (int ss = 0; ss < 2; ++ss) {
            us8 a[4], b[4];
#pragma unroll
            for (int f = 0; f < 4; ++f) {
                const int ar = m0 + f * 16 + lrow;
                const int as = (ss * 4 + kc) ^ (ar & 7);
                a[f] = *reinterpret_cast<const us8*>(&As[(ar * 8 + as) * 8]);
                const int br = n0 + f * 16 + lrow;
                const int bs = (ss * 4 + kc) ^ (br & 7);
                b[f] = *reinterpret_cast<const us8*>(&Ws[(br * 8 + bs) * 8]);
            }
#pragma unroll
            for (int fi = 0; fi < 4; ++fi)
#pragma unroll
                for (int fj = 0; fj < 4; ++fj)
                    acc[fi][fj] = __builtin_amdgcn_mfma_f32_16x16x32_bf16(
                        __builtin_bit_cast(bf16x8, a[fi]),
                        __builtin_bit_cast(bf16x8, b[fj]),
                        acc[fi][fj], 0, 0, 0);
        }
        __syncthreads();
    }

    // epilogue: C/D layout col=lane&15, row=(lane>>4)*4+j
#pragma unroll
    for (int fi = 0; fi < 4; ++fi)
#pragma unroll
        for (int fj = 0; fj < 4; ++fj) {
            const int cN = col0 + n0 + fj * 16 + lrow;
            float bv = 0.f;
            if (b1) bv += b1[cN];
            if (b2) bv += b2[cN];
#pragma unroll
            for (int j = 0; j < 4; ++j) {
                const int r = row0 + m0 + fi * 16 + (lane >> 4) * 4 + j;
                float v = acc[fi][fj][j] + bv;
                if (relu) v = fmaxf(v, 0.f);
                if (out)    out[(size_t)r * N + cN] = v;
                if (out_bf) out_bf[(size_t)r * N + cN] = f2bf(v);
            }
        }
}

// ---------------------------------------------------------------------------
// fp32 -> bf16 bulk convert (n8 = n/8 chunks)
// ---------------------------------------------------------------------------
__global__ void cvt_bf16_kernel(const float* __restrict__ src,
                                unsigned short* __restrict__ dst, int n8)
{
    for (int i = blockIdx.x * blockDim.x + threadIdx.x; i < n8;
         i += gridDim.x * blockDim.x) {
        float4 v0 = *reinterpret_cast<const float4*>(src + (size_t)i * 8);
        float4 v1 = *reinterpret_cast<const float4*>(src + (size_t)i * 8 + 4);
        us8 c = {f2bf(v0.x), f2bf(v0.y), f2bf(v0.z), f2bf(v0.w),
                 f2bf(v1.x), f2bf(v1.y), f2bf(v1.z), f2bf(v1.w)};
        *reinterpret_cast<us8*>(dst + (size_t)i * 8) = c;
    }
}

// ---------------------------------------------------------------------------
// Embedding lookup + input-feeding concat, bf16 output x_bf[2048][2048]
// ---------------------------------------------------------------------------
__global__ void embed_concat_bf_kernel(const float* __restrict__ emb,
                                       const float* __restrict__ ctxin,
                                       const int* __restrict__ tw,
                                       unsigned short* __restrict__ x_bf)
{
    const int total = 2048 * 256;   // 8-elem chunks
    for (int idx = blockIdx.x * blockDim.x + threadIdx.x; idx < total;
         idx += gridDim.x * blockDim.x) {
        int row = idx >> 8;
        int c8  = idx & 255;
        const float* src = (c8 < 128)
            ? emb + (size_t)tw[row] * HID + c8 * 8
            : ctxin + (size_t)row * HID + (c8 - 128) * 8;
        float4 v0 = *reinterpret_cast<const float4*>(src);
        float4 v1 = *reinterpret_cast<const float4*>(src + 4);
        us8 c = {f2bf(v0.x), f2bf(v0.y), f2bf(v0.z), f2bf(v0.w),
                 f2bf(v1.x), f2bf(v1.y), f2bf(v1.z), f2bf(v1.w)};
        *reinterpret_cast<us8*>(x_bf + (size_t)idx * 8) = c;
    }
}

__global__ void zero_flags_kernel(int* p, int n)
{
    int i = blockIdx.x * blockDim.x + threadIdx.x;
    if (i < n) p[i] = 0;
}

// ---------------------------------------------------------------------------
// Hierarchical fenceless grid barrier (256 blocks).
// ---------------------------------------------------------------------------
static __device__ inline void hier_arrive(int* __restrict__ flags, int phase, int tid)
{
    if (tid == 0)
        __hip_atomic_store(&flags[blockIdx.x * 32], phase,
                           __ATOMIC_RELAXED, __HIP_MEMORY_SCOPE_AGENT);
}

static __device__ inline void hier_wait(int* __restrict__ flags, int* __restrict__ epoch,
                                        int phase, int tid)
{
    if (blockIdx.x == 0) {
        while (__hip_atomic_load(&flags[tid * 32], __ATOMIC_RELAXED,
                                 __HIP_MEMORY_SCOPE_AGENT) < phase)
            __builtin_amdgcn_s_sleep(1);
        __syncthreads();
        if (tid < 8)
            __hip_atomic_store(&epoch[tid * 32], phase,
                               __ATOMIC_RELAXED, __HIP_MEMORY_SCOPE_AGENT);
    } else {
        if (tid == 0) {
            const int slot = (blockIdx.x & 7) * 32;
            while (__hip_atomic_load(&epoch[slot], __ATOMIC_RELAXED,
                                     __HIP_MEMORY_SCOPE_AGENT) < phase)
                __builtin_amdgcn_s_sleep(1);
        }
        __syncthreads();
    }
}

// ---------------------------------------------------------------------------
// Fused 2-layer persistent LSTM (unchanged structure; now also emits bf16 y1
// directly into the fc1 concat buffer fin_bf[row][1024..2048)).
// ---------------------------------------------------------------------------
__global__ __launch_bounds__(256) void lstm_fused(
    const float* __restrict__ gpre0,  // [64*32,4096] layer-0 pre-gates
    const float* __restrict__ Whh0,   // [4096,1024]
    const float* __restrict__ Wih1,   // [4096,1024]
    const float* __restrict__ Whh1,   // [4096,1024]
    const float* __restrict__ bih1, const float* __restrict__ bhh1,
    const float* __restrict__ h0all,  // [2,32,1024]
    const float* __restrict__ c0all,  // [2,32,1024]
    float* __restrict__ y1o,          // [64][32][1024] fp32
    unsigned short* __restrict__ fin_bf, // [2048][2048] bf16 (hi half filled here)
    float* __restrict__ hn,           // [2,32,1024]
    float* __restrict__ cn,           // [2,32,1024]
    unsigned short* __restrict__ hbf, // [2 layers][2 bufs][32768] bf16
    int* __restrict__ flags,          // [256*32] zeroed
    int* __restrict__ epoch)          // [8*32] zeroed
{
    __shared__ __align__(16) us8 WB[8192];   // 128 KB
    __shared__ float red2[32 * 132];         // 16.9 KB
    __shared__ float csh[256];

    const int tid  = threadIdx.x;
    const int lane = tid & 63;
    const int w    = tid >> 6;        // wave = K-quarter
    const int n    = lane & 31;
    const int kh   = lane >> 5;
    const bool isL1 = (blockIdx.x >= NBLK);
    const int lb   = isL1 ? (int)blockIdx.x - NBLK : (int)blockIdx.x;
    const int j0   = lb * 8;
    const int b    = tid >> 3;        // elementwise batch
    const int jj   = tid & 7;         // elementwise column
    const int gj   = j0 + jj;

    unsigned short* hb0 = hbf;            // layer-0 ping-pong
    unsigned short* hb1 = hbf + 65536;    // layer-1 ping-pong

    // ---- pack weights into LDS (bf16, MFMA-fragment lane-linear) ----
    const int grow = (n >> 3) * HID + j0 + (n & 7);   // gate-row g*1024 + j
    if (!isL1) {
        const float* wr = Whh0 + (size_t)grow * HID;
#pragma unroll
        for (int f = 0; f < 16; ++f) {
            int k = w * 256 + f * 16 + kh * 8;
            float4 v0 = *reinterpret_cast<const float4*>(wr + k);
            float4 v1 = *reinterpret_cast<const float4*>(wr + k + 4);
            WB[w * 1024 + f * 64 + lane] =
                (us8){f2bf(v0.x), f2bf(v0.y), f2bf(v0.z), f2bf(v0.w),
                      f2bf(v1.x), f2bf(v1.y), f2bf(v1.z), f2bf(v1.w)};
        }
    } else {
        const float* wi = Wih1 + (size_t)grow * HID;
        const float* wh = Whh1 + (size_t)grow * HID;
#pragma unroll
        for (int f = 0; f < 16; ++f) {
            int k = w * 256 + f * 16 + kh * 8;
            float4 v0 = *reinterpret_cast<const float4*>(wi + k);
            float4 v1 = *reinterpret_cast<const float4*>(wi + k + 4);
            WB[w * 1024 + f * 64 + lane] =
                (us8){f2bf(v0.x), f2bf(v0.y), f2bf(v0.z), f2bf(v0.w),
                      f2bf(v1.x), f2bf(v1.y), f2bf(v1.z), f2bf(v1.w)};
            float4 u0 = *reinterpret_cast<const float4*>(wh + k);
            float4 u1 = *reinterpret_cast<const float4*>(wh + k + 4);
            WB[4096 + w * 1024 + f * 64 + lane] =
                (us8){f2bf(u0.x), f2bf(u0.y), f2bf(u0.z), f2bf(u0.w),
                      f2bf(u1.x), f2bf(u1.y), f2bf(u1.z), f2bf(u1.w)};
        }
    }

    // ---- state init ----
    csh[tid] = c0all[(isL1 ? 32768 : 0) + b * HID + gj];
    {
        int idx = lb * 256 + tid;      // 128 blocks x 256 = full 32768
        unsigned int hv = f2bf(h0all[(isL1 ? 32768 : 0) + idx]);
        GST_U16_SC((isL1 ? hb1 : hb0) + idx, hv);
    }

    float bb0 = 0, bb1 = 0, bb2 = 0, bb3 = 0;
    float gp0 = 0, gp1 = 0, gp2 = 0, gp3 = 0;
    if (isL1) {
        bb0 = bih1[gj]            + bhh1[gj];
        bb1 = bih1[HID + gj]      + bhh1[HID + gj];
        bb2 = bih1[2 * HID + gj]  + bhh1[2 * HID + gj];
        bb3 = bih1[3 * HID + gj]  + bhh1[3 * HID + gj];
    } else {
        const float* gp = gpre0 + (size_t)b * 4096 + gj;
        gp0 = gp[0]; gp1 = gp[1024]; gp2 = gp[2048]; gp3 = gp[3072];
    }

    WAIT_VM0();
    __syncthreads();
    hier_arrive(flags, 1, tid);
    hier_wait(flags, epoch, 1, tid);

    for (int s = 0; s <= T_STEPS; ++s) {
        const bool active = isL1 ? (s >= 1) : (s < T_STEPS);
        const int t = isL1 ? s - 1 : s;
        if (active) {
            f32x16 acc = {};
            if (!isL1) {
                const unsigned short* hr = hb0 + (t & 1) * 32768 + n * HID + w * 256 + kh * 8;
                us8 aF[16];
#pragma unroll
                for (int f = 0; f < 16; ++f)
                    GLD_US8_SC(aF[f], hr + f * 16);
                WAIT_VM0();
                __builtin_amdgcn_sched_barrier(0);
#pragma unroll
                for (int f = 0; f < 16; ++f)
                    acc = __builtin_amdgcn_mfma_f32_32x32x16_bf16(
                        __builtin_bit_cast(bf16x8, aF[f]),
                        __builtin_bit_cast(bf16x8, WB[w * 1024 + f * 64 + lane]),
                        acc, 0, 0, 0);
            } else {
                const unsigned short* yr = hb0 + (s & 1) * 32768 + n * HID + w * 256 + kh * 8;
                const unsigned short* hr = hb1 + (t & 1) * 32768 + n * HID + w * 256 + kh * 8;
                us8 aY[16], aH[16];
#pragma unroll
                for (int f = 0; f < 16; ++f)
                    GLD_US8_SC(aY[f], yr + f * 16);
#pragma unroll
                for (int f = 0; f < 16; ++f)
                    GLD_US8_SC(aH[f], hr + f * 16);
                WAIT_VM0();
                __builtin_amdgcn_sched_barrier(0);
#pragma unroll
                for (int f = 0; f < 16; ++f)
                    acc = __builtin_amdgcn_mfma_f32_32x32x16_bf16(
                        __builtin_bit_cast(bf16x8, aY[f]),
                        __builtin_bit_cast(bf16x8, WB[w * 1024 + f * 64 + lane]),
                        acc, 0, 0, 0);
#pragma unroll
                for (int f = 0; f < 16; ++f)
                    acc = __builtin_amdgcn_mfma_f32_32x32x16_bf16(
                        __builtin_bit_cast(bf16x8, aH[f]),
                        __builtin_bit_cast(bf16x8, WB[4096 + w * 1024 + f * 64 + lane]),
                        acc, 0, 0, 0);
            }
            // D layout: col(lane&31)=gate-row, row=(r&3)+8*(r>>2)+4*kh=batch
#pragma unroll
            for (int r = 0; r < 16; ++r) {
                int m = (r & 3) + 8 * (r >> 2) + 4 * kh;
                red2[m * 132 + w * 32 + n] = acc[r];
            }
        }
        __syncthreads();
        if (active) {
            float s0, s1v, s2v, s3v;
            if (isL1) { s0 = bb0; s1v = bb1; s2v = bb2; s3v = bb3; }
            else      { s0 = gp0; s1v = gp1; s2v = gp2; s3v = gp3; }
#pragma unroll
            for (int w2 = 0; w2 < 4; ++w2) {
                const float* rr = &red2[b * 132 + w2 * 32 + jj];
                s0  += rr[0];
                s1v += rr[8];
                s2v += rr[16];
                s3v += rr[24];
            }
            float ig = 1.f / (1.f + expf(-s0));
            float fg = 1.f / (1.f + expf(-s1v));
            float gg = tanhf(s2v);
            float og = 1.f / (1.f + expf(-s3v));
            float cv = fg * csh[tid] + ig * gg;
            csh[tid] = cv;
            float h = og * tanhf(cv);
            if (!isL1) {
                unsigned int hv = f2bf(h);
                GST_U16_SC(hb0 + ((t + 1) & 1) * 32768 + b * HID + gj, hv);  // feeds L1 even at t=63
                if (t == T_STEPS - 1) {
                    hn[b * HID + gj] = h;
                    cn[b * HID + gj] = cv;
                }
            } else {
                __builtin_nontemporal_store(h, &y1o[(size_t)t * (BATCH * HID) + b * HID + gj]);
                fin_bf[(size_t)(t * BATCH + b) * 2048 + 1024 + gj] = f2bf(h);
                if (t == T_STEPS - 1) {
                    hn[32768 + b * HID + gj] = h;
                    cn[32768 + b * HID + gj] = cv;
                } else {
                    unsigned int hv = f2bf(h);
                    GST_U16_SC(hb1 + ((t + 1) & 1) * 32768 + b * HID + gj, hv);
                }
            }
        }
        if (s < T_STEPS) {
            WAIT_VM0();
            __syncthreads();
            hier_arrive(flags, s + 2, tid);
            if (!isL1 && s + 1 < T_STEPS) {
                const float* gp = gpre0 + (size_t)((s + 1) * BATCH + b) * 4096 + gj;
                gp0 = gp[0]; gp1 = gp[1024]; gp2 = gp[2048]; gp3 = gp[3072];
            }
            hier_wait(flags, epoch, s + 2, tid);
        }
    }
}

// ---------------------------------------------------------------------------
// Attention
// ---------------------------------------------------------------------------
__global__ __launch_bounds__(64) void attn_p_kernel(
    const float* __restrict__ hidden1, const float* __restrict__ aw2,
    const float* __restrict__ ab2, const int* __restrict__ lengths,
    float* __restrict__ p_arr, int* __restrict__ win_arr)
{
    const int row = blockIdx.x;
    const int lane = threadIdx.x;
    float s = 0.f;
    for (int i = lane; i < 512; i += 64) s += hidden1[(size_t)row * 512 + i] * aw2[i];
    for (int off = 32; off > 0; off >>= 1) s += __shfl_down(s, off);
    if (lane == 0) {
        float v = s + ab2[0];
        float sig = 1.f / (1.f + expf(-v));
        int b = row & 31;
        float lf = (float)lengths[b];
        p_arr[row] = (float)WSZ_ + lf * sig;
        win_arr[row] = (int)rintf(lf * sig);
    }
}

__global__ void sel_gather_kernel(const float* __restrict__ enc,
                                  const int* __restrict__ win_arr,
                                  float* __restrict__ sel)
{
    const int total = BATCH * WLEN_ * HID;
    for (int idx = blockIdx.x * blockDim.x + threadIdx.x; idx < total;
         idx += gridDim.x * blockDim.x) {
        int h = idx & 1023;
        int w = (idx >> 10) % WLEN_;
        int b = idx / (WLEN_ * HID);
        int s = win_arr[(T_STEPS - 1) * BATCH + b] + w;
        sel[idx] = enc[((size_t)s * BATCH + b) * HID + h];
    }
}

__global__ __launch_bounds__(128) void attn_fused_kernel(
    const float* __restrict__ y1, const float* __restrict__ sel,
    const float* __restrict__ p_arr, const int* __restrict__ win_arr,
    const int* __restrict__ lengths, float* __restrict__ ctx,
    unsigned short* __restrict__ fin_bf)
{
    __shared__ __align__(16) float yl[1024];
    __shared__ float sv[WLEN_];
    __shared__ float av[WLEN_];
    const int row = blockIdx.x;
    const int b   = row & 31;
    const int tid = threadIdx.x;

    for (int i = tid; i < 1024; i += 128) yl[i] = y1[(size_t)row * HID + i];
    __syncthreads();

    const int win = win_arr[row];
    const float p = p_arr[row];
    const int len = lengths[b];

    if (tid < WLEN_) {
        const float4* s4 = reinterpret_cast<const float4*>(sel + ((size_t)b * WLEN_ + tid) * HID);
        const float4* y4 = reinterpret_cast<const float4*>(yl);
        float acc = 0.f;
        for (int q = 0; q < 256; ++q) {
            float4 a = s4[q]; float4 yy = y4[q];
            acc += a.x * yy.x + a.y * yy.y + a.z * yy.z + a.w * yy.w;
        }
        bool lo = tid < (WSZ_ - win);
        bool hi = tid >= (len + WSZ_ - win);
        sv[tid] = (lo || hi) ? 1e-14f : acc;
    }
    __syncthreads();

    float mx = -1e30f;
    for (int w = 0; w < WLEN_; ++w) mx = fmaxf(mx, sv[w]);
    float sum = 0.f;
    for (int w = 0; w < WLEN_; ++w) sum += expf(sv[w] - mx);
    if (tid < WLEN_) {
        float e = expf(sv[tid] - mx) / sum;
        float d = (float)(win + tid) - p;
        av[tid] = e * expf(-(d * d) / 1250.f);
    }
    __syncthreads();

    float acc[8] = {0, 0, 0, 0, 0, 0, 0, 0};
    for (int w = 0; w < WLEN_; ++w) {
        float a = av[w];
        const float* srow = sel + ((size_t)b * WLEN_ + w) * HID;
#pragma unroll
        for (int i = 0; i < 8; ++i) acc[i] += a * srow[tid + 128 * i];
    }
    for (int i = 0; i < 8; ++i) {
        ctx[(size_t)row * HID + tid + 128 * i] = acc[i];
        fin_bf[(size_t)row * 2048 + tid + 128 * i] = f2bf(acc[i]);
    }
}

// ---------------------------------------------------------------------------
extern "C" void kernel_launch(void* const* d_in, const int* in_sizes, int n_in,
                              void* d_out, int out_size, void* d_ws, size_t ws_size,
                              hipStream_t stream)
{
    const float* enc   = (const float*)d_in[0];
    const float* ctxin = (const float*)d_in[1];
    const float* h0    = (const float*)d_in[2];
    const float* c0    = (const float*)d_in[3];
    const float* emb   = (const float*)d_in[4];
    const float* aw1   = (const float*)d_in[5];
    const float* ab1   = (const float*)d_in[6];
    const float* aw2   = (const float*)d_in[7];
    const float* ab2   = (const float*)d_in[8];
    const float* Wih0  = (const float*)d_in[9];
    const float* Whh0  = (const float*)d_in[10];
    const float* bih0  = (const float*)d_in[11];
    const float* bhh0  = (const float*)d_in[12];
    const float* Wih1  = (const float*)d_in[13];
    const float* Whh1  = (const float*)d_in[14];
    const float* bih1  = (const float*)d_in[15];
    const float* bhh1  = (const float*)d_in[16];
    const float* fc1w  = (const float*)d_in[17];
    const float* fc1b  = (const float*)d_in[18];
    const float* fc2w  = (const float*)d_in[19];
    const float* fc2b  = (const float*)d_in[20];
    const int*   tw    = (const int*)d_in[21];
    const int*   lens  = (const int*)d_in[22];

    float* ws = (float*)d_ws;
    // --- dead-early region [0 .. 16,384,000 floats), reused by fc2w_bf ---
    float*          buf_gates = ws;                                   // 8,388,608 fl
    unsigned short* x_bf      = (unsigned short*)(ws + 8388608);      // 4,194,304 sh
    unsigned short* Wih0_bf   = (unsigned short*)(ws + 10485760);     // 8,388,608 sh
    unsigned short* fc2w_bf   = (unsigned short*)ws;                  // 32,768,000 sh (alias, post-LSTM)
    // --- live-late region ---
    float*          buf_y1    = ws + 16384000;                        // 2,097,152 fl
    unsigned short* buf_hbf   = (unsigned short*)(ws + 18481152);     // 131,072 sh
    int*            buf_flags = (int*)(ws + 18546688);                // 8,448 ints
    int*            buf_epoch = buf_flags + 8192;
    float*          buf_hidden1 = ws + 18555136;                      // 1,048,576 fl
    float*          buf_p     = ws + 19603712;                        // 2,048
    int*            buf_win   = (int*)(ws + 19605760);                // 2,048
    float*          buf_sel   = ws + 19607808;                        // 3,309,568 fl
    unsigned short* fin_bf    = (unsigned short*)(ws + 22917376);     // 4,194,304 sh
    unsigned short* fc1w_bf   = (unsigned short*)(ws + 25014528);     // 2,097,152 sh
    unsigned short* fc1out_bf = (unsigned short*)(ws + 26063104);     // 2,097,152 sh

    float* out   = (float*)d_out;
    float* out_hn  = out + Y_SZ;
    float* out_cn  = out + Y_SZ + HN_SZ;
    float* out_ctx = out + CTX_OFF;

    // 0. barrier flags + weight converts + bf16 x
    zero_flags_kernel<<<33, 256, 0, stream>>>(buf_flags, 8448);
    cvt_bf16_kernel<<<2048, 256, 0, stream>>>(Wih0, Wih0_bf, 4096 * 2048 / 8);
    cvt_bf16_kernel<<<1024, 256, 0, stream>>>(fc1w, fc1w_bf, 1024 * 2048 / 8);
    embed_concat_bf_kernel<<<2048, 256, 0, stream>>>(emb, ctxin, tw, x_bf);

    // 1. gates0_pre = x @ Wih0^T + bih0 + bhh0   (bf16 MFMA, async staging)
    gemm_lds_bt<<<512, 256, 0, stream>>>(
        x_bf, Wih0_bf, bih0, bhh0, buf_gates, nullptr, 2048, 4096, 2048, 0);

    // 2. Both LSTM layers (also writes bf16 y1 into fin_bf hi-half)
    lstm_fused<<<2 * NBLK, 256, 0, stream>>>(
        buf_gates, Whh0, Wih1, Whh1, bih1, bhh1, h0, c0,
        buf_y1, fin_bf, out_hn, out_cn, buf_hbf, buf_flags, buf_epoch);

    // 3. fc2 weight convert (gates/x_bf/Wih0_bf dead now; region reused)
    cvt_bf16_kernel<<<2048, 256, 0, stream>>>(fc2w, fc2w_bf, VOCAB * HID / 8);

    // 4. Attention (fp32, exact window/p path); attn_fused also fills fin_bf lo-half
    gemm_bt<<<dim3(512 / 64, 2048 / 128), 256, 0, stream>>>(
        buf_y1, aw1, ab1, nullptr, buf_hidden1, 2048, 512, 1024, 2 /*tanh*/);
    attn_p_kernel<<<2048, 64, 0, stream>>>(buf_hidden1, aw2, ab2, lens, buf_p, buf_win);
    sel_gather_kernel<<<2048, 256, 0, stream>>>(enc, buf_win, buf_sel);
    attn_fused_kernel<<<2048, 128, 0, stream>>>(buf_y1, buf_sel, buf_p, buf_win, lens,
                                                out_ctx, fin_bf);

    // 5. fc1 = relu([ctx, y1] @ fc1_w^T + fc1_b) -> bf16 only
    gemm_lds_bt<<<128, 256, 0, stream>>>(
        fin_bf, fc1w_bf, fc1b, nullptr, nullptr, fc1out_bf, 2048, 1024, 2048, 1);

    // 6. fc2: y = fc1out @ fc2_w^T + fc2_b -> fp32 d_out
    gemm_lds_bt<<<4000, 256, 0, stream>>>(
        fc1out_bf, fc2w_bf, fc2b, nullptr, out, nullptr, 2048, VOCAB, 1024, 0);
}

// Round 9
// 1020.458 us; speedup vs baseline: 9.9851x; 1.1197x over previous
//
#include <hip/hip_runtime.h>
#include <hip/hip_bf16.h>

// Problem constants
#define T_STEPS 64
#define BATCH   32
#define HID     1024
#define VOCAB   32000
#define WLEN_   101
#define WSZ_    50
#define SENC    229
#define LBLK    64      // blocks per LSTM role; grid = 3*LBLK = 192

static const size_t Y_SZ   = (size_t)T_STEPS * BATCH * VOCAB;   // 65,536,000
static const size_t HN_SZ  = (size_t)2 * BATCH * HID;           // 65,536
static const size_t CTX_OFF = Y_SZ + 2 * HN_SZ;                 // y + h_n + c_n

typedef __attribute__((ext_vector_type(8)))  unsigned short us8;
typedef __attribute__((ext_vector_type(8)))  __bf16 bf16x8;
typedef __attribute__((ext_vector_type(4)))  float f32x4;
typedef __attribute__((ext_vector_type(16))) float f32x16;

static __device__ inline unsigned short f2bf(float x) {
    __hip_bfloat16 b = __float2bfloat16(x);
    return __builtin_bit_cast(unsigned short, b);
}

// Coherence-point (LLC) accesses for the LSTM cross-block exchange.
#define GLD_US8_SC(dst, ptr) \
    asm volatile("global_load_dwordx4 %0, %1, off sc0 sc1" : "=v"(dst) : "v"(ptr) : "memory")
#define GLD_F32_SC(dst, ptr) \
    asm volatile("global_load_dword %0, %1, off sc0 sc1" : "=v"(dst) : "v"(ptr) : "memory")
#define GST_U16_SC(ptr, val) \
    asm volatile("global_store_short %0, %1, off sc0 sc1" :: "v"(ptr), "v"(val) : "memory")
#define GST_U32_SC(ptr, val) \
    asm volatile("global_store_dword %0, %1, off sc0 sc1" :: "v"(ptr), "v"(val) : "memory")
#define WAIT_VM0() asm volatile("s_waitcnt vmcnt(0)" ::: "memory")

// ---------------------------------------------------------------------------
// fp32 GEMM (attn-proj path only — keeps window indices exact)
// ---------------------------------------------------------------------------
__global__ __launch_bounds__(256) void gemm_bt(
    const float* __restrict__ A, const float* __restrict__ W,
    const float* __restrict__ b1, const float* __restrict__ b2,
    float* __restrict__ out, int M, int N, int K, int act)
{
    __shared__ __align__(16) float As[16 * 132];
    __shared__ __align__(16) float Ws[16 * 68];
    const int tid  = threadIdx.x;
    const int col0 = blockIdx.x * 64;
    const int row0 = blockIdx.y * 128;
    const int ty   = tid >> 4;
    const int tx   = tid & 15;

    float acc[8][4];
#pragma unroll
    for (int i = 0; i < 8; ++i)
#pragma unroll
        for (int j = 0; j < 4; ++j) acc[i][j] = 0.f;

    for (int k0 = 0; k0 < K; k0 += 16) {
#pragma unroll
        for (int li = 0; li < 2; ++li) {
            int f  = tid + li * 256;
            int r  = f >> 2;
            int kq = (f & 3) << 2;
            float4 v = *reinterpret_cast<const float4*>(A + (size_t)(row0 + r) * K + k0 + kq);
            As[(kq + 0) * 132 + r] = v.x;
            As[(kq + 1) * 132 + r] = v.y;
            As[(kq + 2) * 132 + r] = v.z;
            As[(kq + 3) * 132 + r] = v.w;
        }
        {
            int n  = tid >> 2;
            int kq = (tid & 3) << 2;
            float4 v = *reinterpret_cast<const float4*>(W + (size_t)(col0 + n) * K + k0 + kq);
            Ws[(kq + 0) * 68 + n] = v.x;
            Ws[(kq + 1) * 68 + n] = v.y;
            Ws[(kq + 2) * 68 + n] = v.z;
            Ws[(kq + 3) * 68 + n] = v.w;
        }
        __syncthreads();
#pragma unroll
        for (int k = 0; k < 16; ++k) {
            const float4 a0 = *reinterpret_cast<const float4*>(&As[k * 132 + ty * 8]);
            const float4 a1 = *reinterpret_cast<const float4*>(&As[k * 132 + ty * 8 + 4]);
            const float4 b0 = *reinterpret_cast<const float4*>(&Ws[k * 68 + tx * 4]);
            float av[8] = {a0.x, a0.y, a0.z, a0.w, a1.x, a1.y, a1.z, a1.w};
            float bv[4] = {b0.x, b0.y, b0.z, b0.w};
#pragma unroll
            for (int i = 0; i < 8; ++i)
#pragma unroll
                for (int j = 0; j < 4; ++j) acc[i][j] = fmaf(av[i], bv[j], acc[i][j]);
        }
        __syncthreads();
    }

#pragma unroll
    for (int j = 0; j < 4; ++j) {
        int n = col0 + tx * 4 + j;
        float bias = 0.f;
        if (b1) bias += b1[n];
        if (b2) bias += b2[n];
#pragma unroll
        for (int i = 0; i < 8; ++i) {
            float v = acc[i][j] + bias;
            if (act == 1) v = fmaxf(v, 0.f);
            else if (act == 2) v = tanhf(v);
            out[(size_t)(row0 + ty * 8 + i) * N + n] = v;
        }
    }
}

// ---------------------------------------------------------------------------
// bf16 MFMA GEMM, m97-style (unchanged from round 8, verified).
// ---------------------------------------------------------------------------
__global__ __launch_bounds__(256) void gemm_lds_bt(
    const unsigned short* __restrict__ A, const unsigned short* __restrict__ W,
    const float* __restrict__ b1, const float* __restrict__ b2,
    float* __restrict__ out, unsigned short* __restrict__ out_bf,
    int M, int N, int K, int relu)
{
    __shared__ __align__(16) unsigned short As[8192];
    __shared__ __align__(16) unsigned short Ws[8192];
    const int tid  = threadIdx.x;
    const int lane = tid & 63;
    const int wave = tid >> 6;

    const int nwg = gridDim.x;
    const int bid = blockIdx.x;
    const int q = nwg >> 3, r8 = nwg & 7;
    const int xcd = bid & 7, sidx = bid >> 3;
    const int wgid = (xcd < r8 ? xcd * (q + 1) : r8 * (q + 1) + (xcd - r8) * q) + sidx;
    const int mt = M >> 7;
    const int row0 = (wgid % mt) << 7;
    const int col0 = (wgid / mt) << 7;

    const int m0   = (wave >> 1) * 64;
    const int n0   = (wave & 1) * 64;
    const int lrow = lane & 15;
    const int kc   = lane >> 4;

    f32x4 acc[4][4];
#pragma unroll
    for (int i = 0; i < 4; ++i)
#pragma unroll
        for (int j = 0; j < 4; ++j) acc[i][j] = (f32x4){0.f, 0.f, 0.f, 0.f};

    const bool isA = (wave < 2);
    const int  lw  = wave & 1;
    const unsigned short* gbase = isA ? (A + (size_t)row0 * K) : (W + (size_t)col0 * K);
    unsigned short* lbase = isA ? As : Ws;

    for (int k0 = 0; k0 < K; k0 += 64) {
#pragma unroll
        for (int i = 0; i < 8; ++i) {
            const int c    = lw * 512 + i * 64 + lane;
            const int row  = c >> 3;
            const int slot = c & 7;
            const unsigned short* src =
                gbase + (size_t)row * K + k0 + ((slot ^ (row & 7)) << 3);
            __builtin_amdgcn_global_load_lds(
                (const __attribute__((address_space(1))) void*)src,
                (__attribute__((address_space(3))) void*)(lbase + (size_t)(lw * 512 + i * 64) * 8),
                16, 0, 0);
        }
        __syncthreads();
#pragma unroll
        for (int ss = 0; ss < 2; ++ss) {
            us8 a[4], b[4];
#pragma unroll
            for (int f = 0; f < 4; ++f) {
                const int ar = m0 + f * 16 + lrow;
                const int as = (ss * 4 + kc) ^ (ar & 7);
                a[f] = *reinterpret_cast<const us8*>(&As[(ar * 8 + as) * 8]);
                const int br = n0 + f * 16 + lrow;
                const int bs = (ss * 4 + kc) ^ (br & 7);
                b[f] = *reinterpret_cast<const us8*>(&Ws[(br * 8 + bs) * 8]);
            }
#pragma unroll
            for (int fi = 0; fi < 4; ++fi)
#pragma unroll
                for (int fj = 0; fj < 4; ++fj)
                    acc[fi][fj] = __builtin_amdgcn_mfma_f32_16x16x32_bf16(
                        __builtin_bit_cast(bf16x8, a[fi]),
                        __builtin_bit_cast(bf16x8, b[fj]),
                        acc[fi][fj], 0, 0, 0);
        }
        __syncthreads();
    }

#pragma unroll
    for (int fi = 0; fi < 4; ++fi)
#pragma unroll
        for (int fj = 0; fj < 4; ++fj) {
            const int cN = col0 + n0 + fj * 16 + lrow;
            float bv = 0.f;
            if (b1) bv += b1[cN];
            if (b2) bv += b2[cN];
#pragma unroll
            for (int j = 0; j < 4; ++j) {
                const int r = row0 + m0 + fi * 16 + (lane >> 4) * 4 + j;
                float v = acc[fi][fj][j] + bv;
                if (relu) v = fmaxf(v, 0.f);
                if (out)    out[(size_t)r * N + cN] = v;
                if (out_bf) out_bf[(size_t)r * N + cN] = f2bf(v);
            }
        }
}

// ---------------------------------------------------------------------------
__global__ void cvt_bf16_kernel(const float* __restrict__ src,
                                unsigned short* __restrict__ dst, int n8)
{
    for (int i = blockIdx.x * blockDim.x + threadIdx.x; i < n8;
         i += gridDim.x * blockDim.x) {
        float4 v0 = *reinterpret_cast<const float4*>(src + (size_t)i * 8);
        float4 v1 = *reinterpret_cast<const float4*>(src + (size_t)i * 8 + 4);
        us8 c = {f2bf(v0.x), f2bf(v0.y), f2bf(v0.z), f2bf(v0.w),
                 f2bf(v1.x), f2bf(v1.y), f2bf(v1.z), f2bf(v1.w)};
        *reinterpret_cast<us8*>(dst + (size_t)i * 8) = c;
    }
}

__global__ void embed_concat_bf_kernel(const float* __restrict__ emb,
                                       const float* __restrict__ ctxin,
                                       const int* __restrict__ tw,
                                       unsigned short* __restrict__ x_bf)
{
    const int total = 2048 * 256;
    for (int idx = blockIdx.x * blockDim.x + threadIdx.x; idx < total;
         idx += gridDim.x * blockDim.x) {
        int row = idx >> 8;
        int c8  = idx & 255;
        const float* src = (c8 < 128)
            ? emb + (size_t)tw[row] * HID + c8 * 8
            : ctxin + (size_t)row * HID + (c8 - 128) * 8;
        float4 v0 = *reinterpret_cast<const float4*>(src);
        float4 v1 = *reinterpret_cast<const float4*>(src + 4);
        us8 c = {f2bf(v0.x), f2bf(v0.y), f2bf(v0.z), f2bf(v0.w),
                 f2bf(v1.x), f2bf(v1.y), f2bf(v1.z), f2bf(v1.w)};
        *reinterpret_cast<us8*>(x_bf + (size_t)idx * 8) = c;
    }
}

__global__ void zero_flags_kernel(int* p, int n)
{
    int i = blockIdx.x * blockDim.x + threadIdx.x;
    if (i < n) p[i] = 0;
}

// ---------------------------------------------------------------------------
// Hierarchical fenceless grid barrier (192 blocks).
// ---------------------------------------------------------------------------
static __device__ inline void hier_arrive(int* __restrict__ flags, int phase, int tid)
{
    if (tid == 0)
        __hip_atomic_store(&flags[blockIdx.x * 32], phase,
                           __ATOMIC_RELAXED, __HIP_MEMORY_SCOPE_AGENT);
}

static __device__ inline void hier_wait(int* __restrict__ flags, int* __restrict__ epoch,
                                        int phase, int tid)
{
    if (blockIdx.x == 0) {
        if (tid < 3 * LBLK) {
            while (__hip_atomic_load(&flags[tid * 32], __ATOMIC_RELAXED,
                                     __HIP_MEMORY_SCOPE_AGENT) < phase)
                __builtin_amdgcn_s_sleep(1);
        }
        __syncthreads();
        if (tid < 8)
            __hip_atomic_store(&epoch[tid * 32], phase,
                               __ATOMIC_RELAXED, __HIP_MEMORY_SCOPE_AGENT);
    } else {
        if (tid == 0) {
            const int slot = (blockIdx.x & 7) * 32;
            while (__hip_atomic_load(&epoch[slot], __ATOMIC_RELAXED,
                                     __HIP_MEMORY_SCOPE_AGENT) < phase)
                __builtin_amdgcn_s_sleep(1);
        }
        __syncthreads();
    }
}

// ---------------------------------------------------------------------------
// 3-role fused persistent LSTM, 66 phases, balanced 16-col blocks.
// Role A (blk 0..63):   Whh0 recurrence + elementwise L0; reads h0 (hb0).
// Role C (blk 64..127): y0@Wih1 partials; reads hb0; writes part[t&1].
// Role B (blk 128..191):Whh1 recurrence + partial + elementwise L1.
// A: t=p (p 0..63); C: t=p-1 (p 1..64); B: t=p-2 (p 2..65).
// All exchange via sc0sc1 LLC ops; flag barrier per phase (fenceless).
// Also converts fc2w fp32->bf16 in barrier-spin slack when foldcvt.
// ---------------------------------------------------------------------------
__global__ __launch_bounds__(256) void lstm_fused3(
    const float* __restrict__ gpre0,  // [64*32,4096]
    const float* __restrict__ Whh0, const float* __restrict__ Wih1,
    const float* __restrict__ Whh1,
    const float* __restrict__ bih1, const float* __restrict__ bhh1,
    const float* __restrict__ h0all, const float* __restrict__ c0all,
    float* __restrict__ y1o,          // [64][32][1024] fp32
    unsigned short* __restrict__ fin_bf, // [2048][2048] (hi half)
    float* __restrict__ hn, float* __restrict__ cn,
    unsigned short* __restrict__ hbf, // hb0[2],hb1[2] x 32768 bf16
    float* __restrict__ part,         // [2][64][2048] f32
    int* __restrict__ flags, int* __restrict__ epoch,
    const float* __restrict__ fc2w, unsigned short* __restrict__ fc2w_bf,
    int foldcvt)
{
    __shared__ __align__(16) us8 WB[8192];   // 128 KB
    __shared__ float red2[32 * 132];         // 16.9 KB
    __shared__ float csh[512];

    const int tid  = threadIdx.x;
    const int lane = tid & 63;
    const int w    = tid >> 6;
    const int n    = lane & 31;
    const int kh   = lane >> 5;
    const int bid  = blockIdx.x;
    const int role = bid >> 6;        // 0=A, 1=C, 2=B
    const int lb   = bid & 63;
    const int j0   = lb * 16;
    const int b    = tid >> 3;
    const int jj   = tid & 7;

    unsigned short* hb0 = hbf;
    unsigned short* hb1 = hbf + 65536;

    // ---- pack weights (16 cols = 64 gate rows, 2 tiles x 4 waves x 16 frags) ----
    {
        const float* Wsrc = (role == 0) ? Whh0 : (role == 1 ? Wih1 : Whh1);
        const int g = n >> 3, cj = n & 7;
#pragma unroll
        for (int T = 0; T < 2; ++T) {
            const float* wrow = Wsrc + (size_t)(g * HID + j0 + T * 8 + cj) * HID;
#pragma unroll
            for (int f = 0; f < 16; ++f) {
                int k = w * 256 + f * 16 + kh * 8;
                float4 v0 = *reinterpret_cast<const float4*>(wrow + k);
                float4 v1 = *reinterpret_cast<const float4*>(wrow + k + 4);
                WB[((T * 4 + w) * 16 + f) * 64 + lane] =
                    (us8){f2bf(v0.x), f2bf(v0.y), f2bf(v0.z), f2bf(v0.w),
                          f2bf(v1.x), f2bf(v1.y), f2bf(v1.z), f2bf(v1.w)};
            }
        }
    }

    // ---- state init ----
    float gp[2][4] = {};
    float bb[2][4] = {};
    if (role == 0) {
#pragma unroll
        for (int T = 0; T < 2; ++T) {
            csh[T * 256 + tid] = c0all[b * HID + j0 + T * 8 + jj];
#pragma unroll
            for (int g = 0; g < 4; ++g)
                gp[T][g] = gpre0[(size_t)b * 4096 + g * HID + j0 + T * 8 + jj];
        }
#pragma unroll
        for (int q = 0; q < 2; ++q) {
            int idx = lb * 512 + q * 256 + tid;
            unsigned int hv = f2bf(h0all[idx]);
            GST_U16_SC(hb0 + idx, hv);                 // h0(-1) -> hb0[0]
        }
    } else if (role == 2) {
#pragma unroll
        for (int T = 0; T < 2; ++T) {
            csh[T * 256 + tid] = c0all[32768 + b * HID + j0 + T * 8 + jj];
#pragma unroll
            for (int g = 0; g < 4; ++g)
                bb[T][g] = bih1[g * HID + j0 + T * 8 + jj] + bhh1[g * HID + j0 + T * 8 + jj];
        }
#pragma unroll
        for (int q = 0; q < 2; ++q) {
            int idx = lb * 512 + q * 256 + tid;
            unsigned int hv = f2bf(h0all[32768 + idx]);
            GST_U16_SC(hb1 + 32768 + idx, hv);         // h1(-1) -> hb1[1]
        }
    }

    WAIT_VM0();
    __syncthreads();
    hier_arrive(flags, 1, tid);
    hier_wait(flags, epoch, 1, tid);

    for (int p = 0; p <= 65; ++p) {
        const bool active = (role == 0) ? (p <= 63)
                          : (role == 1) ? (p >= 1 && p <= 64)
                                        : (p >= 2);
        if (active) {
            const int t = p - role;   // role == lag (A:0, C:1, B:2)
            float pv[2][4];
            if (role == 2) {
                const float* pb = part + (size_t)(p & 1) * 131072 + lb * 2048 + b * 64 + jj;
#pragma unroll
                for (int T = 0; T < 2; ++T)
#pragma unroll
                    for (int g = 0; g < 4; ++g)
                        GLD_F32_SC(pv[T][g], pb + T * 32 + g * 8);
            }
            const unsigned short* hsrc = (role == 2)
                ? hb1 + ((p + 1) & 1) * 32768
                : hb0 + (p & 1) * 32768;
            const unsigned short* hr = hsrc + n * HID + w * 256 + kh * 8;
            us8 aF[16];
#pragma unroll
            for (int f = 0; f < 16; ++f)
                GLD_US8_SC(aF[f], hr + f * 16);
            WAIT_VM0();
            __builtin_amdgcn_sched_barrier(0);

            f32x16 acc0 = {}, acc1 = {};
#pragma unroll
            for (int f = 0; f < 16; ++f)
                acc0 = __builtin_amdgcn_mfma_f32_32x32x16_bf16(
                    __builtin_bit_cast(bf16x8, aF[f]),
                    __builtin_bit_cast(bf16x8, WB[((0 * 4 + w) * 16 + f) * 64 + lane]),
                    acc0, 0, 0, 0);
#pragma unroll
            for (int f = 0; f < 16; ++f)
                acc1 = __builtin_amdgcn_mfma_f32_32x32x16_bf16(
                    __builtin_bit_cast(bf16x8, aF[f]),
                    __builtin_bit_cast(bf16x8, WB[((1 * 4 + w) * 16 + f) * 64 + lane]),
                    acc1, 0, 0, 0);

            // ---- two reduce+elementwise passes (T=0 uses acc0, T=1 acc1) ----
#pragma unroll
            for (int T = 0; T < 2; ++T) {
                if (T == 1) __syncthreads();   // prior red2 reads done
#pragma unroll
                for (int r = 0; r < 16; ++r) {
                    int m = (r & 3) + 8 * (r >> 2) + 4 * kh;
                    red2[m * 132 + w * 32 + n] = (T == 0) ? acc0[r] : acc1[r];
                }
                __syncthreads();
                float s0, s1, s2, s3;
                {
                    const float* rr = &red2[b * 132 + jj];
                    s0 = rr[0]  + rr[32]  + rr[64]  + rr[96];
                    s1 = rr[8]  + rr[40]  + rr[72]  + rr[104];
                    s2 = rr[16] + rr[48]  + rr[80]  + rr[112];
                    s3 = rr[24] + rr[56]  + rr[88]  + rr[120];
                }
                const int col = j0 + T * 8 + jj;
                if (role == 1) {
                    float* pdst = part + (size_t)((p - 1) & 1) * 131072 + lb * 2048
                                + b * 64 + T * 32 + jj;
                    GST_U32_SC(pdst,      s0);
                    GST_U32_SC(pdst + 8,  s1);
                    GST_U32_SC(pdst + 16, s2);
                    GST_U32_SC(pdst + 24, s3);
                } else {
                    if (role == 0) { s0 += gp[T][0]; s1 += gp[T][1]; s2 += gp[T][2]; s3 += gp[T][3]; }
                    else { s0 += pv[T][0] + bb[T][0]; s1 += pv[T][1] + bb[T][1];
                           s2 += pv[T][2] + bb[T][2]; s3 += pv[T][3] + bb[T][3]; }
                    float ig = 1.f / (1.f + expf(-s0));
                    float fg = 1.f / (1.f + expf(-s1));
                    float gg = tanhf(s2);
                    float og = 1.f / (1.f + expf(-s3));
                    float cv = fg * csh[T * 256 + tid] + ig * gg;
                    csh[T * 256 + tid] = cv;
                    float h = og * tanhf(cv);
                    unsigned int hv = f2bf(h);
                    if (role == 0) {
                        GST_U16_SC(hb0 + ((p + 1) & 1) * 32768 + b * HID + col, hv);
                        if (t == T_STEPS - 1) { hn[b * HID + col] = h; cn[b * HID + col] = cv; }
                    } else {
                        __builtin_nontemporal_store(h, &y1o[(size_t)t * 32768 + b * HID + col]);
                        fin_bf[(size_t)(t * BATCH + b) * 2048 + 1024 + col] = f2bf(h);
                        if (t == T_STEPS - 1) {
                            hn[32768 + b * HID + col] = h;
                            cn[32768 + b * HID + col] = cv;
                        } else {
                            GST_U16_SC(hb1 + (p & 1) * 32768 + b * HID + col, hv);
                        }
                    }
                }
            }
        }
        if (p < 65) {
            WAIT_VM0();
            __syncthreads();
            hier_arrive(flags, p + 2, tid);
            if (role == 0 && p + 1 <= 63) {
                const float* gsrc = gpre0 + (size_t)((p + 1) * BATCH + b) * 4096 + j0 + jj;
#pragma unroll
                for (int T = 0; T < 2; ++T)
#pragma unroll
                    for (int g = 0; g < 4; ++g)
                        gp[T][g] = gsrc[g * HID + T * 8];
            }
            if (foldcvt && p < 64 && bid != 0) {
                const int slot = p * 191 + (bid - 1);
                for (int j = tid; j < 336; j += 256) {
                    int i = slot * 336 + j;
                    if (i < 4096000) {
                        float4 v0 = *reinterpret_cast<const float4*>(fc2w + (size_t)i * 8);
                        float4 v1 = *reinterpret_cast<const float4*>(fc2w + (size_t)i * 8 + 4);
                        us8 c = {f2bf(v0.x), f2bf(v0.y), f2bf(v0.z), f2bf(v0.w),
                                 f2bf(v1.x), f2bf(v1.y), f2bf(v1.z), f2bf(v1.w)};
                        *reinterpret_cast<us8*>(fc2w_bf + (size_t)i * 8) = c;
                    }
                }
            }
            hier_wait(flags, epoch, p + 2, tid);
        }
    }
}

// ---------------------------------------------------------------------------
// Attention
// ---------------------------------------------------------------------------
__global__ __launch_bounds__(64) void attn_p_kernel(
    const float* __restrict__ hidden1, const float* __restrict__ aw2,
    const float* __restrict__ ab2, const int* __restrict__ lengths,
    float* __restrict__ p_arr, int* __restrict__ win_arr)
{
    const int row = blockIdx.x;
    const int lane = threadIdx.x;
    float s = 0.f;
    for (int i = lane; i < 512; i += 64) s += hidden1[(size_t)row * 512 + i] * aw2[i];
    for (int off = 32; off > 0; off >>= 1) s += __shfl_down(s, off);
    if (lane == 0) {
        float v = s + ab2[0];
        float sig = 1.f / (1.f + expf(-v));
        int b = row & 31;
        float lf = (float)lengths[b];
        p_arr[row] = (float)WSZ_ + lf * sig;
        win_arr[row] = (int)rintf(lf * sig);
    }
}

// Fused attention; selection read DIRECTLY from enc via win_last[b].
__global__ __launch_bounds__(128) void attn_fused_kernel(
    const float* __restrict__ y1, const float* __restrict__ enc,
    const float* __restrict__ p_arr, const int* __restrict__ win_arr,
    const int* __restrict__ lengths, float* __restrict__ ctx,
    unsigned short* __restrict__ fin_bf)
{
    __shared__ __align__(16) float yl[1024];
    __shared__ float sv[WLEN_];
    __shared__ float av[WLEN_];
    const int row = blockIdx.x;
    const int b   = row & 31;
    const int tid = threadIdx.x;

    for (int i = tid; i < 1024; i += 128) yl[i] = y1[(size_t)row * HID + i];
    __syncthreads();

    const int win = win_arr[row];
    const int wl  = win_arr[(T_STEPS - 1) * BATCH + b];   // last step's window
    const float p = p_arr[row];
    const int len = lengths[b];

    if (tid < WLEN_) {
        const float4* s4 = reinterpret_cast<const float4*>(
            enc + ((size_t)(wl + tid) * BATCH + b) * HID);
        const float4* y4 = reinterpret_cast<const float4*>(yl);
        float acc = 0.f;
        for (int q = 0; q < 256; ++q) {
            float4 a = s4[q]; float4 yy = y4[q];
            acc += a.x * yy.x + a.y * yy.y + a.z * yy.z + a.w * yy.w;
        }
        bool lo = tid < (WSZ_ - win);
        bool hi = tid >= (len + WSZ_ - win);
        sv[tid] = (lo || hi) ? 1e-14f : acc;
    }
    __syncthreads();

    float mx = -1e30f;
    for (int w = 0; w < WLEN_; ++w) mx = fmaxf(mx, sv[w]);
    float sum = 0.f;
    for (int w = 0; w < WLEN_; ++w) sum += expf(sv[w] - mx);
    if (tid < WLEN_) {
        float e = expf(sv[tid] - mx) / sum;
        float d = (float)(win + tid) - p;
        av[tid] = e * expf(-(d * d) / 1250.f);
    }
    __syncthreads();

    float acc[8] = {0, 0, 0, 0, 0, 0, 0, 0};
    for (int w = 0; w < WLEN_; ++w) {
        float a = av[w];
        const float* srow = enc + ((size_t)(wl + w) * BATCH + b) * HID;
#pragma unroll
        for (int i = 0; i < 8; ++i) acc[i] += a * srow[tid + 128 * i];
    }
    for (int i = 0; i < 8; ++i) {
        ctx[(size_t)row * HID + tid + 128 * i] = acc[i];
        fin_bf[(size_t)row * 2048 + tid + 128 * i] = f2bf(acc[i]);
    }
}

// ---------------------------------------------------------------------------
extern "C" void kernel_launch(void* const* d_in, const int* in_sizes, int n_in,
                              void* d_out, int out_size, void* d_ws, size_t ws_size,
                              hipStream_t stream)
{
    const float* enc   = (const float*)d_in[0];
    const float* ctxin = (const float*)d_in[1];
    const float* h0    = (const float*)d_in[2];
    const float* c0    = (const float*)d_in[3];
    const float* emb   = (const float*)d_in[4];
    const float* aw1   = (const float*)d_in[5];
    const float* ab1   = (const float*)d_in[6];
    const float* aw2   = (const float*)d_in[7];
    const float* ab2   = (const float*)d_in[8];
    const float* Wih0  = (const float*)d_in[9];
    const float* Whh0  = (const float*)d_in[10];
    const float* bih0  = (const float*)d_in[11];
    const float* bhh0  = (const float*)d_in[12];
    const float* Wih1  = (const float*)d_in[13];
    const float* Whh1  = (const float*)d_in[14];
    const float* bih1  = (const float*)d_in[15];
    const float* bhh1  = (const float*)d_in[16];
    const float* fc1w  = (const float*)d_in[17];
    const float* fc1b  = (const float*)d_in[18];
    const float* fc2w  = (const float*)d_in[19];
    const float* fc2b  = (const float*)d_in[20];
    const int*   tw    = (const int*)d_in[21];
    const int*   lens  = (const int*)d_in[22];

    float* ws = (float*)d_ws;
    float*          buf_gates = ws;                                   // 8,388,608 fl (gpre0)
    unsigned short* x_bf      = (unsigned short*)(ws + 8388608);      // dead post-gates0
    float*          buf_part  = ws + 8388608;                         // alias x_bf: 262,144 fl
    unsigned short* Wih0_bf   = (unsigned short*)(ws + 10485760);     // dead post-gates0
    float*          buf_y1    = ws + 16384000;
    unsigned short* buf_hbf   = (unsigned short*)(ws + 18481152);     // 131,072 sh
    int*            buf_flags = (int*)(ws + 18546688);
    int*            buf_epoch = buf_flags + 8192;
    float*          buf_hidden1 = ws + 18555136;
    float*          buf_p     = ws + 19603712;
    int*            buf_win   = (int*)(ws + 19605760);
    unsigned short* fin_bf    = (unsigned short*)(ws + 22917376);
    unsigned short* fc1w_bf   = (unsigned short*)(ws + 25014528);
    unsigned short* fc1out_bf = (unsigned short*)(ws + 26063104);     // ends 27,111,680 fl

    // fc2w_bf: folded into LSTM spin slack if ws has room; else post-LSTM alias of ws[0]
    const size_t fold_end_bytes = (size_t)(27111680 + 8192000) * 4;   // ~141.2 MB
    const int foldcvt = (ws_size >= fold_end_bytes) ? 1 : 0;
    unsigned short* fc2w_bf = foldcvt ? (unsigned short*)(ws + 27111680)
                                      : (unsigned short*)ws;

    float* out   = (float*)d_out;
    float* out_hn  = out + Y_SZ;
    float* out_cn  = out + Y_SZ + HN_SZ;
    float* out_ctx = out + CTX_OFF;

    // 0. barrier flags + weight converts + bf16 x
    zero_flags_kernel<<<33, 256, 0, stream>>>(buf_flags, 8448);
    cvt_bf16_kernel<<<2048, 256, 0, stream>>>(Wih0, Wih0_bf, 4096 * 2048 / 8);
    cvt_bf16_kernel<<<1024, 256, 0, stream>>>(fc1w, fc1w_bf, 1024 * 2048 / 8);
    embed_concat_bf_kernel<<<2048, 256, 0, stream>>>(emb, ctxin, tw, x_bf);

    // 1. gates0_pre = x @ Wih0^T + bih0 + bhh0   (bf16 MFMA, async staging)
    gemm_lds_bt<<<512, 256, 0, stream>>>(
        x_bf, Wih0_bf, bih0, bhh0, buf_gates, nullptr, 2048, 4096, 2048, 0);

    // 2. Both LSTM layers, 3-role balanced persistent pipeline
    lstm_fused3<<<3 * LBLK, 256, 0, stream>>>(
        buf_gates, Whh0, Wih1, Whh1, bih1, bhh1, h0, c0,
        buf_y1, fin_bf, out_hn, out_cn, buf_hbf, buf_part,
        buf_flags, buf_epoch, fc2w, fc2w_bf, foldcvt);

    // 3. fc2 weight convert fallback (only if not folded)
    if (!foldcvt)
        cvt_bf16_kernel<<<2048, 256, 0, stream>>>(fc2w, fc2w_bf, VOCAB * HID / 8);

    // 4. Attention (fp32 exact); attn_fused reads enc directly, fills fin_bf lo
    gemm_bt<<<dim3(512 / 64, 2048 / 128), 256, 0, stream>>>(
        buf_y1, aw1, ab1, nullptr, buf_hidden1, 2048, 512, 1024, 2 /*tanh*/);
    attn_p_kernel<<<2048, 64, 0, stream>>>(buf_hidden1, aw2, ab2, lens, buf_p, buf_win);
    attn_fused_kernel<<<2048, 128, 0, stream>>>(buf_y1, enc, buf_p, buf_win, lens,
                                                out_ctx, fin_bf);

    // 5. fc1 = relu([ctx, y1] @ fc1_w^T + fc1_b) -> bf16
    gemm_lds_bt<<<128, 256, 0, stream>>>(
        fin_bf, fc1w_bf, fc1b, nullptr, nullptr, fc1out_bf, 2048, 1024, 2048, 1);

    // 6. fc2: y = fc1out @ fc2_w^T + fc2_b -> fp32 d_out
    gemm_lds_bt<<<4000, 256, 0, stream>>>(
        fc1out_bf, fc2w_bf, fc2b, nullptr, out, nullptr, 2048, VOCAB, 1024, 0);
}

// Round 10
// 936.171 us; speedup vs baseline: 10.8841x; 1.0900x over previous
//
#include <hip/hip_runtime.h>
#include <hip/hip_bf16.h>

// Problem constants
#define T_STEPS 64
#define BATCH   32
#define HID     1024
#define VOCAB   32000
#define WLEN_   101
#define WSZ_    50
#define SENC    229
#define LBLK    64      // blocks per LSTM role; grid = 3*LBLK = 192

static const size_t Y_SZ   = (size_t)T_STEPS * BATCH * VOCAB;   // 65,536,000
static const size_t HN_SZ  = (size_t)2 * BATCH * HID;           // 65,536
static const size_t CTX_OFF = Y_SZ + 2 * HN_SZ;                 // y + h_n + c_n

typedef __attribute__((ext_vector_type(8)))  unsigned short us8;
typedef __attribute__((ext_vector_type(8)))  __bf16 bf16x8;
typedef __attribute__((ext_vector_type(4)))  float f32x4;
typedef __attribute__((ext_vector_type(16))) float f32x16;

static __device__ inline unsigned short f2bf(float x) {
    __hip_bfloat16 b = __float2bfloat16(x);
    return __builtin_bit_cast(unsigned short, b);
}

// Coherence-point (LLC) accesses for the LSTM cross-block exchange.
#define GLD_US8_SC(dst, ptr) \
    asm volatile("global_load_dwordx4 %0, %1, off sc0 sc1" : "=v"(dst) : "v"(ptr) : "memory")
#define GLD_F32_SC(dst, ptr) \
    asm volatile("global_load_dword %0, %1, off sc0 sc1" : "=v"(dst) : "v"(ptr) : "memory")
#define GST_U16_SC(ptr, val) \
    asm volatile("global_store_short %0, %1, off sc0 sc1" :: "v"(ptr), "v"(val) : "memory")
#define GST_U32_SC(ptr, val) \
    asm volatile("global_store_dword %0, %1, off sc0 sc1" :: "v"(ptr), "v"(val) : "memory")
#define WAIT_VM0() asm volatile("s_waitcnt vmcnt(0)" ::: "memory")

// ---------------------------------------------------------------------------
// fp32 GEMM (attn-proj path only — keeps window indices exact)
// ---------------------------------------------------------------------------
__global__ __launch_bounds__(256) void gemm_bt(
    const float* __restrict__ A, const float* __restrict__ W,
    const float* __restrict__ b1, const float* __restrict__ b2,
    float* __restrict__ out, int M, int N, int K, int act)
{
    __shared__ __align__(16) float As[16 * 132];
    __shared__ __align__(16) float Ws[16 * 68];
    const int tid  = threadIdx.x;
    const int col0 = blockIdx.x * 64;
    const int row0 = blockIdx.y * 128;
    const int ty   = tid >> 4;
    const int tx   = tid & 15;

    float acc[8][4];
#pragma unroll
    for (int i = 0; i < 8; ++i)
#pragma unroll
        for (int j = 0; j < 4; ++j) acc[i][j] = 0.f;

    for (int k0 = 0; k0 < K; k0 += 16) {
#pragma unroll
        for (int li = 0; li < 2; ++li) {
            int f  = tid + li * 256;
            int r  = f >> 2;
            int kq = (f & 3) << 2;
            float4 v = *reinterpret_cast<const float4*>(A + (size_t)(row0 + r) * K + k0 + kq);
            As[(kq + 0) * 132 + r] = v.x;
            As[(kq + 1) * 132 + r] = v.y;
            As[(kq + 2) * 132 + r] = v.z;
            As[(kq + 3) * 132 + r] = v.w;
        }
        {
            int n  = tid >> 2;
            int kq = (tid & 3) << 2;
            float4 v = *reinterpret_cast<const float4*>(W + (size_t)(col0 + n) * K + k0 + kq);
            Ws[(kq + 0) * 68 + n] = v.x;
            Ws[(kq + 1) * 68 + n] = v.y;
            Ws[(kq + 2) * 68 + n] = v.z;
            Ws[(kq + 3) * 68 + n] = v.w;
        }
        __syncthreads();
#pragma unroll
        for (int k = 0; k < 16; ++k) {
            const float4 a0 = *reinterpret_cast<const float4*>(&As[k * 132 + ty * 8]);
            const float4 a1 = *reinterpret_cast<const float4*>(&As[k * 132 + ty * 8 + 4]);
            const float4 b0 = *reinterpret_cast<const float4*>(&Ws[k * 68 + tx * 4]);
            float av[8] = {a0.x, a0.y, a0.z, a0.w, a1.x, a1.y, a1.z, a1.w};
            float bv[4] = {b0.x, b0.y, b0.z, b0.w};
#pragma unroll
            for (int i = 0; i < 8; ++i)
#pragma unroll
                for (int j = 0; j < 4; ++j) acc[i][j] = fmaf(av[i], bv[j], acc[i][j]);
        }
        __syncthreads();
    }

#pragma unroll
    for (int j = 0; j < 4; ++j) {
        int n = col0 + tx * 4 + j;
        float bias = 0.f;
        if (b1) bias += b1[n];
        if (b2) bias += b2[n];
#pragma unroll
        for (int i = 0; i < 8; ++i) {
            float v = acc[i][j] + bias;
            if (act == 1) v = fmaxf(v, 0.f);
            else if (act == 2) v = tanhf(v);
            out[(size_t)(row0 + ty * 8 + i) * N + n] = v;
        }
    }
}

// ---------------------------------------------------------------------------
// bf16 MFMA GEMM, m97-style (unchanged, verified rounds 8-9).
// ---------------------------------------------------------------------------
__global__ __launch_bounds__(256) void gemm_lds_bt(
    const unsigned short* __restrict__ A, const unsigned short* __restrict__ W,
    const float* __restrict__ b1, const float* __restrict__ b2,
    float* __restrict__ out, unsigned short* __restrict__ out_bf,
    int M, int N, int K, int relu)
{
    __shared__ __align__(16) unsigned short As[8192];
    __shared__ __align__(16) unsigned short Ws[8192];
    const int tid  = threadIdx.x;
    const int lane = tid & 63;
    const int wave = tid >> 6;

    const int nwg = gridDim.x;
    const int bid = blockIdx.x;
    const int q = nwg >> 3, r8 = nwg & 7;
    const int xcd = bid & 7, sidx = bid >> 3;
    const int wgid = (xcd < r8 ? xcd * (q + 1) : r8 * (q + 1) + (xcd - r8) * q) + sidx;
    const int mt = M >> 7;
    const int row0 = (wgid % mt) << 7;
    const int col0 = (wgid / mt) << 7;

    const int m0   = (wave >> 1) * 64;
    const int n0   = (wave & 1) * 64;
    const int lrow = lane & 15;
    const int kc   = lane >> 4;

    f32x4 acc[4][4];
#pragma unroll
    for (int i = 0; i < 4; ++i)
#pragma unroll
        for (int j = 0; j < 4; ++j) acc[i][j] = (f32x4){0.f, 0.f, 0.f, 0.f};

    const bool isA = (wave < 2);
    const int  lw  = wave & 1;
    const unsigned short* gbase = isA ? (A + (size_t)row0 * K) : (W + (size_t)col0 * K);
    unsigned short* lbase = isA ? As : Ws;

    for (int k0 = 0; k0 < K; k0 += 64) {
#pragma unroll
        for (int i = 0; i < 8; ++i) {
            const int c    = lw * 512 + i * 64 + lane;
            const int row  = c >> 3;
            const int slot = c & 7;
            const unsigned short* src =
                gbase + (size_t)row * K + k0 + ((slot ^ (row & 7)) << 3);
            __builtin_amdgcn_global_load_lds(
                (const __attribute__((address_space(1))) void*)src,
                (__attribute__((address_space(3))) void*)(lbase + (size_t)(lw * 512 + i * 64) * 8),
                16, 0, 0);
        }
        __syncthreads();
#pragma unroll
        for (int ss = 0; ss < 2; ++ss) {
            us8 a[4], b[4];
#pragma unroll
            for (int f = 0; f < 4; ++f) {
                const int ar = m0 + f * 16 + lrow;
                const int as = (ss * 4 + kc) ^ (ar & 7);
                a[f] = *reinterpret_cast<const us8*>(&As[(ar * 8 + as) * 8]);
                const int br = n0 + f * 16 + lrow;
                const int bs = (ss * 4 + kc) ^ (br & 7);
                b[f] = *reinterpret_cast<const us8*>(&Ws[(br * 8 + bs) * 8]);
            }
#pragma unroll
            for (int fi = 0; fi < 4; ++fi)
#pragma unroll
                for (int fj = 0; fj < 4; ++fj)
                    acc[fi][fj] = __builtin_amdgcn_mfma_f32_16x16x32_bf16(
                        __builtin_bit_cast(bf16x8, a[fi]),
                        __builtin_bit_cast(bf16x8, b[fj]),
                        acc[fi][fj], 0, 0, 0);
        }
        __syncthreads();
    }

#pragma unroll
    for (int fi = 0; fi < 4; ++fi)
#pragma unroll
        for (int fj = 0; fj < 4; ++fj) {
            const int cN = col0 + n0 + fj * 16 + lrow;
            float bv = 0.f;
            if (b1) bv += b1[cN];
            if (b2) bv += b2[cN];
#pragma unroll
            for (int j = 0; j < 4; ++j) {
                const int r = row0 + m0 + fi * 16 + (lane >> 4) * 4 + j;
                float v = acc[fi][fj][j] + bv;
                if (relu) v = fmaxf(v, 0.f);
                if (out)    out[(size_t)r * N + cN] = v;
                if (out_bf) out_bf[(size_t)r * N + cN] = f2bf(v);
            }
        }
}

// ---------------------------------------------------------------------------
__global__ void cvt_bf16_kernel(const float* __restrict__ src,
                                unsigned short* __restrict__ dst, int n8)
{
    for (int i = blockIdx.x * blockDim.x + threadIdx.x; i < n8;
         i += gridDim.x * blockDim.x) {
        float4 v0 = *reinterpret_cast<const float4*>(src + (size_t)i * 8);
        float4 v1 = *reinterpret_cast<const float4*>(src + (size_t)i * 8 + 4);
        us8 c = {f2bf(v0.x), f2bf(v0.y), f2bf(v0.z), f2bf(v0.w),
                 f2bf(v1.x), f2bf(v1.y), f2bf(v1.z), f2bf(v1.w)};
        *reinterpret_cast<us8*>(dst + (size_t)i * 8) = c;
    }
}

__global__ void embed_concat_bf_kernel(const float* __restrict__ emb,
                                       const float* __restrict__ ctxin,
                                       const int* __restrict__ tw,
                                       unsigned short* __restrict__ x_bf)
{
    const int total = 2048 * 256;
    for (int idx = blockIdx.x * blockDim.x + threadIdx.x; idx < total;
         idx += gridDim.x * blockDim.x) {
        int row = idx >> 8;
        int c8  = idx & 255;
        const float* src = (c8 < 128)
            ? emb + (size_t)tw[row] * HID + c8 * 8
            : ctxin + (size_t)row * HID + (c8 - 128) * 8;
        float4 v0 = *reinterpret_cast<const float4*>(src);
        float4 v1 = *reinterpret_cast<const float4*>(src + 4);
        us8 c = {f2bf(v0.x), f2bf(v0.y), f2bf(v0.z), f2bf(v0.w),
                 f2bf(v1.x), f2bf(v1.y), f2bf(v1.z), f2bf(v1.w)};
        *reinterpret_cast<us8*>(x_bf + (size_t)idx * 8) = c;
    }
}

__global__ void zero_flags_kernel(int* p, int n)
{
    int i = blockIdx.x * blockDim.x + threadIdx.x;
    if (i < n) p[i] = 0;
}

// ---------------------------------------------------------------------------
// Hierarchical fenceless grid barrier (192 blocks).
// ---------------------------------------------------------------------------
static __device__ inline void hier_arrive(int* __restrict__ flags, int phase, int tid)
{
    if (tid == 0)
        __hip_atomic_store(&flags[blockIdx.x * 32], phase,
                           __ATOMIC_RELAXED, __HIP_MEMORY_SCOPE_AGENT);
}

static __device__ inline void hier_wait(int* __restrict__ flags, int* __restrict__ epoch,
                                        int phase, int tid)
{
    if (blockIdx.x == 0) {
        if (tid < 3 * LBLK) {
            while (__hip_atomic_load(&flags[tid * 32], __ATOMIC_RELAXED,
                                     __HIP_MEMORY_SCOPE_AGENT) < phase)
                __builtin_amdgcn_s_sleep(1);
        }
        __syncthreads();
        if (tid < 8)
            __hip_atomic_store(&epoch[tid * 32], phase,
                               __ATOMIC_RELAXED, __HIP_MEMORY_SCOPE_AGENT);
    } else {
        if (tid == 0) {
            const int slot = (blockIdx.x & 7) * 32;
            while (__hip_atomic_load(&epoch[slot], __ATOMIC_RELAXED,
                                     __HIP_MEMORY_SCOPE_AGENT) < phase)
                __builtin_amdgcn_s_sleep(1);
        }
        __syncthreads();
    }
}

// ---------------------------------------------------------------------------
// 3-role fused persistent LSTM, 66 phases, balanced 16-col blocks.
// h ping-pong buffers use FRAGMENT-LINEAR layout so every cross-block LLC
// access is contiguous per instruction:
//   h[chunk cc=k/8][batch n][k%8]  ->  elem = cc*256 + n*8 + (k&7)
//   reader (lane,frag f, wave w):  base + (w*32+f*2)*512B + lane*16B  (1KB/load)
//   writer (thread tid, tile T):   base + (lb*2+T)*512B + tid*2B      (contig)
// Partials use tid-linear layout:  part[p&1][lb][T*4+g][tid]          (256B/op)
// Roles: A=Whh0+elemwise L0 (t=p), C=y0@Wih1 partials (t=p-1),
//        B=Whh1+partial+elemwise L1 (t=p-2). sc0sc1 LLC exchange, flag barrier.
// Also converts fc2w fp32->bf16 in barrier-spin slack when foldcvt.
// ---------------------------------------------------------------------------
__global__ __launch_bounds__(256) void lstm_fused3(
    const float* __restrict__ gpre0,  // [64*32,4096]
    const float* __restrict__ Whh0, const float* __restrict__ Wih1,
    const float* __restrict__ Whh1,
    const float* __restrict__ bih1, const float* __restrict__ bhh1,
    const float* __restrict__ h0all, const float* __restrict__ c0all,
    float* __restrict__ y1o,          // [64][32][1024] fp32
    unsigned short* __restrict__ fin_bf, // [2048][2048] (hi half)
    float* __restrict__ hn, float* __restrict__ cn,
    unsigned short* __restrict__ hbf, // hb0[2],hb1[2] x 32768 bf16 (fragment-linear)
    float* __restrict__ part,         // [2][64][8][256] f32
    int* __restrict__ flags, int* __restrict__ epoch,
    const float* __restrict__ fc2w, unsigned short* __restrict__ fc2w_bf,
    int foldcvt)
{
    __shared__ __align__(16) us8 WB[8192];   // 128 KB
    __shared__ float red2[32 * 132];         // 16.9 KB
    __shared__ float csh[512];

    const int tid  = threadIdx.x;
    const int lane = tid & 63;
    const int w    = tid >> 6;
    const int n    = lane & 31;
    const int kh   = lane >> 5;
    const int bid  = blockIdx.x;
    const int role = bid >> 6;        // 0=A, 1=C, 2=B
    const int lb   = bid & 63;
    const int j0   = lb * 16;
    const int b    = tid >> 3;
    const int jj   = tid & 7;

    unsigned short* hb0 = hbf;
    unsigned short* hb1 = hbf + 65536;

    // ---- pack weights (16 cols = 64 gate rows, 2 tiles x 4 waves x 16 frags) ----
    {
        const float* Wsrc = (role == 0) ? Whh0 : (role == 1 ? Wih1 : Whh1);
        const int g = n >> 3, cj = n & 7;
#pragma unroll
        for (int T = 0; T < 2; ++T) {
            const float* wrow = Wsrc + (size_t)(g * HID + j0 + T * 8 + cj) * HID;
#pragma unroll
            for (int f = 0; f < 16; ++f) {
                int k = w * 256 + f * 16 + kh * 8;
                float4 v0 = *reinterpret_cast<const float4*>(wrow + k);
                float4 v1 = *reinterpret_cast<const float4*>(wrow + k + 4);
                WB[((T * 4 + w) * 16 + f) * 64 + lane] =
                    (us8){f2bf(v0.x), f2bf(v0.y), f2bf(v0.z), f2bf(v0.w),
                          f2bf(v1.x), f2bf(v1.y), f2bf(v1.z), f2bf(v1.w)};
            }
        }
    }

    // ---- state init (fragment-linear: e = cc*256 + n*8 + c7) ----
    float gp[2][4] = {};
    float bb[2][4] = {};
    if (role == 0) {
#pragma unroll
        for (int T = 0; T < 2; ++T) {
            csh[T * 256 + tid] = c0all[b * HID + j0 + T * 8 + jj];
#pragma unroll
            for (int g = 0; g < 4; ++g)
                gp[T][g] = gpre0[(size_t)b * 4096 + g * HID + j0 + T * 8 + jj];
        }
#pragma unroll
        for (int q = 0; q < 2; ++q) {
            int e = lb * 512 + q * 256 + tid;
            unsigned int hv = f2bf(h0all[((e >> 3) & 31) * HID + (e >> 8) * 8 + (e & 7)]);
            GST_U16_SC(hb0 + e, hv);                   // h0(-1) -> hb0[0]
        }
    } else if (role == 2) {
#pragma unroll
        for (int T = 0; T < 2; ++T) {
            csh[T * 256 + tid] = c0all[32768 + b * HID + j0 + T * 8 + jj];
#pragma unroll
            for (int g = 0; g < 4; ++g)
                bb[T][g] = bih1[g * HID + j0 + T * 8 + jj] + bhh1[g * HID + j0 + T * 8 + jj];
        }
#pragma unroll
        for (int q = 0; q < 2; ++q) {
            int e = lb * 512 + q * 256 + tid;
            unsigned int hv = f2bf(h0all[32768 + ((e >> 3) & 31) * HID + (e >> 8) * 8 + (e & 7)]);
            GST_U16_SC(hb1 + 32768 + e, hv);           // h1(-1) -> hb1[1]
        }
    }

    WAIT_VM0();
    __syncthreads();
    hier_arrive(flags, 1, tid);
    hier_wait(flags, epoch, 1, tid);

    for (int p = 0; p <= 65; ++p) {
        const bool active = (role == 0) ? (p <= 63)
                          : (role == 1) ? (p >= 1 && p <= 64)
                                        : (p >= 2);
        if (active) {
            const int t = p - role;   // role == lag (A:0, C:1, B:2)
            float pv[2][4];
            if (role == 2) {
                const float* pb = part + (size_t)(p & 1) * 131072 + lb * 2048 + tid;
#pragma unroll
                for (int T = 0; T < 2; ++T)
#pragma unroll
                    for (int g = 0; g < 4; ++g)
                        GLD_F32_SC(pv[T][g], pb + (T * 4 + g) * 256);
            }
            const unsigned short* hsrc = (role == 2)
                ? hb1 + ((p + 1) & 1) * 32768
                : hb0 + (p & 1) * 32768;
            // fragment-linear read: 1KB contiguous per instruction
            const unsigned short* hr = hsrc + (size_t)w * 8192 + lane * 8;
            us8 aF[16];
#pragma unroll
            for (int f = 0; f < 16; ++f)
                GLD_US8_SC(aF[f], hr + f * 512);
            WAIT_VM0();
            __builtin_amdgcn_sched_barrier(0);

            f32x16 acc0 = {}, acc1 = {};
#pragma unroll
            for (int f = 0; f < 16; ++f)
                acc0 = __builtin_amdgcn_mfma_f32_32x32x16_bf16(
                    __builtin_bit_cast(bf16x8, aF[f]),
                    __builtin_bit_cast(bf16x8, WB[((0 * 4 + w) * 16 + f) * 64 + lane]),
                    acc0, 0, 0, 0);
#pragma unroll
            for (int f = 0; f < 16; ++f)
                acc1 = __builtin_amdgcn_mfma_f32_32x32x16_bf16(
                    __builtin_bit_cast(bf16x8, aF[f]),
                    __builtin_bit_cast(bf16x8, WB[((1 * 4 + w) * 16 + f) * 64 + lane]),
                    acc1, 0, 0, 0);

            // ---- two reduce+elementwise passes ----
#pragma unroll
            for (int T = 0; T < 2; ++T) {
                if (T == 1) __syncthreads();
#pragma unroll
                for (int r = 0; r < 16; ++r) {
                    int m = (r & 3) + 8 * (r >> 2) + 4 * kh;
                    red2[m * 132 + w * 32 + n] = (T == 0) ? acc0[r] : acc1[r];
                }
                __syncthreads();
                float s0, s1, s2, s3;
                {
                    const float* rr = &red2[b * 132 + jj];
                    s0 = rr[0]  + rr[32]  + rr[64]  + rr[96];
                    s1 = rr[8]  + rr[40]  + rr[72]  + rr[104];
                    s2 = rr[16] + rr[48]  + rr[80]  + rr[112];
                    s3 = rr[24] + rr[56]  + rr[88]  + rr[120];
                }
                const int col = j0 + T * 8 + jj;
                const int he  = (lb * 2 + T) * 256 + tid;   // fragment-linear write slot
                if (role == 1) {
                    float* pdst = part + (size_t)((p - 1) & 1) * 131072 + lb * 2048 + tid;
                    GST_U32_SC(pdst + (T * 4 + 0) * 256, s0);
                    GST_U32_SC(pdst + (T * 4 + 1) * 256, s1);
                    GST_U32_SC(pdst + (T * 4 + 2) * 256, s2);
                    GST_U32_SC(pdst + (T * 4 + 3) * 256, s3);
                } else {
                    if (role == 0) { s0 += gp[T][0]; s1 += gp[T][1]; s2 += gp[T][2]; s3 += gp[T][3]; }
                    else { s0 += pv[T][0] + bb[T][0]; s1 += pv[T][1] + bb[T][1];
                           s2 += pv[T][2] + bb[T][2]; s3 += pv[T][3] + bb[T][3]; }
                    float ig = 1.f / (1.f + expf(-s0));
                    float fg = 1.f / (1.f + expf(-s1));
                    float gg = tanhf(s2);
                    float og = 1.f / (1.f + expf(-s3));
                    float cv = fg * csh[T * 256 + tid] + ig * gg;
                    csh[T * 256 + tid] = cv;
                    float h = og * tanhf(cv);
                    unsigned int hv = f2bf(h);
                    if (role == 0) {
                        GST_U16_SC(hb0 + ((p + 1) & 1) * 32768 + he, hv);
                        if (t == T_STEPS - 1) { hn[b * HID + col] = h; cn[b * HID + col] = cv; }
                    } else {
                        __builtin_nontemporal_store(h, &y1o[(size_t)t * 32768 + b * HID + col]);
                        fin_bf[(size_t)(t * BATCH + b) * 2048 + 1024 + col] = f2bf(h);
                        if (t == T_STEPS - 1) {
                            hn[32768 + b * HID + col] = h;
                            cn[32768 + b * HID + col] = cv;
                        } else {
                            GST_U16_SC(hb1 + (p & 1) * 32768 + he, hv);
                        }
                    }
                }
            }
        }
        if (p < 65) {
            WAIT_VM0();
            __syncthreads();
            hier_arrive(flags, p + 2, tid);
            if (role == 0 && p + 1 <= 63) {
                const float* gsrc = gpre0 + (size_t)((p + 1) * BATCH + b) * 4096 + j0 + jj;
#pragma unroll
                for (int T = 0; T < 2; ++T)
#pragma unroll
                    for (int g = 0; g < 4; ++g)
                        gp[T][g] = gsrc[g * HID + T * 8];
            }
            if (foldcvt && p < 64 && bid != 0) {
                const int slot = p * 191 + (bid - 1);
                for (int j = tid; j < 336; j += 256) {
                    int i = slot * 336 + j;
                    if (i < 4096000) {
                        float4 v0 = *reinterpret_cast<const float4*>(fc2w + (size_t)i * 8);
                        float4 v1 = *reinterpret_cast<const float4*>(fc2w + (size_t)i * 8 + 4);
                        us8 c = {f2bf(v0.x), f2bf(v0.y), f2bf(v0.z), f2bf(v0.w),
                                 f2bf(v1.x), f2bf(v1.y), f2bf(v1.z), f2bf(v1.w)};
                        *reinterpret_cast<us8*>(fc2w_bf + (size_t)i * 8) = c;
                    }
                }
            }
            hier_wait(flags, epoch, p + 2, tid);
        }
    }
}

// ---------------------------------------------------------------------------
// Attention
// ---------------------------------------------------------------------------
__global__ __launch_bounds__(64) void attn_p_kernel(
    const float* __restrict__ hidden1, const float* __restrict__ aw2,
    const float* __restrict__ ab2, const int* __restrict__ lengths,
    float* __restrict__ p_arr, int* __restrict__ win_arr)
{
    const int row = blockIdx.x;
    const int lane = threadIdx.x;
    float s = 0.f;
    for (int i = lane; i < 512; i += 64) s += hidden1[(size_t)row * 512 + i] * aw2[i];
    for (int off = 32; off > 0; off >>= 1) s += __shfl_down(s, off);
    if (lane == 0) {
        float v = s + ab2[0];
        float sig = 1.f / (1.f + expf(-v));
        int b = row & 31;
        float lf = (float)lengths[b];
        p_arr[row] = (float)WSZ_ + lf * sig;
        win_arr[row] = (int)rintf(lf * sig);
    }
}

// Fused attention; selection read DIRECTLY from enc via win_last[b].
__global__ __launch_bounds__(128) void attn_fused_kernel(
    const float* __restrict__ y1, const float* __restrict__ enc,
    const float* __restrict__ p_arr, const int* __restrict__ win_arr,
    const int* __restrict__ lengths, float* __restrict__ ctx,
    unsigned short* __restrict__ fin_bf)
{
    __shared__ __align__(16) float yl[1024];
    __shared__ float sv[WLEN_];
    __shared__ float av[WLEN_];
    const int row = blockIdx.x;
    const int b   = row & 31;
    const int tid = threadIdx.x;

    for (int i = tid; i < 1024; i += 128) yl[i] = y1[(size_t)row * HID + i];
    __syncthreads();

    const int win = win_arr[row];
    const int wl  = win_arr[(T_STEPS - 1) * BATCH + b];   // last step's window
    const float p = p_arr[row];
    const int len = lengths[b];

    if (tid < WLEN_) {
        const float4* s4 = reinterpret_cast<const float4*>(
            enc + ((size_t)(wl + tid) * BATCH + b) * HID);
        const float4* y4 = reinterpret_cast<const float4*>(yl);
        float acc = 0.f;
        for (int q = 0; q < 256; ++q) {
            float4 a = s4[q]; float4 yy = y4[q];
            acc += a.x * yy.x + a.y * yy.y + a.z * yy.z + a.w * yy.w;
        }
        bool lo = tid < (WSZ_ - win);
        bool hi = tid >= (len + WSZ_ - win);
        sv[tid] = (lo || hi) ? 1e-14f : acc;
    }
    __syncthreads();

    float mx = -1e30f;
    for (int w = 0; w < WLEN_; ++w) mx = fmaxf(mx, sv[w]);
    float sum = 0.f;
    for (int w = 0; w < WLEN_; ++w) sum += expf(sv[w] - mx);
    if (tid < WLEN_) {
        float e = expf(sv[tid] - mx) / sum;
        float d = (float)(win + tid) - p;
        av[tid] = e * expf(-(d * d) / 1250.f);
    }
    __syncthreads();

    float acc[8] = {0, 0, 0, 0, 0, 0, 0, 0};
    for (int w = 0; w < WLEN_; ++w) {
        float a = av[w];
        const float* srow = enc + ((size_t)(wl + w) * BATCH + b) * HID;
#pragma unroll
        for (int i = 0; i < 8; ++i) acc[i] += a * srow[tid + 128 * i];
    }
    for (int i = 0; i < 8; ++i) {
        ctx[(size_t)row * HID + tid + 128 * i] = acc[i];
        fin_bf[(size_t)row * 2048 + tid + 128 * i] = f2bf(acc[i]);
    }
}

// ---------------------------------------------------------------------------
extern "C" void kernel_launch(void* const* d_in, const int* in_sizes, int n_in,
                              void* d_out, int out_size, void* d_ws, size_t ws_size,
                              hipStream_t stream)
{
    const float* enc   = (const float*)d_in[0];
    const float* ctxin = (const float*)d_in[1];
    const float* h0    = (const float*)d_in[2];
    const float* c0    = (const float*)d_in[3];
    const float* emb   = (const float*)d_in[4];
    const float* aw1   = (const float*)d_in[5];
    const float* ab1   = (const float*)d_in[6];
    const float* aw2   = (const float*)d_in[7];
    const float* ab2   = (const float*)d_in[8];
    const float* Wih0  = (const float*)d_in[9];
    const float* Whh0  = (const float*)d_in[10];
    const float* bih0  = (const float*)d_in[11];
    const float* bhh0  = (const float*)d_in[12];
    const float* Wih1  = (const float*)d_in[13];
    const float* Whh1  = (const float*)d_in[14];
    const float* bih1  = (const float*)d_in[15];
    const float* bhh1  = (const float*)d_in[16];
    const float* fc1w  = (const float*)d_in[17];
    const float* fc1b  = (const float*)d_in[18];
    const float* fc2w  = (const float*)d_in[19];
    const float* fc2b  = (const float*)d_in[20];
    const int*   tw    = (const int*)d_in[21];
    const int*   lens  = (const int*)d_in[22];

    float* ws = (float*)d_ws;
    float*          buf_gates = ws;                                   // 8,388,608 fl (gpre0)
    unsigned short* x_bf      = (unsigned short*)(ws + 8388608);      // dead post-gates0
    float*          buf_part  = ws + 8388608;                         // alias x_bf: 262,144 fl
    unsigned short* Wih0_bf   = (unsigned short*)(ws + 10485760);     // dead post-gates0
    float*          buf_y1    = ws + 16384000;
    unsigned short* buf_hbf   = (unsigned short*)(ws + 18481152);     // 131,072 sh
    int*            buf_flags = (int*)(ws + 18546688);
    int*            buf_epoch = buf_flags + 8192;
    float*          buf_hidden1 = ws + 18555136;
    float*          buf_p     = ws + 19603712;
    int*            buf_win   = (int*)(ws + 19605760);
    unsigned short* fin_bf    = (unsigned short*)(ws + 22917376);
    unsigned short* fc1w_bf   = (unsigned short*)(ws + 25014528);
    unsigned short* fc1out_bf = (unsigned short*)(ws + 26063104);     // ends 27,111,680 fl

    const size_t fold_end_bytes = (size_t)(27111680 + 8192000) * 4;
    const int foldcvt = (ws_size >= fold_end_bytes) ? 1 : 0;
    unsigned short* fc2w_bf = foldcvt ? (unsigned short*)(ws + 27111680)
                                      : (unsigned short*)ws;

    float* out   = (float*)d_out;
    float* out_hn  = out + Y_SZ;
    float* out_cn  = out + Y_SZ + HN_SZ;
    float* out_ctx = out + CTX_OFF;

    // 0. barrier flags + weight converts + bf16 x
    zero_flags_kernel<<<33, 256, 0, stream>>>(buf_flags, 8448);
    cvt_bf16_kernel<<<2048, 256, 0, stream>>>(Wih0, Wih0_bf, 4096 * 2048 / 8);
    cvt_bf16_kernel<<<1024, 256, 0, stream>>>(fc1w, fc1w_bf, 1024 * 2048 / 8);
    embed_concat_bf_kernel<<<2048, 256, 0, stream>>>(emb, ctxin, tw, x_bf);

    // 1. gates0_pre = x @ Wih0^T + bih0 + bhh0   (bf16 MFMA, async staging)
    gemm_lds_bt<<<512, 256, 0, stream>>>(
        x_bf, Wih0_bf, bih0, bhh0, buf_gates, nullptr, 2048, 4096, 2048, 0);

    // 2. Both LSTM layers, 3-role balanced pipeline, coalesced h exchange
    lstm_fused3<<<3 * LBLK, 256, 0, stream>>>(
        buf_gates, Whh0, Wih1, Whh1, bih1, bhh1, h0, c0,
        buf_y1, fin_bf, out_hn, out_cn, buf_hbf, buf_part,
        buf_flags, buf_epoch, fc2w, fc2w_bf, foldcvt);

    // 3. fc2 weight convert fallback (only if not folded)
    if (!foldcvt)
        cvt_bf16_kernel<<<2048, 256, 0, stream>>>(fc2w, fc2w_bf, VOCAB * HID / 8);

    // 4. Attention (fp32 exact); attn_fused reads enc directly, fills fin_bf lo
    gemm_bt<<<dim3(512 / 64, 2048 / 128), 256, 0, stream>>>(
        buf_y1, aw1, ab1, nullptr, buf_hidden1, 2048, 512, 1024, 2 /*tanh*/);
    attn_p_kernel<<<2048, 64, 0, stream>>>(buf_hidden1, aw2, ab2, lens, buf_p, buf_win);
    attn_fused_kernel<<<2048, 128, 0, stream>>>(buf_y1, enc, buf_p, buf_win, lens,
                                                out_ctx, fin_bf);

    // 5. fc1 = relu([ctx, y1] @ fc1_w^T + fc1_b) -> bf16
    gemm_lds_bt<<<128, 256, 0, stream>>>(
        fin_bf, fc1w_bf, fc1b, nullptr, nullptr, fc1out_bf, 2048, 1024, 2048, 1);

    // 6. fc2: y = fc1out @ fc2_w^T + fc2_b -> fp32 d_out
    gemm_lds_bt<<<4000, 256, 0, stream>>>(
        fc1out_bf, fc2w_bf, fc2b, nullptr, out, nullptr, 2048, VOCAB, 1024, 0);
}